// Round 4
// baseline (1226.385 us; speedup 1.0000x reference)
//
#include <hip/hip_runtime.h>

#define N_PTS   100000
#define M_CL    12500
#define E0_N    1600000
#define E1_N    400000

#define NB      128          // buckets for CSR build
#define BIN_CAP 48           // LDS staging entries per bucket
#define RANGE0  782          // ceil(N/NB)
#define RANGE1  98           // ceil(M/NB)
#define BCAP0   16384        // tmp region per bucket (l0, mean 12504)
#define BCAP1   4096         // tmp region per bucket (l1, mean 3125)

typedef unsigned short ushortT;

__device__ inline ushortT f2bf(float x){
  union{float f; unsigned u;} v; v.f = x;
  unsigned r = v.u + 0x7fffu + ((v.u >> 16) & 1u);   // RNE
  return (ushortT)(r >> 16);
}
__device__ inline float bf2f(ushortT h){
  union{unsigned u; float f;} v; v.u = ((unsigned)h) << 16;
  return v.f;
}

// ============================ bucketed CSR build ============================

__global__ void k_binit(int* c0, int* c1){
  int t = threadIdx.x;
  if (t < NB) c0[t] = t*BCAP0;
  else        c1[t-NB] = (t-NB)*BCAP1;
}

// Phase A: bin edges by dst range; LDS write-combining; packed (src<<11)|localDst
template<int RANGE>
__global__ __launch_bounds__(256) void k_bin(const int* __restrict__ edges, int E,
                                             int* __restrict__ bcur, unsigned* __restrict__ tmp){
  __shared__ unsigned stage[NB*BIN_CAP];   // 24 KB
  __shared__ int scnt[NB];
  __shared__ int sbase[NB];
  int tid = threadIdx.x;
  int nchunks = (E + 2047) / 2048;
  for (int c = blockIdx.x; c < nchunks; c += gridDim.x){
    int base = c*2048;
    if (tid < NB) scnt[tid] = 0;
    __syncthreads();
    #pragma unroll
    for (int r=0;r<8;++r){
      int e = base + r*256 + tid;
      if (e < E){
        int s = edges[2*e], d = edges[2*e+1];
        int bk = d / RANGE;                       // compile-time divisor
        unsigned packed = ((unsigned)s << 11) | (unsigned)(d - bk*RANGE);
        int pos = atomicAdd(&scnt[bk], 1);
        if (pos < BIN_CAP) stage[bk*BIN_CAP+pos] = packed;
        else tmp[atomicAdd(&bcur[bk],1)] = packed;   // rare overflow fallback
      }
    }
    __syncthreads();
    if (tid < NB){
      int nfl = scnt[tid]; if (nfl > BIN_CAP) nfl = BIN_CAP;
      sbase[tid] = atomicAdd(&bcur[tid], nfl);
    }
    __syncthreads();
    int wv = tid >> 6, ln = tid & 63;
    for (int bb=0; bb<NB/4; ++bb){
      int bk = wv*(NB/4) + bb;
      int nfl = scnt[bk]; if (nfl > BIN_CAP) nfl = BIN_CAP;
      if (ln < nfl) tmp[sbase[bk]+ln] = stage[bk*BIN_CAP+ln];
    }
    __syncthreads();
  }
}

// exclusive scan of the 128 bucket counts (2 blocks: 0->l0, 1->l1)
__global__ void k_scan_bases(const int* c0, int* bb0, int* off0e,
                             const int* c1, int* bb1, int* off1e){
  const int* cur = blockIdx.x ? c1 : c0;
  int* bb = blockIdx.x ? bb1 : bb0;
  int* offe = blockIdx.x ? off1e : off0e;
  int BC = blockIdx.x ? BCAP1 : BCAP0;
  int lane = threadIdx.x & 63;
  int v0 = cur[2*lane]   - (2*lane)*BC;
  int v1 = cur[2*lane+1] - (2*lane+1)*BC;
  int psum = v0 + v1, sc = psum;
  #pragma unroll
  for (int st=1; st<64; st<<=1){
    int x = __shfl_up(sc, st, 64);
    if (lane >= st) sc += x;
  }
  int ex = sc - psum;
  bb[2*lane] = ex; bb[2*lane+1] = ex + v0;
  if (lane == 63) *offe = sc;
}

// Phase B: per-bucket histogram + scan + L2-local scatter -> offs + csr
template<int RANGE, int BCAP>
__global__ __launch_bounds__(256) void k_csr_build(const unsigned* __restrict__ tmp, const int* __restrict__ bcur,
                                                   const int* __restrict__ bb, int n,
                                                   int* __restrict__ offs, int* __restrict__ csr){
  constexpr int K = (RANGE + 255) / 256;
  __shared__ int hist[RANGE];
  __shared__ int part[256];
  int b = blockIdx.x, tid = threadIdx.x;
  int dlo = b*RANGE;
  int range = n - dlo; if (range > RANGE) range = RANGE; if (range < 0) range = 0;
  int cnt = bcur[b] - b*BCAP;
  for (int t=tid; t<RANGE; t+=256) hist[t] = 0;
  __syncthreads();
  const unsigned* sl = tmp + (size_t)b*BCAP;
  for (int j=tid; j<cnt; j+=256) atomicAdd(&hist[sl[j] & 2047u], 1);
  __syncthreads();
  int s = 0; int loc[K];
  #pragma unroll
  for (int kk=0; kk<K; ++kk){
    int idx = tid*K + kk;
    int v = (idx < RANGE) ? hist[idx] : 0;
    loc[kk] = s; s += v;
  }
  part[tid] = s; __syncthreads();
  int own = s;
  for (int st=1; st<256; st<<=1){
    int x = (tid >= st) ? part[tid-st] : 0;
    __syncthreads();
    part[tid] += x;
    __syncthreads();
  }
  int ebase = part[tid] - own;      // exclusive block base for this thread's chunk
  int gb = bb[b];
  __syncthreads();                  // all loc[] reads of hist done -> safe to overwrite
  #pragma unroll
  for (int kk=0; kk<K; ++kk){
    int idx = tid*K + kk;
    if (idx < RANGE){
      int ex = ebase + loc[kk];
      if (idx < range) offs[dlo+idx] = gb + ex;
      hist[idx] = ex;               // becomes running cursor
    }
  }
  __syncthreads();
  for (int j=tid; j<cnt; j+=256){
    unsigned p = sl[j];
    int pos = atomicAdd(&hist[p & 2047u], 1);
    csr[gb + pos] = (int)(p >> 11);
  }
}

// ============================ label CSR (small: targets L2-resident) ============================

__global__ __launch_bounds__(256) void k_count_lab(const int* __restrict__ labels, int n, int* __restrict__ cnt){
  int i = blockIdx.x*256 + threadIdx.x;
  if (i < n) atomicAdd(&cnt[labels[i]], 1);
}

__global__ __launch_bounds__(256) void k_chunk_sum(const int* __restrict__ cnt, int n, int* __restrict__ part){
  __shared__ int sd[256];
  int t = threadIdx.x, base = blockIdx.x*2048;
  int s = 0;
  #pragma unroll
  for (int r=0;r<8;++r){ int i = base + t*8 + r; if (i<n) s += cnt[i]; }
  sd[t]=s; __syncthreads();
  for (int st=128; st>0; st>>=1){ if (t<st) sd[t]+=sd[t+st]; __syncthreads(); }
  if (t==0) part[blockIdx.x]=sd[0];
}

__global__ void k_scan_part(int* part, int B, int* offs, int n){
  int lane = threadIdx.x & 63;
  int v = (lane < B) ? part[lane] : 0;
  int orig = v;
  #pragma unroll
  for (int st=1; st<64; st<<=1){
    int x = __shfl_up(v, st, 64);
    if (lane >= st) v += x;
  }
  if (lane < B) part[lane] = v - orig;
  if (lane == 63) offs[n] = v;
}

__global__ __launch_bounds__(256) void k_chunk_scan(const int* __restrict__ cnt, int n,
                                                    const int* __restrict__ part, int* __restrict__ offs){
  __shared__ int sd[256];
  int t=threadIdx.x, base=blockIdx.x*2048;
  int v[8]; int s=0;
  #pragma unroll
  for (int r=0;r<8;++r){ int i=base+t*8+r; v[r] = (i<n)?cnt[i]:0; s+=v[r]; }
  sd[t]=s; __syncthreads();
  for (int st=1; st<256; st<<=1){
    int x = (t>=st)? sd[t-st] : 0;
    __syncthreads();
    sd[t]+=x;
    __syncthreads();
  }
  int acc = part[blockIdx.x] + sd[t] - s;
  #pragma unroll
  for (int r=0;r<8;++r){ int i=base+t*8+r; if (i<n) offs[i]=acc; acc+=v[r]; }
}

__global__ __launch_bounds__(256) void k_fill_lab(const int* __restrict__ labels, int n,
                                                  const int* __restrict__ offs, int* __restrict__ cur,
                                                  int* __restrict__ csr){
  int i = blockIdx.x*256 + threadIdx.x;
  if (i < n){
    int d = labels[i];
    int p = atomicAdd(&cur[d], 1);
    csr[offs[d]+p] = i;
  }
}

// ============================ fused feature encoder: rel + f1 + g0(bf16) ============================
// launch_bounds(256,2): EWc[64] must live in VGPRs (spill -> scratch was the R3 killer)

__global__ __launch_bounds__(256, 2) void k_f1f(const float* __restrict__ features, const float* __restrict__ points,
                                             const float* __restrict__ centers, const int* __restrict__ labels,
                                             const float* __restrict__ W, const float* __restrict__ b,
                                             const float* __restrict__ EW, const float* __restrict__ Eb,
                                             float* __restrict__ rel, float* __restrict__ f1,
                                             ushortT* __restrict__ gout, int n){
  __shared__ float rowbuf[256];
  int tid = threadIdx.x, lane = tid & 63, wslot = tid >> 6;
  int gw = (blockIdx.x*256 + tid) >> 6;
  int nw = (gridDim.x*256) >> 6;
  float Wf0=W[0*64+lane], Wf1=W[1*64+lane], Wf2=W[2*64+lane], Wf3=W[3*64+lane];
  float wr0=W[4*64+lane], wr1=W[5*64+lane], wr2=W[6*64+lane];
  float bias=b[lane];
  float EWc[64];
  #pragma unroll
  for (int k=0;k<64;++k) EWc[k] = EW[k*64+lane];
  float eb = Eb[lane];
  for (int i=gw; i<n; i+=nw){
    int lb = labels[i];
    float rx = points[i*3+0]-centers[lb*3+0];
    float ry = points[i*3+1]-centers[lb*3+1];
    float rz = points[i*3+2]-centers[lb*3+2];
    if (lane==0){ rel[i*3+0]=rx; rel[i*3+1]=ry; rel[i*3+2]=rz; }
    float acc = bias + wr0*rx + wr1*ry + wr2*rz;
    acc += features[i*4+0]*Wf0 + features[i*4+1]*Wf1;
    acc += features[i*4+2]*Wf2 + features[i*4+3]*Wf3;
    acc = fmaxf(acc, 0.f);
    f1[(size_t)i*64+lane] = acc;
    rowbuf[wslot*64+lane] = acc;
    __builtin_amdgcn_wave_barrier();
    const float4* rb = (const float4*)(rowbuf + wslot*64);
    float e0=0.f,e1=0.f,e2=0.f,e3=0.f;
    #pragma unroll
    for (int kk=0; kk<16; ++kk){
      float4 a4 = rb[kk];
      e0 += a4.x*EWc[4*kk+0]; e1 += a4.y*EWc[4*kk+1];
      e2 += a4.z*EWc[4*kk+2]; e3 += a4.w*EWc[4*kk+3];
    }
    gout[(size_t)i*64+lane] = f2bf(eb + (e0+e1) + (e2+e3));
  }
}

// ============================ node MLP with fused emit ============================
// EMODE: 0=none, 1=emit g bf16 (64-wide EW + Eb), 2=emit h bf16 (67-wide EW: +rel rows, +Eb, relu),
//        3=emit out8 fp32 (EW=W_c 64x8, Eb=b_c)
// launch_bounds(256,2): Wc[64]+EWc[64] = 128+ VGPRs MUST be in registers; the default
// cap spilled them to scratch (R3: VGPR_Count=84, 101us, VALUBusy 20%).

template<bool RELU, bool USE_REL, int NRES, bool GATHER, bool WRITEOUT, int EMODE>
__global__ __launch_bounds__(256, 2) void k_mlp(const float* __restrict__ A, const int* __restrict__ gidx,
                                             const float* __restrict__ rel,
                                             const float* __restrict__ W, const float* __restrict__ b,
                                             const float* __restrict__ r1, const float* __restrict__ r2,
                                             float* __restrict__ out,
                                             const float* __restrict__ EW, const float* __restrict__ Eb,
                                             void* __restrict__ eout, int n){
  __shared__ float rowbuf[256];
  __shared__ float wcs[512];
  int tid = threadIdx.x, lane = tid & 63, wslot = tid >> 6;
  if (EMODE == 3){
    wcs[tid] = EW[tid]; wcs[tid+256] = EW[tid+256];
    __syncthreads();
  }
  int gw = (blockIdx.x*256 + tid) >> 6;
  int nw = (gridDim.x*256) >> 6;
  float Wc[64];
  #pragma unroll
  for (int k=0;k<64;++k) Wc[k] = W[k*64+lane];
  float wr0=0.f, wr1=0.f, wr2=0.f;
  if (USE_REL){ wr0=W[64*64+lane]; wr1=W[65*64+lane]; wr2=W[66*64+lane]; }
  float bias = b[lane];
  float EWc[64];
  float er0=0.f, er1=0.f, er2=0.f, eb=0.f;
  if (EMODE==1 || EMODE==2){
    #pragma unroll
    for (int k=0;k<64;++k) EWc[k] = EW[k*64+lane];
    eb = Eb[lane];
  }
  if (EMODE==2){ er0=EW[64*64+lane]; er1=EW[65*64+lane]; er2=EW[66*64+lane]; }
  float ebias3 = 0.f;
  if (EMODE==3 && lane < 8) ebias3 = Eb[lane];
  for (int i=gw; i<n; i+=nw){
    int ar = GATHER ? gidx[i] : i;
    const float4* Arow = (const float4*)(A + (size_t)ar*64);
    float a0=0.f,a1=0.f,a2=0.f,a3=0.f;
    #pragma unroll
    for (int kk=0; kk<16; ++kk){
      float4 a4 = Arow[kk];
      a0 += a4.x*Wc[4*kk+0];
      a1 += a4.y*Wc[4*kk+1];
      a2 += a4.z*Wc[4*kk+2];
      a3 += a4.w*Wc[4*kk+3];
    }
    float acc = bias + (a0+a1) + (a2+a3);
    if (USE_REL) acc += rel[i*3+0]*wr0 + rel[i*3+1]*wr1 + rel[i*3+2]*wr2;
    if (RELU) acc = fmaxf(acc, 0.f);
    if (NRES>=1) acc += r1[(size_t)i*64+lane];
    if (NRES>=2) acc += r2[(size_t)i*64+lane];
    if (WRITEOUT) out[(size_t)i*64+lane] = acc;
    if (EMODE){
      rowbuf[wslot*64+lane] = acc;
      __builtin_amdgcn_wave_barrier();
      if (EMODE == 3){
        if (lane < 8){
          const float* rw = rowbuf + wslot*64;
          float s0=0.f, s1=0.f;
          #pragma unroll
          for (int k=0;k<64;k+=2){
            s0 += rw[k]  *wcs[k*8+lane];
            s1 += rw[k+1]*wcs[(k+1)*8+lane];
          }
          ((float*)eout)[(size_t)i*8+lane] = ebias3 + s0 + s1;
        }
      } else {
        const float4* rb = (const float4*)(rowbuf + wslot*64);
        float e0=0.f,e1=0.f,e2=0.f,e3=0.f;
        #pragma unroll
        for (int kk=0; kk<16; ++kk){
          float4 a4 = rb[kk];
          e0 += a4.x*EWc[4*kk+0]; e1 += a4.y*EWc[4*kk+1];
          e2 += a4.z*EWc[4*kk+2]; e3 += a4.w*EWc[4*kk+3];
        }
        float g = eb + (e0+e1) + (e2+e3);
        if (EMODE==2){
          g += rel[i*3+0]*er0 + rel[i*3+1]*er1 + rel[i*3+2]*er2;
          g = fmaxf(g, 0.f);
        }
        ((ushortT*)eout)[(size_t)i*64+lane] = f2bf(g);
      }
    }
  }
}

// ============================ edge aggregation (segment max via CSR) ============================

__global__ __launch_bounds__(256) void k_edge_agg(const int* __restrict__ offs, const int* __restrict__ csr,
                                                  const float* __restrict__ pos, const ushortT* __restrict__ g,
                                                  const float* __restrict__ Wp, float* __restrict__ agg, int n){
  int lane = threadIdx.x & 63;
  int gw = (blockIdx.x*256 + threadIdx.x) >> 6;
  int nw = (gridDim.x*256) >> 6;
  float w0 = Wp[0*64+lane], w1 = Wp[1*64+lane], w2 = Wp[2*64+lane];
  for (int i=gw; i<n; i+=nw){
    int b = offs[i], e = offs[i+1];
    float px = pos[i*3+0], py = pos[i*3+1], pz = pos[i*3+2];
    float m0=0.f, m1=0.f, m2=0.f, m3=0.f;
    int k = b;
    for (; k+4<=e; k+=4){
      int s0=csr[k+0], s1=csr[k+1], s2=csr[k+2], s3=csr[k+3];
      const float* p0=pos+3*s0; const float* p1=pos+3*s1;
      const float* p2=pos+3*s2; const float* p3=pos+3*s3;
      float g0=bf2f(g[(size_t)s0*64+lane]);
      float g1=bf2f(g[(size_t)s1*64+lane]);
      float g2=bf2f(g[(size_t)s2*64+lane]);
      float g3=bf2f(g[(size_t)s3*64+lane]);
      m0=fmaxf(m0, g0 + w0*(p0[0]-px) + w1*(p0[1]-py) + w2*(p0[2]-pz));
      m1=fmaxf(m1, g1 + w0*(p1[0]-px) + w1*(p1[1]-py) + w2*(p1[2]-pz));
      m2=fmaxf(m2, g2 + w0*(p2[0]-px) + w1*(p2[1]-py) + w2*(p2[2]-pz));
      m3=fmaxf(m3, g3 + w0*(p3[0]-px) + w1*(p3[1]-py) + w2*(p3[2]-pz));
    }
    for (; k<e; ++k){
      int s=csr[k];
      m0=fmaxf(m0, bf2f(g[(size_t)s*64+lane]) + w0*(pos[3*s]-px) + w1*(pos[3*s+1]-py) + w2*(pos[3*s+2]-pz));
    }
    agg[(size_t)i*64+lane] = fmaxf(fmaxf(m0,m1),fmaxf(m2,m3));
  }
}

// ============================ segment sum via label CSR (gather) ============================

__global__ __launch_bounds__(256) void k_seg_gather(const int* __restrict__ offs, const int* __restrict__ csr,
                                                    const ushortT* __restrict__ h, float* __restrict__ c, int m){
  int lane = threadIdx.x & 63;
  int wv = (blockIdx.x*256 + threadIdx.x) >> 6;
  if (wv >= m) return;
  int b = offs[wv], e = offs[wv+1];
  float acc = 0.f;
  for (int k=b; k<e; ++k){
    int i = csr[k];
    acc += bf2f(h[(size_t)i*64+lane]);
  }
  c[(size_t)wv*64+lane] = acc;
}

// ============================ host launcher ============================

extern "C" void kernel_launch(void* const* d_in, const int* in_sizes, int n_in,
                              void* d_out, int out_size, void* d_ws, size_t ws_size,
                              hipStream_t stream){
  const float* features = (const float*)d_in[0];
  const float* points   = (const float*)d_in[1];
  const float* centers  = (const float*)d_in[2];
  const int*   l0e      = (const int*)d_in[3];
  const int*   l1e      = (const int*)d_in[4];
  const int*   labels   = (const int*)d_in[5];
  const float* W_fe = (const float*)d_in[6];
  const float* b_fe = (const float*)d_in[7];
  const float* mWe  = (const float*)d_in[8];   // (4,67,64)
  const float* mbe  = (const float*)d_in[9];
  const float* mWu  = (const float*)d_in[10];  // (4,64,64)
  const float* mbu  = (const float*)d_in[11];
  const float* W_m1 = (const float*)d_in[12];
  const float* b_m1 = (const float*)d_in[13];
  const float* W_m2 = (const float*)d_in[14];
  const float* b_m2 = (const float*)d_in[15];
  const float* gWe  = (const float*)d_in[16];  // (2,67,64)
  const float* gbe  = (const float*)d_in[17];
  const float* gWu  = (const float*)d_in[18];
  const float* gbu  = (const float*)d_in[19];
  const float* W_l  = (const float*)d_in[20];
  const float* b_l  = (const float*)d_in[21];
  const float* W_c  = (const float*)d_in[22];
  const float* b_c  = (const float*)d_in[23];
  float* out = (float*)d_out;

  char* w = (char*)d_ws;
  size_t off = 0;
  auto alloc = [&](size_t bytes)->void*{
    void* p = (void*)(w + off);
    off = (off + bytes + 255) & ~(size_t)255;
    return p;
  };
  float* rel  = (float*)alloc((size_t)N_PTS*3*4);
  float* buf0 = (float*)alloc((size_t)N_PTS*64*4);     // f1 -> f5
  float* buf1 = (float*)alloc((size_t)N_PTS*64*4);     // f2
  float* buf2 = (float*)alloc((size_t)N_PTS*64*4);     // f2_1
  float* buf3 = (float*)alloc((size_t)N_PTS*64*4);     // f6
  ushortT* gbuf = (ushortT*)alloc((size_t)N_PTS*64*2); // g / h (bf16)
  float* abuf = (float*)alloc((size_t)N_PTS*64*4);     // agg
  float* cbuf = (float*)alloc((size_t)M_CL*64*4);
  float* f3   = (float*)alloc((size_t)M_CL*64*4);
  ushortT* cg = (ushortT*)alloc((size_t)M_CL*64*2);
  float* cagg = (float*)alloc((size_t)M_CL*64*4);
  float* f4   = (float*)alloc((size_t)M_CL*64*4);
  float* f41  = (float*)alloc((size_t)M_CL*64*4);
  int* offs0 = (int*)alloc((size_t)(N_PTS+1)*4);
  int* csr0  = (int*)alloc((size_t)E0_N*4);
  int* offs1 = (int*)alloc((size_t)(M_CL+1)*4);
  int* csr1  = (int*)alloc((size_t)E1_N*4);
  unsigned* tmp0 = (unsigned*)alloc((size_t)NB*BCAP0*4);  // 8.4 MB
  unsigned* tmp1 = (unsigned*)alloc((size_t)NB*BCAP1*4);  // 2.1 MB
  int* bcur0 = (int*)alloc(NB*4);
  int* bcur1 = (int*)alloc(NB*4);
  int* bb0   = (int*)alloc(NB*4);
  int* bb1   = (int*)alloc(NB*4);
  // label CSR (zeroed block)
  char* zbase = (char*)alloc(0);
  int* cntL = (int*)alloc((size_t)M_CL*4);
  int* curL = (int*)alloc((size_t)M_CL*4);
  size_t zbytes = (size_t)((char*)(w+off) - zbase);
  int* offsL = (int*)alloc((size_t)(M_CL+1)*4);
  int* csrL  = (int*)alloc((size_t)N_PTS*4);
  int* partL = (int*)alloc(64*4);
  (void)ws_size; (void)in_sizes; (void)n_in; (void)out_size;

  const int GB_N = 2048;
  const int GB_M = 512;

  hipMemsetAsync(zbase, 0, zbytes, stream);

  // ---- CSR builds (bucketed counting sort) ----
  k_binit<<<1, 256, 0, stream>>>(bcur0, bcur1);
  k_bin<RANGE0><<<256, 256, 0, stream>>>(l0e, E0_N, bcur0, tmp0);
  k_bin<RANGE1><<<196, 256, 0, stream>>>(l1e, E1_N, bcur1, tmp1);
  k_scan_bases<<<2, 64, 0, stream>>>(bcur0, bb0, offs0+N_PTS, bcur1, bb1, offs1+M_CL);
  k_csr_build<RANGE0,BCAP0><<<NB, 256, 0, stream>>>(tmp0, bcur0, bb0, N_PTS, offs0, csr0);
  k_csr_build<RANGE1,BCAP1><<<NB, 256, 0, stream>>>(tmp1, bcur1, bb1, M_CL, offs1, csr1);

  // ---- label CSR ----
  k_count_lab<<<(N_PTS+255)/256, 256, 0, stream>>>(labels, N_PTS, cntL);
  k_chunk_sum<<<7, 256, 0, stream>>>(cntL, M_CL, partL);
  k_scan_part<<<1, 64, 0, stream>>>(partL, 7, offsL, M_CL);
  k_chunk_scan<<<7, 256, 0, stream>>>(cntL, M_CL, partL, offsL);
  k_fill_lab<<<(N_PTS+255)/256, 256, 0, stream>>>(labels, N_PTS, offsL, curL, csrL);

  // ---- encoder: rel + f1 + g0 ----
  k_f1f<<<GB_N, 256, 0, stream>>>(features, points, centers, labels, W_fe, b_fe,
                                  mWe+192, mbe, rel, buf0, gbuf, N_PTS);

  // ---- mini layer 0: f2 + g1 ----
  k_edge_agg<<<GB_N,256,0,stream>>>(offs0, csr0, points, gbuf, mWe+0*4288, abuf, N_PTS);
  k_mlp<true,false,1,false,true,1><<<GB_N,256,0,stream>>>(abuf, nullptr, nullptr, mWu+0*4096, mbu+0*64,
      buf0, nullptr, buf1, mWe+1*4288+192, mbe+64, gbuf, N_PTS);

  // ---- mini layer 1: f2_1 + h (bf16 into gbuf) ----
  k_edge_agg<<<GB_N,256,0,stream>>>(offs0, csr0, points, gbuf, mWe+1*4288, abuf, N_PTS);
  k_mlp<true,false,1,false,true,2><<<GB_N,256,0,stream>>>(abuf, nullptr, rel, mWu+1*4096, mbu+1*64,
      buf1, nullptr, buf2, W_m1, b_m1, gbuf, N_PTS);

  // ---- c = segment_sum(h) ; f3 + cg0 ----
  k_seg_gather<<<(M_CL*64+255)/256, 256, 0, stream>>>(offsL, csrL, gbuf, cbuf, M_CL);
  k_mlp<true,false,0,false,true,1><<<GB_M,256,0,stream>>>(cbuf, nullptr, nullptr, W_m2, b_m2,
      nullptr, nullptr, f3, gWe+0*4288+192, gbe+0*64, cg, M_CL);

  // ---- cluster layer 0: f4 + cg1 ----
  k_edge_agg<<<GB_M,256,0,stream>>>(offs1, csr1, centers, cg, gWe+0*4288, cagg, M_CL);
  k_mlp<true,false,1,false,true,1><<<GB_M,256,0,stream>>>(cagg, nullptr, nullptr, gWu+0*4096, gbu+0*64,
      f3, nullptr, f4, gWe+1*4288+192, gbe+64, cg, M_CL);

  // ---- cluster layer 1: f4_1 ----
  k_edge_agg<<<GB_M,256,0,stream>>>(offs1, csr1, centers, cg, gWe+1*4288, cagg, M_CL);
  k_mlp<true,false,1,false,true,0><<<GB_M,256,0,stream>>>(cagg, nullptr, nullptr, gWu+1*4096, gbu+1*64,
      f4, nullptr, f41, nullptr, nullptr, nullptr, M_CL);

  // ---- f5 = relu([f4_1[labels], rel] @ W_l + b_l) + g2 ----
  k_mlp<true,true,0,true,true,1><<<GB_N,256,0,stream>>>(f41, labels, rel, W_l, b_l,
      nullptr, nullptr, buf0, mWe+2*4288+192, mbe+128, gbuf, N_PTS);

  // ---- mini layer 2: f6 = relu(agg@Wu2+bu2) + f5 + f2_1 ; g3 ----
  k_edge_agg<<<GB_N,256,0,stream>>>(offs0, csr0, points, gbuf, mWe+2*4288, abuf, N_PTS);
  k_mlp<true,false,2,false,true,1><<<GB_N,256,0,stream>>>(abuf, nullptr, nullptr, mWu+2*4096, mbu+2*64,
      buf0, buf2, buf3, mWe+3*4288+192, mbe+192, gbuf, N_PTS);

  // ---- mini layer 3 + classifier: out = (relu(agg@Wu3+bu3)+f6+f2) @ W_c + b_c ----
  k_edge_agg<<<GB_N,256,0,stream>>>(offs0, csr0, points, gbuf, mWe+3*4288, abuf, N_PTS);
  k_mlp<true,false,2,false,false,3><<<GB_N,256,0,stream>>>(abuf, nullptr, nullptr, mWu+3*4096, mbu+3*64,
      buf3, buf1, nullptr, W_c, b_c, out, N_PTS);
}

// Round 5
// 952.098 us; speedup vs baseline: 1.2881x; 1.2881x over previous
//
#include <hip/hip_runtime.h>

#define N_PTS   100000
#define M_CL    12500
#define E0_N    1600000
#define E1_N    400000

#define NB      128
#define BIN_CAP 48
#define RANGE0  782
#define RANGE1  98
#define BCAP0   16384
#define BCAP1   4096

typedef unsigned short ushortT;
typedef short  short8 __attribute__((ext_vector_type(8)));
typedef float  v4f    __attribute__((ext_vector_type(4)));

__device__ inline ushortT f2bf(float x){
  union{float f; unsigned u;} v; v.f = x;
  unsigned r = v.u + 0x7fffu + ((v.u >> 16) & 1u);   // RNE
  return (ushortT)(r >> 16);
}
__device__ inline float bf2f(ushortT h){
  union{unsigned u; float f;} v; v.u = ((unsigned)h) << 16;
  return v.f;
}

// ============================ bucketed CSR build ============================

__global__ void k_binit(int* c0, int* c1){
  int t = threadIdx.x;
  if (t < NB) c0[t] = t*BCAP0;
  else        c1[t-NB] = (t-NB)*BCAP1;
}

template<int RANGE>
__global__ __launch_bounds__(256) void k_bin(const int* __restrict__ edges, int E,
                                             int* __restrict__ bcur, unsigned* __restrict__ tmp){
  __shared__ unsigned stage[NB*BIN_CAP];
  __shared__ int scnt[NB];
  __shared__ int sbase[NB];
  int tid = threadIdx.x;
  int nchunks = (E + 2047) / 2048;
  for (int c = blockIdx.x; c < nchunks; c += gridDim.x){
    int base = c*2048;
    if (tid < NB) scnt[tid] = 0;
    __syncthreads();
    #pragma unroll
    for (int r=0;r<8;++r){
      int e = base + r*256 + tid;
      if (e < E){
        int s = edges[2*e], d = edges[2*e+1];
        int bk = d / RANGE;
        unsigned packed = ((unsigned)s << 11) | (unsigned)(d - bk*RANGE);
        int pos = atomicAdd(&scnt[bk], 1);
        if (pos < BIN_CAP) stage[bk*BIN_CAP+pos] = packed;
        else tmp[atomicAdd(&bcur[bk],1)] = packed;
      }
    }
    __syncthreads();
    if (tid < NB){
      int nfl = scnt[tid]; if (nfl > BIN_CAP) nfl = BIN_CAP;
      sbase[tid] = atomicAdd(&bcur[tid], nfl);
    }
    __syncthreads();
    int wv = tid >> 6, ln = tid & 63;
    for (int bb=0; bb<NB/4; ++bb){
      int bk = wv*(NB/4) + bb;
      int nfl = scnt[bk]; if (nfl > BIN_CAP) nfl = BIN_CAP;
      if (ln < nfl) tmp[sbase[bk]+ln] = stage[bk*BIN_CAP+ln];
    }
    __syncthreads();
  }
}

__global__ void k_scan_bases(const int* c0, int* bb0, int* off0e,
                             const int* c1, int* bb1, int* off1e){
  const int* cur = blockIdx.x ? c1 : c0;
  int* bb = blockIdx.x ? bb1 : bb0;
  int* offe = blockIdx.x ? off1e : off0e;
  int BC = blockIdx.x ? BCAP1 : BCAP0;
  int lane = threadIdx.x & 63;
  int v0 = cur[2*lane]   - (2*lane)*BC;
  int v1 = cur[2*lane+1] - (2*lane+1)*BC;
  int psum = v0 + v1, sc = psum;
  #pragma unroll
  for (int st=1; st<64; st<<=1){
    int x = __shfl_up(sc, st, 64);
    if (lane >= st) sc += x;
  }
  int ex = sc - psum;
  bb[2*lane] = ex; bb[2*lane+1] = ex + v0;
  if (lane == 63) *offe = sc;
}

template<int RANGE, int BCAP>
__global__ __launch_bounds__(256) void k_csr_build(const unsigned* __restrict__ tmp, const int* __restrict__ bcur,
                                                   const int* __restrict__ bb, int n,
                                                   int* __restrict__ offs, int* __restrict__ csr){
  constexpr int K = (RANGE + 255) / 256;
  __shared__ int hist[RANGE];
  __shared__ int part[256];
  int b = blockIdx.x, tid = threadIdx.x;
  int dlo = b*RANGE;
  int range = n - dlo; if (range > RANGE) range = RANGE; if (range < 0) range = 0;
  int cnt = bcur[b] - b*BCAP;
  for (int t=tid; t<RANGE; t+=256) hist[t] = 0;
  __syncthreads();
  const unsigned* sl = tmp + (size_t)b*BCAP;
  for (int j=tid; j<cnt; j+=256) atomicAdd(&hist[sl[j] & 2047u], 1);
  __syncthreads();
  int s = 0; int loc[K];
  #pragma unroll
  for (int kk=0; kk<K; ++kk){
    int idx = tid*K + kk;
    int v = (idx < RANGE) ? hist[idx] : 0;
    loc[kk] = s; s += v;
  }
  part[tid] = s; __syncthreads();
  int own = s;
  for (int st=1; st<256; st<<=1){
    int x = (tid >= st) ? part[tid-st] : 0;
    __syncthreads();
    part[tid] += x;
    __syncthreads();
  }
  int ebase = part[tid] - own;
  int gb = bb[b];
  __syncthreads();
  #pragma unroll
  for (int kk=0; kk<K; ++kk){
    int idx = tid*K + kk;
    if (idx < RANGE){
      int ex = ebase + loc[kk];
      if (idx < range) offs[dlo+idx] = gb + ex;
      hist[idx] = ex;
    }
  }
  __syncthreads();
  for (int j=tid; j<cnt; j+=256){
    unsigned p = sl[j];
    int pos = atomicAdd(&hist[p & 2047u], 1);
    csr[gb + pos] = (int)(p >> 11);
  }
}

// ============================ label CSR ============================

__global__ __launch_bounds__(256) void k_count_lab(const int* __restrict__ labels, int n, int* __restrict__ cnt){
  int i = blockIdx.x*256 + threadIdx.x;
  if (i < n) atomicAdd(&cnt[labels[i]], 1);
}

__global__ __launch_bounds__(256) void k_chunk_sum(const int* __restrict__ cnt, int n, int* __restrict__ part){
  __shared__ int sd[256];
  int t = threadIdx.x, base = blockIdx.x*2048;
  int s = 0;
  #pragma unroll
  for (int r=0;r<8;++r){ int i = base + t*8 + r; if (i<n) s += cnt[i]; }
  sd[t]=s; __syncthreads();
  for (int st=128; st>0; st>>=1){ if (t<st) sd[t]+=sd[t+st]; __syncthreads(); }
  if (t==0) part[blockIdx.x]=sd[0];
}

__global__ void k_scan_part(int* part, int B, int* offs, int n){
  int lane = threadIdx.x & 63;
  int v = (lane < B) ? part[lane] : 0;
  int orig = v;
  #pragma unroll
  for (int st=1; st<64; st<<=1){
    int x = __shfl_up(v, st, 64);
    if (lane >= st) v += x;
  }
  if (lane < B) part[lane] = v - orig;
  if (lane == 63) offs[n] = v;
}

__global__ __launch_bounds__(256) void k_chunk_scan(const int* __restrict__ cnt, int n,
                                                    const int* __restrict__ part, int* __restrict__ offs){
  __shared__ int sd[256];
  int t=threadIdx.x, base=blockIdx.x*2048;
  int v[8]; int s=0;
  #pragma unroll
  for (int r=0;r<8;++r){ int i=base+t*8+r; v[r] = (i<n)?cnt[i]:0; s+=v[r]; }
  sd[t]=s; __syncthreads();
  for (int st=1; st<256; st<<=1){
    int x = (t>=st)? sd[t-st] : 0;
    __syncthreads();
    sd[t]+=x;
    __syncthreads();
  }
  int acc = part[blockIdx.x] + sd[t] - s;
  #pragma unroll
  for (int r=0;r<8;++r){ int i=base+t*8+r; if (i<n) offs[i]=acc; acc+=v[r]; }
}

__global__ __launch_bounds__(256) void k_fill_lab(const int* __restrict__ labels, int n,
                                                  const int* __restrict__ offs, int* __restrict__ cur,
                                                  int* __restrict__ csr){
  int i = blockIdx.x*256 + threadIdx.x;
  if (i < n){
    int d = labels[i];
    int p = atomicAdd(&cur[d], 1);
    csr[offs[d]+p] = i;
  }
}

// ============================ weight prep: bf16 transposed copies ============================
// wt slot s (s<15): wt[s*4096 + n*64 + k] = bf16(src_s[k*64+n])   (64x64)
// slot 15: wtc[n*64+k] = n<8 ? bf16(W_c[k*8+n]) : 0               (16x64 padded)

struct WSrc { const float* p[16]; };

__global__ __launch_bounds__(256) void k_wprep(WSrc s, ushortT* __restrict__ wt, ushortT* __restrict__ wtc){
  int slot = blockIdx.x;
  if (slot < 15){
    const float* src = s.p[slot];
    ushortT* dst = wt + slot*4096;
    for (int e=threadIdx.x; e<4096; e+=256){
      int nn = e>>6, kk = e&63;
      dst[e] = f2bf(src[kk*64+nn]);
    }
  } else {
    const float* src = s.p[15];
    for (int e=threadIdx.x; e<1024; e+=256){
      int nn = e>>6, kk = e&63;
      wtc[e] = (nn<8) ? f2bf(src[kk*8+nn]) : (ushortT)0;
    }
  }
}

// ============================ feature encoder: rel + f1 (fp32 + bf16) ============================

__global__ __launch_bounds__(256) void k_f1(const float* __restrict__ features, const float* __restrict__ points,
                                            const float* __restrict__ centers, const int* __restrict__ labels,
                                            const float* __restrict__ W, const float* __restrict__ b,
                                            float* __restrict__ rel, float* __restrict__ f1,
                                            ushortT* __restrict__ f1b, int n){
  int lane = threadIdx.x & 63;
  int gw = (blockIdx.x*256 + threadIdx.x) >> 6;
  int nw = (gridDim.x*256) >> 6;
  float Wf0=W[0*64+lane], Wf1=W[1*64+lane], Wf2=W[2*64+lane], Wf3=W[3*64+lane];
  float wr0=W[4*64+lane], wr1=W[5*64+lane], wr2=W[6*64+lane];
  float bias=b[lane];
  for (int i=gw; i<n; i+=nw){
    int lb = labels[i];
    float rx = points[i*3+0]-centers[lb*3+0];
    float ry = points[i*3+1]-centers[lb*3+1];
    float rz = points[i*3+2]-centers[lb*3+2];
    if (lane==0){ rel[i*3+0]=rx; rel[i*3+1]=ry; rel[i*3+2]=rz; }
    float acc = bias + wr0*rx + wr1*ry + wr2*rz;
    acc += features[i*4+0]*Wf0 + features[i*4+1]*Wf1;
    acc += features[i*4+2]*Wf2 + features[i*4+3]*Wf3;
    acc = fmaxf(acc, 0.f);
    f1[(size_t)i*64+lane] = acc;
    f1b[(size_t)i*64+lane] = f2bf(acc);
  }
}

// ============================ MFMA GEMM: out[rows x 64] = act(A_bf16 @ W + b) (+rel) (+res) ============================
// A: bf16 row-major [n x 64]; Wt: bf16 [n_out=64][k=64] (transposed); per-wave 16x64 strip.
// Layouts (gfx950 mfma_f32_16x16x32_bf16, HW-verified): A[m=lane&15][k=quad*8+j],
// B[k=quad*8+j][n=lane&15], C/D[row=quad*4+reg][col=lane&15].

template<bool RELU, int NRES, bool USEREL, bool GATHER, bool OUT32, bool OUT16, bool R2BF>
__global__ __launch_bounds__(256) void k_gemm(
    const ushortT* __restrict__ A, const ushortT* __restrict__ Wt,
    const float* __restrict__ bias, const float* __restrict__ Wr,
    const float* __restrict__ rel, const int* __restrict__ gidx,
    const float* __restrict__ r1, const void* __restrict__ r2,
    float* __restrict__ out32, ushortT* __restrict__ out16,
    int n, int ntiles)
{
  int lane = threadIdx.x & 63;
  int quad = lane >> 4, l15 = lane & 15;
  int gw = (blockIdx.x*256 + threadIdx.x) >> 6;
  int nw = (gridDim.x*256) >> 6;

  short8 bfr0_0 = *(const short8*)(Wt + ( 0 + l15)*64 +  0 + quad*8);
  short8 bfr0_1 = *(const short8*)(Wt + ( 0 + l15)*64 + 32 + quad*8);
  short8 bfr1_0 = *(const short8*)(Wt + (16 + l15)*64 +  0 + quad*8);
  short8 bfr1_1 = *(const short8*)(Wt + (16 + l15)*64 + 32 + quad*8);
  short8 bfr2_0 = *(const short8*)(Wt + (32 + l15)*64 +  0 + quad*8);
  short8 bfr2_1 = *(const short8*)(Wt + (32 + l15)*64 + 32 + quad*8);
  short8 bfr3_0 = *(const short8*)(Wt + (48 + l15)*64 +  0 + quad*8);
  short8 bfr3_1 = *(const short8*)(Wt + (48 + l15)*64 + 32 + quad*8);
  float bs0 = bias[ 0 + l15], bs1 = bias[16 + l15];
  float bs2 = bias[32 + l15], bs3 = bias[48 + l15];
  float w0c0=0,w0c1=0,w0c2=0,w0c3=0, w1c0=0,w1c1=0,w1c2=0,w1c3=0, w2c0=0,w2c1=0,w2c2=0,w2c3=0;
  if (USEREL){
    w0c0=Wr[0*64+l15]; w0c1=Wr[0*64+16+l15]; w0c2=Wr[0*64+32+l15]; w0c3=Wr[0*64+48+l15];
    w1c0=Wr[1*64+l15]; w1c1=Wr[1*64+16+l15]; w1c2=Wr[1*64+32+l15]; w1c3=Wr[1*64+48+l15];
    w2c0=Wr[2*64+l15]; w2c1=Wr[2*64+16+l15]; w2c2=Wr[2*64+32+l15]; w2c3=Wr[2*64+48+l15];
  }

  for (int t=gw; t<ntiles; t+=nw){
    int i0 = t*16;
    int rowA = i0 + l15; if (rowA >= n) rowA = n-1;
    if (GATHER) rowA = gidx[rowA];
    const ushortT* ap = A + (size_t)rowA*64 + quad*8;
    short8 a0 = *(const short8*)(ap);
    short8 a1 = *(const short8*)(ap + 32);
    v4f ac0 = {0.f,0.f,0.f,0.f}, ac1 = ac0, ac2 = ac0, ac3 = ac0;
    ac0 = __builtin_amdgcn_mfma_f32_16x16x32_bf16(a0, bfr0_0, ac0, 0,0,0);
    ac1 = __builtin_amdgcn_mfma_f32_16x16x32_bf16(a0, bfr1_0, ac1, 0,0,0);
    ac2 = __builtin_amdgcn_mfma_f32_16x16x32_bf16(a0, bfr2_0, ac2, 0,0,0);
    ac3 = __builtin_amdgcn_mfma_f32_16x16x32_bf16(a0, bfr3_0, ac3, 0,0,0);
    ac0 = __builtin_amdgcn_mfma_f32_16x16x32_bf16(a1, bfr0_1, ac0, 0,0,0);
    ac1 = __builtin_amdgcn_mfma_f32_16x16x32_bf16(a1, bfr1_1, ac1, 0,0,0);
    ac2 = __builtin_amdgcn_mfma_f32_16x16x32_bf16(a1, bfr2_1, ac2, 0,0,0);
    ac3 = __builtin_amdgcn_mfma_f32_16x16x32_bf16(a1, bfr3_1, ac3, 0,0,0);

    #pragma unroll
    for (int r=0;r<4;++r){
      int row = i0 + quad*4 + r;
      bool rowok = (row < n);
      float rx=0.f, ry=0.f, rz=0.f;
      if (USEREL && rowok){ rx=rel[row*3+0]; ry=rel[row*3+1]; rz=rel[row*3+2]; }
      float v0 = ac0[r] + bs0, v1 = ac1[r] + bs1, v2 = ac2[r] + bs2, v3 = ac3[r] + bs3;
      if (USEREL){
        v0 += rx*w0c0 + ry*w1c0 + rz*w2c0;
        v1 += rx*w0c1 + ry*w1c1 + rz*w2c1;
        v2 += rx*w0c2 + ry*w1c2 + rz*w2c2;
        v3 += rx*w0c3 + ry*w1c3 + rz*w2c3;
      }
      if (RELU){ v0=fmaxf(v0,0.f); v1=fmaxf(v1,0.f); v2=fmaxf(v2,0.f); v3=fmaxf(v3,0.f); }
      size_t base = (size_t)row*64 + l15;
      if (rowok){
        if (NRES>=1){
          v0 += r1[base]; v1 += r1[base+16]; v2 += r1[base+32]; v3 += r1[base+48];
        }
        if (NRES>=2){
          if (R2BF){
            const ushortT* rr = (const ushortT*)r2;
            v0 += bf2f(rr[base]); v1 += bf2f(rr[base+16]); v2 += bf2f(rr[base+32]); v3 += bf2f(rr[base+48]);
          } else {
            const float* rr = (const float*)r2;
            v0 += rr[base]; v1 += rr[base+16]; v2 += rr[base+32]; v3 += rr[base+48];
          }
        }
        if (OUT32){
          out32[base] = v0; out32[base+16] = v1; out32[base+32] = v2; out32[base+48] = v3;
        }
        if (OUT16){
          out16[base] = f2bf(v0); out16[base+16] = f2bf(v1); out16[base+32] = f2bf(v2); out16[base+48] = f2bf(v3);
        }
      }
    }
  }
}

// ============================ classifier: out[n x 8] = A_bf16 @ Wc + bc ============================

__global__ __launch_bounds__(256) void k_cls(const ushortT* __restrict__ A, const ushortT* __restrict__ wtc,
                                             const float* __restrict__ bc, float* __restrict__ out,
                                             int n, int ntiles){
  int lane = threadIdx.x & 63;
  int quad = lane >> 4, l15 = lane & 15;
  int gw = (blockIdx.x*256 + threadIdx.x) >> 6;
  int nw = (gridDim.x*256) >> 6;
  short8 b0 = *(const short8*)(wtc + l15*64 +  0 + quad*8);
  short8 b1 = *(const short8*)(wtc + l15*64 + 32 + quad*8);
  float bias = (l15 < 8) ? bc[l15] : 0.f;
  for (int t=gw; t<ntiles; t+=nw){
    int i0 = t*16;
    int rowA = i0 + l15; if (rowA >= n) rowA = n-1;
    const ushortT* ap = A + (size_t)rowA*64 + quad*8;
    short8 a0 = *(const short8*)(ap);
    short8 a1 = *(const short8*)(ap + 32);
    v4f acc = {0.f,0.f,0.f,0.f};
    acc = __builtin_amdgcn_mfma_f32_16x16x32_bf16(a0, b0, acc, 0,0,0);
    acc = __builtin_amdgcn_mfma_f32_16x16x32_bf16(a1, b1, acc, 0,0,0);
    if (l15 < 8){
      #pragma unroll
      for (int r=0;r<4;++r){
        int row = i0 + quad*4 + r;
        if (row < n) out[(size_t)row*8 + l15] = acc[r] + bias;
      }
    }
  }
}

// ============================ edge aggregation (bf16 in, bf16 out) ============================

__global__ __launch_bounds__(256) void k_edge_agg(const int* __restrict__ offs, const int* __restrict__ csr,
                                                  const float* __restrict__ pos, const ushortT* __restrict__ g,
                                                  const float* __restrict__ Wp, ushortT* __restrict__ agg, int n){
  int lane = threadIdx.x & 63;
  int gw = (blockIdx.x*256 + threadIdx.x) >> 6;
  int nw = (gridDim.x*256) >> 6;
  float w0 = Wp[0*64+lane], w1 = Wp[1*64+lane], w2 = Wp[2*64+lane];
  for (int i=gw; i<n; i+=nw){
    int b = offs[i], e = offs[i+1];
    float px = pos[i*3+0], py = pos[i*3+1], pz = pos[i*3+2];
    float m0=0.f, m1=0.f, m2=0.f, m3=0.f;
    int k = b;
    for (; k+4<=e; k+=4){
      int s0=csr[k+0], s1=csr[k+1], s2=csr[k+2], s3=csr[k+3];
      const float* p0=pos+3*s0; const float* p1=pos+3*s1;
      const float* p2=pos+3*s2; const float* p3=pos+3*s3;
      float g0=bf2f(g[(size_t)s0*64+lane]);
      float g1=bf2f(g[(size_t)s1*64+lane]);
      float g2=bf2f(g[(size_t)s2*64+lane]);
      float g3=bf2f(g[(size_t)s3*64+lane]);
      m0=fmaxf(m0, g0 + w0*(p0[0]-px) + w1*(p0[1]-py) + w2*(p0[2]-pz));
      m1=fmaxf(m1, g1 + w0*(p1[0]-px) + w1*(p1[1]-py) + w2*(p1[2]-pz));
      m2=fmaxf(m2, g2 + w0*(p2[0]-px) + w1*(p2[1]-py) + w2*(p2[2]-pz));
      m3=fmaxf(m3, g3 + w0*(p3[0]-px) + w1*(p3[1]-py) + w2*(p3[2]-pz));
    }
    for (; k<e; ++k){
      int s=csr[k];
      m0=fmaxf(m0, bf2f(g[(size_t)s*64+lane]) + w0*(pos[3*s]-px) + w1*(pos[3*s+1]-py) + w2*(pos[3*s+2]-pz));
    }
    agg[(size_t)i*64+lane] = f2bf(fmaxf(fmaxf(m0,m1),fmaxf(m2,m3)));
  }
}

// ============================ segment sum via label CSR ============================

__global__ __launch_bounds__(256) void k_seg_gather(const int* __restrict__ offs, const int* __restrict__ csr,
                                                    const ushortT* __restrict__ h, ushortT* __restrict__ c, int m){
  int lane = threadIdx.x & 63;
  int wv = (blockIdx.x*256 + threadIdx.x) >> 6;
  if (wv >= m) return;
  int b = offs[wv], e = offs[wv+1];
  float acc = 0.f;
  for (int k=b; k<e; ++k){
    int i = csr[k];
    acc += bf2f(h[(size_t)i*64+lane]);
  }
  c[(size_t)wv*64+lane] = f2bf(acc);
}

// ============================ host launcher ============================

extern "C" void kernel_launch(void* const* d_in, const int* in_sizes, int n_in,
                              void* d_out, int out_size, void* d_ws, size_t ws_size,
                              hipStream_t stream){
  const float* features = (const float*)d_in[0];
  const float* points   = (const float*)d_in[1];
  const float* centers  = (const float*)d_in[2];
  const int*   l0e      = (const int*)d_in[3];
  const int*   l1e      = (const int*)d_in[4];
  const int*   labels   = (const int*)d_in[5];
  const float* W_fe = (const float*)d_in[6];
  const float* b_fe = (const float*)d_in[7];
  const float* mWe  = (const float*)d_in[8];   // (4,67,64)
  const float* mbe  = (const float*)d_in[9];
  const float* mWu  = (const float*)d_in[10];  // (4,64,64)
  const float* mbu  = (const float*)d_in[11];
  const float* W_m1 = (const float*)d_in[12];
  const float* b_m1 = (const float*)d_in[13];
  const float* W_m2 = (const float*)d_in[14];
  const float* b_m2 = (const float*)d_in[15];
  const float* gWe  = (const float*)d_in[16];  // (2,67,64)
  const float* gbe  = (const float*)d_in[17];
  const float* gWu  = (const float*)d_in[18];
  const float* gbu  = (const float*)d_in[19];
  const float* W_l  = (const float*)d_in[20];
  const float* b_l  = (const float*)d_in[21];
  const float* W_c  = (const float*)d_in[22];
  const float* b_c  = (const float*)d_in[23];
  float* out = (float*)d_out;

  char* w = (char*)d_ws;
  size_t off = 0;
  auto alloc = [&](size_t bytes)->void*{
    void* p = (void*)(w + off);
    off = (off + bytes + 255) & ~(size_t)255;
    return p;
  };
  float* rel  = (float*)alloc((size_t)N_PTS*3*4);
  float* B0 = (float*)alloc((size_t)N_PTS*64*4);   // f1 -> f5 (fp32 residual)
  float* B1 = (float*)alloc((size_t)N_PTS*64*4);   // f2
  float* B3 = (float*)alloc((size_t)N_PTS*64*4);   // f6
  ushortT* U0 = (ushortT*)alloc((size_t)N_PTS*64*2); // f1b -> f21b
  ushortT* U1 = (ushortT*)alloc((size_t)N_PTS*64*2); // f2b -> f5b
  ushortT* U2 = (ushortT*)alloc((size_t)N_PTS*64*2); // f6b -> finalb
  ushortT* gbuf = (ushortT*)alloc((size_t)N_PTS*64*2);
  ushortT* abuf = (ushortT*)alloc((size_t)N_PTS*64*2);
  ushortT* cb_b = (ushortT*)alloc((size_t)M_CL*64*2);
  float* f3_32  = (float*)alloc((size_t)M_CL*64*4);
  ushortT* f3_b = (ushortT*)alloc((size_t)M_CL*64*2);
  ushortT* cg_b = (ushortT*)alloc((size_t)M_CL*64*2);
  ushortT* cagg_b = (ushortT*)alloc((size_t)M_CL*64*2);
  float* f4_32  = (float*)alloc((size_t)M_CL*64*4);
  ushortT* f4_b = (ushortT*)alloc((size_t)M_CL*64*2);
  ushortT* f41_b = (ushortT*)alloc((size_t)M_CL*64*2);
  ushortT* wt  = (ushortT*)alloc((size_t)15*4096*2);
  ushortT* wtc = (ushortT*)alloc((size_t)1024*2);
  int* offs0 = (int*)alloc((size_t)(N_PTS+1)*4);
  int* csr0  = (int*)alloc((size_t)E0_N*4);
  int* offs1 = (int*)alloc((size_t)(M_CL+1)*4);
  int* csr1  = (int*)alloc((size_t)E1_N*4);
  unsigned* tmp0 = (unsigned*)alloc((size_t)NB*BCAP0*4);
  unsigned* tmp1 = (unsigned*)alloc((size_t)NB*BCAP1*4);
  int* bcur0 = (int*)alloc(NB*4);
  int* bcur1 = (int*)alloc(NB*4);
  int* bb0   = (int*)alloc(NB*4);
  int* bb1   = (int*)alloc(NB*4);
  char* zbase = (char*)alloc(0);
  int* cntL = (int*)alloc((size_t)M_CL*4);
  int* curL = (int*)alloc((size_t)M_CL*4);
  size_t zbytes = (size_t)((char*)(w+off) - zbase);
  int* offsL = (int*)alloc((size_t)(M_CL+1)*4);
  int* csrL  = (int*)alloc((size_t)N_PTS*4);
  int* partL = (int*)alloc(64*4);
  (void)ws_size; (void)in_sizes; (void)n_in; (void)out_size;

  const int NT_N = (N_PTS+15)/16;   // 6250
  const int NT_M = (M_CL +15)/16;   // 782
  const int GBG_N = 1563;           // 6252 waves
  const int GBG_M = 196;            // 784 waves
  const int GB_N  = 2048;           // edge_agg grid

  hipMemsetAsync(zbase, 0, zbytes, stream);

  // ---- CSR builds ----
  k_binit<<<1, 256, 0, stream>>>(bcur0, bcur1);
  k_bin<RANGE0><<<256, 256, 0, stream>>>(l0e, E0_N, bcur0, tmp0);
  k_bin<RANGE1><<<196, 256, 0, stream>>>(l1e, E1_N, bcur1, tmp1);
  k_scan_bases<<<2, 64, 0, stream>>>(bcur0, bb0, offs0+N_PTS, bcur1, bb1, offs1+M_CL);
  k_csr_build<RANGE0,BCAP0><<<NB, 256, 0, stream>>>(tmp0, bcur0, bb0, N_PTS, offs0, csr0);
  k_csr_build<RANGE1,BCAP1><<<NB, 256, 0, stream>>>(tmp1, bcur1, bb1, M_CL, offs1, csr1);

  // ---- label CSR ----
  k_count_lab<<<(N_PTS+255)/256, 256, 0, stream>>>(labels, N_PTS, cntL);
  k_chunk_sum<<<7, 256, 0, stream>>>(cntL, M_CL, partL);
  k_scan_part<<<1, 64, 0, stream>>>(partL, 7, offsL, M_CL);
  k_chunk_scan<<<7, 256, 0, stream>>>(cntL, M_CL, partL, offsL);
  k_fill_lab<<<(N_PTS+255)/256, 256, 0, stream>>>(labels, N_PTS, offsL, curL, csrL);

  // ---- weight prep ----
  WSrc ws{};
  ws.p[0]=mWu+0*4096; ws.p[1]=mWu+1*4096; ws.p[2]=mWu+2*4096; ws.p[3]=mWu+3*4096;
  ws.p[4]=W_m2; ws.p[5]=gWu+0*4096; ws.p[6]=gWu+1*4096;
  ws.p[7]=mWe+0*4288+192; ws.p[8]=mWe+1*4288+192; ws.p[9]=mWe+2*4288+192; ws.p[10]=mWe+3*4288+192;
  ws.p[11]=W_m1; ws.p[12]=W_l; ws.p[13]=gWe+0*4288+192; ws.p[14]=gWe+1*4288+192;
  ws.p[15]=W_c;
  k_wprep<<<16, 256, 0, stream>>>(ws, wt, wtc);

  // ---- encoder ----
  k_f1<<<GB_N, 256, 0, stream>>>(features, points, centers, labels, W_fe, b_fe, rel, B0, U0, N_PTS);

  // ---- g0 = f1 @ mWe0 + be0 ----
  k_gemm<false,0,false,false,false,true,false><<<GBG_N,256,0,stream>>>(U0, wt+7*4096, mbe+0,
      nullptr, nullptr, nullptr, nullptr, nullptr, nullptr, gbuf, N_PTS, NT_N);
  // ---- layer0: agg -> f2 = relu(.@Wu0+bu0)+f1 ----
  k_edge_agg<<<GB_N,256,0,stream>>>(offs0, csr0, points, gbuf, mWe+0*4288, abuf, N_PTS);
  k_gemm<true,1,false,false,true,true,false><<<GBG_N,256,0,stream>>>(abuf, wt+0*4096, mbu+0,
      nullptr, nullptr, nullptr, B0, nullptr, B1, U1, N_PTS, NT_N);
  // ---- g1 = f2 @ mWe1 + be1 ----
  k_gemm<false,0,false,false,false,true,false><<<GBG_N,256,0,stream>>>(U1, wt+8*4096, mbe+64,
      nullptr, nullptr, nullptr, nullptr, nullptr, nullptr, gbuf, N_PTS, NT_N);
  // ---- layer1: f2_1 (bf16 only, into U0) ----
  k_edge_agg<<<GB_N,256,0,stream>>>(offs0, csr0, points, gbuf, mWe+1*4288, abuf, N_PTS);
  k_gemm<true,1,false,false,false,true,false><<<GBG_N,256,0,stream>>>(abuf, wt+1*4096, mbu+64,
      nullptr, nullptr, nullptr, B1, nullptr, nullptr, U0, N_PTS, NT_N);
  // ---- h = relu(f2_1@W_m1 + rel@W_m1[64:] + b_m1) -> gbuf ----
  k_gemm<true,0,true,false,false,true,false><<<GBG_N,256,0,stream>>>(U0, wt+11*4096, b_m1,
      W_m1+4096, rel, nullptr, nullptr, nullptr, nullptr, gbuf, N_PTS, NT_N);
  // ---- c = segsum(h); f3 = relu(c@W_m2+b_m2) ----
  k_seg_gather<<<(M_CL*64+255)/256, 256, 0, stream>>>(offsL, csrL, gbuf, cb_b, M_CL);
  k_gemm<true,0,false,false,true,true,false><<<GBG_M,256,0,stream>>>(cb_b, wt+4*4096, b_m2,
      nullptr, nullptr, nullptr, nullptr, nullptr, f3_32, f3_b, M_CL, NT_M);
  // ---- cluster layer0 ----
  k_gemm<false,0,false,false,false,true,false><<<GBG_M,256,0,stream>>>(f3_b, wt+13*4096, gbe+0,
      nullptr, nullptr, nullptr, nullptr, nullptr, nullptr, cg_b, M_CL, NT_M);
  k_edge_agg<<<GBG_M,256,0,stream>>>(offs1, csr1, centers, cg_b, gWe+0*4288, cagg_b, M_CL);
  k_gemm<true,1,false,false,true,true,false><<<GBG_M,256,0,stream>>>(cagg_b, wt+5*4096, gbu+0,
      nullptr, nullptr, nullptr, f3_32, nullptr, f4_32, f4_b, M_CL, NT_M);
  // ---- cluster layer1 ----
  k_gemm<false,0,false,false,false,true,false><<<GBG_M,256,0,stream>>>(f4_b, wt+14*4096, gbe+64,
      nullptr, nullptr, nullptr, nullptr, nullptr, nullptr, cg_b, M_CL, NT_M);
  k_edge_agg<<<GBG_M,256,0,stream>>>(offs1, csr1, centers, cg_b, gWe+1*4288, cagg_b, M_CL);
  k_gemm<true,1,false,false,false,true,false><<<GBG_M,256,0,stream>>>(cagg_b, wt+6*4096, gbu+64,
      nullptr, nullptr, nullptr, f4_32, nullptr, nullptr, f41_b, M_CL, NT_M);
  // ---- f5 = relu(f41[labels]@W_l + rel@W_l[64:] + b_l) -> B0 fp32 + U1 bf16 ----
  k_gemm<true,0,true,true,true,true,false><<<GBG_N,256,0,stream>>>(f41_b, wt+12*4096, b_l,
      W_l+4096, rel, labels, nullptr, nullptr, B0, U1, N_PTS, NT_N);
  // ---- g2 = f5 @ mWe2 + be2 ----
  k_gemm<false,0,false,false,false,true,false><<<GBG_N,256,0,stream>>>(U1, wt+9*4096, mbe+128,
      nullptr, nullptr, nullptr, nullptr, nullptr, nullptr, gbuf, N_PTS, NT_N);
  // ---- layer2: f6 = relu(.@Wu2+bu2)+f5+f2_1(bf16) ----
  k_edge_agg<<<GB_N,256,0,stream>>>(offs0, csr0, points, gbuf, mWe+2*4288, abuf, N_PTS);
  k_gemm<true,2,false,false,true,true,true><<<GBG_N,256,0,stream>>>(abuf, wt+2*4096, mbu+128,
      nullptr, nullptr, nullptr, B0, U0, B3, U2, N_PTS, NT_N);
  // ---- g3 = f6 @ mWe3 + be3 ----
  k_gemm<false,0,false,false,false,true,false><<<GBG_N,256,0,stream>>>(U2, wt+10*4096, mbe+192,
      nullptr, nullptr, nullptr, nullptr, nullptr, nullptr, gbuf, N_PTS, NT_N);
  // ---- layer3: final = relu(.@Wu3+bu3)+f6+f2 -> U2 bf16 ----
  k_edge_agg<<<GB_N,256,0,stream>>>(offs0, csr0, points, gbuf, mWe+3*4288, abuf, N_PTS);
  k_gemm<true,2,false,false,false,true,false><<<GBG_N,256,0,stream>>>(abuf, wt+3*4096, mbu+192,
      nullptr, nullptr, nullptr, B3, B1, nullptr, U2, N_PTS, NT_N);
  // ---- out = final @ W_c + b_c ----
  k_cls<<<GBG_N,256,0,stream>>>(U2, wtc, b_c, out, N_PTS, NT_N);
}

// Round 6
// 733.862 us; speedup vs baseline: 1.6711x; 1.2974x over previous
//
#include <hip/hip_runtime.h>

#define N_PTS   100000
#define M_CL    12500
#define E0_N    1600000
#define E1_N    400000

#define NB      128
#define BIN_CAP 48
#define RANGE0  782
#define RANGE1  98
#define BCAP0   16384
#define BCAP1   4096

typedef unsigned short ushortT;
typedef short  short8 __attribute__((ext_vector_type(8)));
typedef float  v4f    __attribute__((ext_vector_type(4)));

__device__ inline ushortT f2bf(float x){
  union{float f; unsigned u;} v; v.f = x;
  unsigned r = v.u + 0x7fffu + ((v.u >> 16) & 1u);   // RNE
  return (ushortT)(r >> 16);
}
__device__ inline float bf2f(ushortT h){
  union{unsigned u; float f;} v; v.u = ((unsigned)h) << 16;
  return v.f;
}

// ============================ bucketed CSR build ============================

__global__ void k_binit(int* c0, int* c1){
  int t = threadIdx.x;
  if (t < NB) c0[t] = t*BCAP0;
  else        c1[t-NB] = (t-NB)*BCAP1;
}

template<int RANGE>
__global__ __launch_bounds__(256) void k_bin(const int* __restrict__ edges, int E,
                                             int* __restrict__ bcur, unsigned* __restrict__ tmp){
  __shared__ unsigned stage[NB*BIN_CAP];
  __shared__ int scnt[NB];
  __shared__ int sbase[NB];
  int tid = threadIdx.x;
  int nchunks = (E + 2047) / 2048;
  for (int c = blockIdx.x; c < nchunks; c += gridDim.x){
    int base = c*2048;
    if (tid < NB) scnt[tid] = 0;
    __syncthreads();
    #pragma unroll
    for (int r=0;r<8;++r){
      int e = base + r*256 + tid;
      if (e < E){
        int s = edges[2*e], d = edges[2*e+1];
        int bk = d / RANGE;
        unsigned packed = ((unsigned)s << 11) | (unsigned)(d - bk*RANGE);
        int pos = atomicAdd(&scnt[bk], 1);
        if (pos < BIN_CAP) stage[bk*BIN_CAP+pos] = packed;
        else tmp[atomicAdd(&bcur[bk],1)] = packed;
      }
    }
    __syncthreads();
    if (tid < NB){
      int nfl = scnt[tid]; if (nfl > BIN_CAP) nfl = BIN_CAP;
      sbase[tid] = atomicAdd(&bcur[tid], nfl);
    }
    __syncthreads();
    int wv = tid >> 6, ln = tid & 63;
    for (int bb=0; bb<NB/4; ++bb){
      int bk = wv*(NB/4) + bb;
      int nfl = scnt[bk]; if (nfl > BIN_CAP) nfl = BIN_CAP;
      if (ln < nfl) tmp[sbase[bk]+ln] = stage[bk*BIN_CAP+ln];
    }
    __syncthreads();
  }
}

__global__ void k_scan_bases(const int* c0, int* bb0, int* off0e,
                             const int* c1, int* bb1, int* off1e){
  const int* cur = blockIdx.x ? c1 : c0;
  int* bb = blockIdx.x ? bb1 : bb0;
  int* offe = blockIdx.x ? off1e : off0e;
  int BC = blockIdx.x ? BCAP1 : BCAP0;
  int lane = threadIdx.x & 63;
  int v0 = cur[2*lane]   - (2*lane)*BC;
  int v1 = cur[2*lane+1] - (2*lane+1)*BC;
  int psum = v0 + v1, sc = psum;
  #pragma unroll
  for (int st=1; st<64; st<<=1){
    int x = __shfl_up(sc, st, 64);
    if (lane >= st) sc += x;
  }
  int ex = sc - psum;
  bb[2*lane] = ex; bb[2*lane+1] = ex + v0;
  if (lane == 63) *offe = sc;
}

template<int RANGE, int BCAP>
__global__ __launch_bounds__(256) void k_csr_build(const unsigned* __restrict__ tmp, const int* __restrict__ bcur,
                                                   const int* __restrict__ bb, int n,
                                                   int* __restrict__ offs, int* __restrict__ csr){
  constexpr int K = (RANGE + 255) / 256;
  __shared__ int hist[RANGE];
  __shared__ int part[256];
  int b = blockIdx.x, tid = threadIdx.x;
  int dlo = b*RANGE;
  int range = n - dlo; if (range > RANGE) range = RANGE; if (range < 0) range = 0;
  int cnt = bcur[b] - b*BCAP;
  for (int t=tid; t<RANGE; t+=256) hist[t] = 0;
  __syncthreads();
  const unsigned* sl = tmp + (size_t)b*BCAP;
  for (int j=tid; j<cnt; j+=256) atomicAdd(&hist[sl[j] & 2047u], 1);
  __syncthreads();
  int s = 0; int loc[K];
  #pragma unroll
  for (int kk=0; kk<K; ++kk){
    int idx = tid*K + kk;
    int v = (idx < RANGE) ? hist[idx] : 0;
    loc[kk] = s; s += v;
  }
  part[tid] = s; __syncthreads();
  int own = s;
  for (int st=1; st<256; st<<=1){
    int x = (tid >= st) ? part[tid-st] : 0;
    __syncthreads();
    part[tid] += x;
    __syncthreads();
  }
  int ebase = part[tid] - own;
  int gb = bb[b];
  __syncthreads();
  #pragma unroll
  for (int kk=0; kk<K; ++kk){
    int idx = tid*K + kk;
    if (idx < RANGE){
      int ex = ebase + loc[kk];
      if (idx < range) offs[dlo+idx] = gb + ex;
      hist[idx] = ex;
    }
  }
  __syncthreads();
  for (int j=tid; j<cnt; j+=256){
    unsigned p = sl[j];
    int pos = atomicAdd(&hist[p & 2047u], 1);
    csr[gb + pos] = (int)(p >> 11);
  }
}

// ============================ label CSR ============================

__global__ __launch_bounds__(256) void k_count_lab(const int* __restrict__ labels, int n, int* __restrict__ cnt){
  int i = blockIdx.x*256 + threadIdx.x;
  if (i < n) atomicAdd(&cnt[labels[i]], 1);
}

__global__ __launch_bounds__(256) void k_chunk_sum(const int* __restrict__ cnt, int n, int* __restrict__ part){
  __shared__ int sd[256];
  int t = threadIdx.x, base = blockIdx.x*2048;
  int s = 0;
  #pragma unroll
  for (int r=0;r<8;++r){ int i = base + t*8 + r; if (i<n) s += cnt[i]; }
  sd[t]=s; __syncthreads();
  for (int st=128; st>0; st>>=1){ if (t<st) sd[t]+=sd[t+st]; __syncthreads(); }
  if (t==0) part[blockIdx.x]=sd[0];
}

__global__ void k_scan_part(int* part, int B, int* offs, int n){
  int lane = threadIdx.x & 63;
  int v = (lane < B) ? part[lane] : 0;
  int orig = v;
  #pragma unroll
  for (int st=1; st<64; st<<=1){
    int x = __shfl_up(v, st, 64);
    if (lane >= st) v += x;
  }
  if (lane < B) part[lane] = v - orig;
  if (lane == 63) offs[n] = v;
}

__global__ __launch_bounds__(256) void k_chunk_scan(const int* __restrict__ cnt, int n,
                                                    const int* __restrict__ part, int* __restrict__ offs){
  __shared__ int sd[256];
  int t=threadIdx.x, base=blockIdx.x*2048;
  int v[8]; int s=0;
  #pragma unroll
  for (int r=0;r<8;++r){ int i=base+t*8+r; v[r] = (i<n)?cnt[i]:0; s+=v[r]; }
  sd[t]=s; __syncthreads();
  for (int st=1; st<256; st<<=1){
    int x = (t>=st)? sd[t-st] : 0;
    __syncthreads();
    sd[t]+=x;
    __syncthreads();
  }
  int acc = part[blockIdx.x] + sd[t] - s;
  #pragma unroll
  for (int r=0;r<8;++r){ int i=base+t*8+r; if (i<n) offs[i]=acc; acc+=v[r]; }
}

__global__ __launch_bounds__(256) void k_fill_lab(const int* __restrict__ labels, int n,
                                                  const int* __restrict__ offs, int* __restrict__ cur,
                                                  int* __restrict__ csr){
  int i = blockIdx.x*256 + threadIdx.x;
  if (i < n){
    int d = labels[i];
    int p = atomicAdd(&cur[d], 1);
    csr[offs[d]+p] = i;
  }
}

// ============================ weight prep ============================

struct WSrc { const float* p[16]; };

__global__ __launch_bounds__(256) void k_wprep(WSrc s, ushortT* __restrict__ wt, ushortT* __restrict__ wtc){
  int slot = blockIdx.x;
  if (slot < 15){
    const float* src = s.p[slot];
    ushortT* dst = wt + slot*4096;
    for (int e=threadIdx.x; e<4096; e+=256){
      int nn = e>>6, kk = e&63;
      dst[e] = f2bf(src[kk*64+nn]);
    }
  } else {
    const float* src = s.p[15];
    for (int e=threadIdx.x; e<1024; e+=256){
      int nn = e>>6, kk = e&63;
      wtc[e] = (nn<8) ? f2bf(src[kk*8+nn]) : (ushortT)0;
    }
  }
}

// ============================ feature encoder: rel + f1 (fp32 + bf16) ============================

__global__ __launch_bounds__(256) void k_f1(const float* __restrict__ features, const float* __restrict__ points,
                                            const float* __restrict__ centers, const int* __restrict__ labels,
                                            const float* __restrict__ W, const float* __restrict__ b,
                                            float* __restrict__ rel, float* __restrict__ f1,
                                            ushortT* __restrict__ f1b, int n){
  int lane = threadIdx.x & 63;
  int gw = (blockIdx.x*256 + threadIdx.x) >> 6;
  int nw = (gridDim.x*256) >> 6;
  float Wf0=W[0*64+lane], Wf1=W[1*64+lane], Wf2=W[2*64+lane], Wf3=W[3*64+lane];
  float wr0=W[4*64+lane], wr1=W[5*64+lane], wr2=W[6*64+lane];
  float bias=b[lane];
  for (int i=gw; i<n; i+=nw){
    int lb = labels[i];
    float rx = points[i*3+0]-centers[lb*3+0];
    float ry = points[i*3+1]-centers[lb*3+1];
    float rz = points[i*3+2]-centers[lb*3+2];
    if (lane==0){ rel[i*3+0]=rx; rel[i*3+1]=ry; rel[i*3+2]=rz; }
    float acc = bias + wr0*rx + wr1*ry + wr2*rz;
    acc += features[i*4+0]*Wf0 + features[i*4+1]*Wf1;
    acc += features[i*4+2]*Wf2 + features[i*4+3]*Wf3;
    acc = fmaxf(acc, 0.f);
    f1[(size_t)i*64+lane] = acc;
    f1b[(size_t)i*64+lane] = f2bf(acc);
  }
}

// ============================ MFMA GEMM ============================
// USEREL doubles as the ADDPOS path: for g'-producers pass rel=points/centers and
// Wr = We rows 0..2 so out = A@W + b + pos.Wp  (fold of the edge pos-term).

template<bool RELU, int NRES, bool USEREL, bool GATHER, bool OUT32, bool OUT16, bool R2BF>
__global__ __launch_bounds__(256) void k_gemm(
    const ushortT* __restrict__ A, const ushortT* __restrict__ Wt,
    const float* __restrict__ bias, const float* __restrict__ Wr,
    const float* __restrict__ rel, const int* __restrict__ gidx,
    const float* __restrict__ r1, const void* __restrict__ r2,
    float* __restrict__ out32, ushortT* __restrict__ out16,
    int n, int ntiles)
{
  int lane = threadIdx.x & 63;
  int quad = lane >> 4, l15 = lane & 15;
  int gw = (blockIdx.x*256 + threadIdx.x) >> 6;
  int nw = (gridDim.x*256) >> 6;

  short8 bfr0_0 = *(const short8*)(Wt + ( 0 + l15)*64 +  0 + quad*8);
  short8 bfr0_1 = *(const short8*)(Wt + ( 0 + l15)*64 + 32 + quad*8);
  short8 bfr1_0 = *(const short8*)(Wt + (16 + l15)*64 +  0 + quad*8);
  short8 bfr1_1 = *(const short8*)(Wt + (16 + l15)*64 + 32 + quad*8);
  short8 bfr2_0 = *(const short8*)(Wt + (32 + l15)*64 +  0 + quad*8);
  short8 bfr2_1 = *(const short8*)(Wt + (32 + l15)*64 + 32 + quad*8);
  short8 bfr3_0 = *(const short8*)(Wt + (48 + l15)*64 +  0 + quad*8);
  short8 bfr3_1 = *(const short8*)(Wt + (48 + l15)*64 + 32 + quad*8);
  float bs0 = bias[ 0 + l15], bs1 = bias[16 + l15];
  float bs2 = bias[32 + l15], bs3 = bias[48 + l15];
  float w0c0=0,w0c1=0,w0c2=0,w0c3=0, w1c0=0,w1c1=0,w1c2=0,w1c3=0, w2c0=0,w2c1=0,w2c2=0,w2c3=0;
  if (USEREL){
    w0c0=Wr[0*64+l15]; w0c1=Wr[0*64+16+l15]; w0c2=Wr[0*64+32+l15]; w0c3=Wr[0*64+48+l15];
    w1c0=Wr[1*64+l15]; w1c1=Wr[1*64+16+l15]; w1c2=Wr[1*64+32+l15]; w1c3=Wr[1*64+48+l15];
    w2c0=Wr[2*64+l15]; w2c1=Wr[2*64+16+l15]; w2c2=Wr[2*64+32+l15]; w2c3=Wr[2*64+48+l15];
  }

  for (int t=gw; t<ntiles; t+=nw){
    int i0 = t*16;
    int rowA = i0 + l15; if (rowA >= n) rowA = n-1;
    if (GATHER) rowA = gidx[rowA];
    const ushortT* ap = A + (size_t)rowA*64 + quad*8;
    short8 a0 = *(const short8*)(ap);
    short8 a1 = *(const short8*)(ap + 32);
    v4f ac0 = {0.f,0.f,0.f,0.f}, ac1 = ac0, ac2 = ac0, ac3 = ac0;
    ac0 = __builtin_amdgcn_mfma_f32_16x16x32_bf16(a0, bfr0_0, ac0, 0,0,0);
    ac1 = __builtin_amdgcn_mfma_f32_16x16x32_bf16(a0, bfr1_0, ac1, 0,0,0);
    ac2 = __builtin_amdgcn_mfma_f32_16x16x32_bf16(a0, bfr2_0, ac2, 0,0,0);
    ac3 = __builtin_amdgcn_mfma_f32_16x16x32_bf16(a0, bfr3_0, ac3, 0,0,0);
    ac0 = __builtin_amdgcn_mfma_f32_16x16x32_bf16(a1, bfr0_1, ac0, 0,0,0);
    ac1 = __builtin_amdgcn_mfma_f32_16x16x32_bf16(a1, bfr1_1, ac1, 0,0,0);
    ac2 = __builtin_amdgcn_mfma_f32_16x16x32_bf16(a1, bfr2_1, ac2, 0,0,0);
    ac3 = __builtin_amdgcn_mfma_f32_16x16x32_bf16(a1, bfr3_1, ac3, 0,0,0);

    #pragma unroll
    for (int r=0;r<4;++r){
      int row = i0 + quad*4 + r;
      bool rowok = (row < n);
      float rx=0.f, ry=0.f, rz=0.f;
      if (USEREL && rowok){ rx=rel[row*3+0]; ry=rel[row*3+1]; rz=rel[row*3+2]; }
      float v0 = ac0[r] + bs0, v1 = ac1[r] + bs1, v2 = ac2[r] + bs2, v3 = ac3[r] + bs3;
      if (USEREL){
        v0 += rx*w0c0 + ry*w1c0 + rz*w2c0;
        v1 += rx*w0c1 + ry*w1c1 + rz*w2c1;
        v2 += rx*w0c2 + ry*w1c2 + rz*w2c2;
        v3 += rx*w0c3 + ry*w1c3 + rz*w2c3;
      }
      if (RELU){ v0=fmaxf(v0,0.f); v1=fmaxf(v1,0.f); v2=fmaxf(v2,0.f); v3=fmaxf(v3,0.f); }
      size_t base = (size_t)row*64 + l15;
      if (rowok){
        if (NRES>=1){
          v0 += r1[base]; v1 += r1[base+16]; v2 += r1[base+32]; v3 += r1[base+48];
        }
        if (NRES>=2){
          if (R2BF){
            const ushortT* rr = (const ushortT*)r2;
            v0 += bf2f(rr[base]); v1 += bf2f(rr[base+16]); v2 += bf2f(rr[base+32]); v3 += bf2f(rr[base+48]);
          } else {
            const float* rr = (const float*)r2;
            v0 += rr[base]; v1 += rr[base+16]; v2 += rr[base+32]; v3 += rr[base+48];
          }
        }
        if (OUT32){
          out32[base] = v0; out32[base+16] = v1; out32[base+32] = v2; out32[base+48] = v3;
        }
        if (OUT16){
          out16[base] = f2bf(v0); out16[base+16] = f2bf(v1); out16[base+32] = f2bf(v2); out16[base+48] = f2bf(v3);
        }
      }
    }
  }
}

// ============================ classifier ============================

__global__ __launch_bounds__(256) void k_cls(const ushortT* __restrict__ A, const ushortT* __restrict__ wtc,
                                             const float* __restrict__ bc, float* __restrict__ out,
                                             int n, int ntiles){
  int lane = threadIdx.x & 63;
  int quad = lane >> 4, l15 = lane & 15;
  int gw = (blockIdx.x*256 + threadIdx.x) >> 6;
  int nw = (gridDim.x*256) >> 6;
  short8 b0 = *(const short8*)(wtc + l15*64 +  0 + quad*8);
  short8 b1 = *(const short8*)(wtc + l15*64 + 32 + quad*8);
  float bias = (l15 < 8) ? bc[l15] : 0.f;
  for (int t=gw; t<ntiles; t+=nw){
    int i0 = t*16;
    int rowA = i0 + l15; if (rowA >= n) rowA = n-1;
    const ushortT* ap = A + (size_t)rowA*64 + quad*8;
    short8 a0 = *(const short8*)(ap);
    short8 a1 = *(const short8*)(ap + 32);
    v4f acc = {0.f,0.f,0.f,0.f};
    acc = __builtin_amdgcn_mfma_f32_16x16x32_bf16(a0, b0, acc, 0,0,0);
    acc = __builtin_amdgcn_mfma_f32_16x16x32_bf16(a1, b1, acc, 0,0,0);
    if (l15 < 8){
      #pragma unroll
      for (int r=0;r<4;++r){
        int row = i0 + quad*4 + r;
        if (row < n) out[(size_t)row*8 + l15] = acc[r] + bias;
      }
    }
  }
}

// ============================ edge aggregation: pure gather+max ============================
// g holds g'[s] = g[s] + Wp.pos[s] (folded at producer). Here:
// agg[d] = bf16( max(0, max_s g'[s][lane] - Wp[lane].pos[d]) )
// Inner loop: readlane(src) -> uniform-base 2B gather -> shift -> max. 8 accumulators.

__global__ __launch_bounds__(256) void k_edge_agg(const int* __restrict__ offs, const int* __restrict__ csr,
                                                  const float* __restrict__ pos, const ushortT* __restrict__ g,
                                                  const float* __restrict__ Wp, ushortT* __restrict__ agg, int n){
  int lane = threadIdx.x & 63;
  int gw = (blockIdx.x*256 + threadIdx.x) >> 6;
  int nw = (gridDim.x*256) >> 6;
  float w0 = Wp[0*64+lane], w1 = Wp[1*64+lane], w2 = Wp[2*64+lane];
  for (int i=gw; i<n; i+=nw){
    int b = offs[i], e = offs[i+1];
    float m0=-3.0e38f, m1=m0, m2=m0, m3=m0, m4=m0, m5=m0, m6=m0, m7=m0;
    for (int cb=b; cb<e; cb+=64){
      int cnt = e - cb; if (cnt > 64) cnt = 64;
      int li = (lane < cnt) ? lane : 0;
      int sv = csr[cb + li];
      int j = 0;
      for (; j+8<=cnt; j+=8){
        int s0=__builtin_amdgcn_readlane(sv,j+0);
        int s1=__builtin_amdgcn_readlane(sv,j+1);
        int s2=__builtin_amdgcn_readlane(sv,j+2);
        int s3=__builtin_amdgcn_readlane(sv,j+3);
        int s4=__builtin_amdgcn_readlane(sv,j+4);
        int s5=__builtin_amdgcn_readlane(sv,j+5);
        int s6=__builtin_amdgcn_readlane(sv,j+6);
        int s7=__builtin_amdgcn_readlane(sv,j+7);
        unsigned u0 = g[(unsigned)s0*64u+lane];
        unsigned u1 = g[(unsigned)s1*64u+lane];
        unsigned u2 = g[(unsigned)s2*64u+lane];
        unsigned u3 = g[(unsigned)s3*64u+lane];
        unsigned u4 = g[(unsigned)s4*64u+lane];
        unsigned u5 = g[(unsigned)s5*64u+lane];
        unsigned u6 = g[(unsigned)s6*64u+lane];
        unsigned u7 = g[(unsigned)s7*64u+lane];
        m0 = fmaxf(m0, __uint_as_float(u0<<16));
        m1 = fmaxf(m1, __uint_as_float(u1<<16));
        m2 = fmaxf(m2, __uint_as_float(u2<<16));
        m3 = fmaxf(m3, __uint_as_float(u3<<16));
        m4 = fmaxf(m4, __uint_as_float(u4<<16));
        m5 = fmaxf(m5, __uint_as_float(u5<<16));
        m6 = fmaxf(m6, __uint_as_float(u6<<16));
        m7 = fmaxf(m7, __uint_as_float(u7<<16));
      }
      for (; j<cnt; ++j){
        int s=__builtin_amdgcn_readlane(sv,j);
        unsigned u = g[(unsigned)s*64u+lane];
        m0 = fmaxf(m0, __uint_as_float(u<<16));
      }
    }
    float mm = fmaxf(fmaxf(fmaxf(m0,m1),fmaxf(m2,m3)), fmaxf(fmaxf(m4,m5),fmaxf(m6,m7)));
    float sub = w0*pos[i*3+0] + w1*pos[i*3+1] + w2*pos[i*3+2];
    agg[(size_t)i*64+lane] = f2bf(fmaxf(mm - sub, 0.f));
  }
}

// ============================ segment sum via label CSR ============================

__global__ __launch_bounds__(256) void k_seg_gather(const int* __restrict__ offs, const int* __restrict__ csr,
                                                    const ushortT* __restrict__ h, ushortT* __restrict__ c, int m){
  int lane = threadIdx.x & 63;
  int wv = (blockIdx.x*256 + threadIdx.x) >> 6;
  if (wv >= m) return;
  int b = offs[wv], e = offs[wv+1];
  float acc = 0.f;
  for (int k=b; k<e; ++k){
    int i = csr[k];
    acc += bf2f(h[(size_t)i*64+lane]);
  }
  c[(size_t)wv*64+lane] = f2bf(acc);
}

// ============================ host launcher ============================

extern "C" void kernel_launch(void* const* d_in, const int* in_sizes, int n_in,
                              void* d_out, int out_size, void* d_ws, size_t ws_size,
                              hipStream_t stream){
  const float* features = (const float*)d_in[0];
  const float* points   = (const float*)d_in[1];
  const float* centers  = (const float*)d_in[2];
  const int*   l0e      = (const int*)d_in[3];
  const int*   l1e      = (const int*)d_in[4];
  const int*   labels   = (const int*)d_in[5];
  const float* W_fe = (const float*)d_in[6];
  const float* b_fe = (const float*)d_in[7];
  const float* mWe  = (const float*)d_in[8];   // (4,67,64)
  const float* mbe  = (const float*)d_in[9];
  const float* mWu  = (const float*)d_in[10];  // (4,64,64)
  const float* mbu  = (const float*)d_in[11];
  const float* W_m1 = (const float*)d_in[12];
  const float* b_m1 = (const float*)d_in[13];
  const float* W_m2 = (const float*)d_in[14];
  const float* b_m2 = (const float*)d_in[15];
  const float* gWe  = (const float*)d_in[16];  // (2,67,64)
  const float* gbe  = (const float*)d_in[17];
  const float* gWu  = (const float*)d_in[18];
  const float* gbu  = (const float*)d_in[19];
  const float* W_l  = (const float*)d_in[20];
  const float* b_l  = (const float*)d_in[21];
  const float* W_c  = (const float*)d_in[22];
  const float* b_c  = (const float*)d_in[23];
  float* out = (float*)d_out;

  char* w = (char*)d_ws;
  size_t off = 0;
  auto alloc = [&](size_t bytes)->void*{
    void* p = (void*)(w + off);
    off = (off + bytes + 255) & ~(size_t)255;
    return p;
  };
  float* rel  = (float*)alloc((size_t)N_PTS*3*4);
  float* B0 = (float*)alloc((size_t)N_PTS*64*4);   // f1 -> f5 (fp32 residual)
  float* B1 = (float*)alloc((size_t)N_PTS*64*4);   // f2
  float* B3 = (float*)alloc((size_t)N_PTS*64*4);   // f6
  ushortT* U0 = (ushortT*)alloc((size_t)N_PTS*64*2); // f1b -> f21b
  ushortT* U1 = (ushortT*)alloc((size_t)N_PTS*64*2); // f2b -> f5b
  ushortT* U2 = (ushortT*)alloc((size_t)N_PTS*64*2); // f6b -> finalb
  ushortT* gbuf = (ushortT*)alloc((size_t)N_PTS*64*2);
  ushortT* abuf = (ushortT*)alloc((size_t)N_PTS*64*2);
  ushortT* cb_b = (ushortT*)alloc((size_t)M_CL*64*2);
  float* f3_32  = (float*)alloc((size_t)M_CL*64*4);
  ushortT* f3_b = (ushortT*)alloc((size_t)M_CL*64*2);
  ushortT* cg_b = (ushortT*)alloc((size_t)M_CL*64*2);
  ushortT* cagg_b = (ushortT*)alloc((size_t)M_CL*64*2);
  float* f4_32  = (float*)alloc((size_t)M_CL*64*4);
  ushortT* f4_b = (ushortT*)alloc((size_t)M_CL*64*2);
  ushortT* f41_b = (ushortT*)alloc((size_t)M_CL*64*2);
  ushortT* wt  = (ushortT*)alloc((size_t)15*4096*2);
  ushortT* wtc = (ushortT*)alloc((size_t)1024*2);
  int* offs0 = (int*)alloc((size_t)(N_PTS+1)*4);
  int* csr0  = (int*)alloc((size_t)E0_N*4);
  int* offs1 = (int*)alloc((size_t)(M_CL+1)*4);
  int* csr1  = (int*)alloc((size_t)E1_N*4);
  unsigned* tmp0 = (unsigned*)alloc((size_t)NB*BCAP0*4);
  unsigned* tmp1 = (unsigned*)alloc((size_t)NB*BCAP1*4);
  int* bcur0 = (int*)alloc(NB*4);
  int* bcur1 = (int*)alloc(NB*4);
  int* bb0   = (int*)alloc(NB*4);
  int* bb1   = (int*)alloc(NB*4);
  char* zbase = (char*)alloc(0);
  int* cntL = (int*)alloc((size_t)M_CL*4);
  int* curL = (int*)alloc((size_t)M_CL*4);
  size_t zbytes = (size_t)((char*)(w+off) - zbase);
  int* offsL = (int*)alloc((size_t)(M_CL+1)*4);
  int* csrL  = (int*)alloc((size_t)N_PTS*4);
  int* partL = (int*)alloc(64*4);
  (void)ws_size; (void)in_sizes; (void)n_in; (void)out_size;

  const int NT_N = (N_PTS+15)/16;   // 6250
  const int NT_M = (M_CL +15)/16;   // 782
  const int GBG_N = 1563;
  const int GBG_M = 196;
  const int GB_N  = 2048;

  hipMemsetAsync(zbase, 0, zbytes, stream);

  // ---- CSR builds ----
  k_binit<<<1, 256, 0, stream>>>(bcur0, bcur1);
  k_bin<RANGE0><<<256, 256, 0, stream>>>(l0e, E0_N, bcur0, tmp0);
  k_bin<RANGE1><<<196, 256, 0, stream>>>(l1e, E1_N, bcur1, tmp1);
  k_scan_bases<<<2, 64, 0, stream>>>(bcur0, bb0, offs0+N_PTS, bcur1, bb1, offs1+M_CL);
  k_csr_build<RANGE0,BCAP0><<<NB, 256, 0, stream>>>(tmp0, bcur0, bb0, N_PTS, offs0, csr0);
  k_csr_build<RANGE1,BCAP1><<<NB, 256, 0, stream>>>(tmp1, bcur1, bb1, M_CL, offs1, csr1);

  // ---- label CSR ----
  k_count_lab<<<(N_PTS+255)/256, 256, 0, stream>>>(labels, N_PTS, cntL);
  k_chunk_sum<<<7, 256, 0, stream>>>(cntL, M_CL, partL);
  k_scan_part<<<1, 64, 0, stream>>>(partL, 7, offsL, M_CL);
  k_chunk_scan<<<7, 256, 0, stream>>>(cntL, M_CL, partL, offsL);
  k_fill_lab<<<(N_PTS+255)/256, 256, 0, stream>>>(labels, N_PTS, offsL, curL, csrL);

  // ---- weight prep ----
  WSrc ws{};
  ws.p[0]=mWu+0*4096; ws.p[1]=mWu+1*4096; ws.p[2]=mWu+2*4096; ws.p[3]=mWu+3*4096;
  ws.p[4]=W_m2; ws.p[5]=gWu+0*4096; ws.p[6]=gWu+1*4096;
  ws.p[7]=mWe+0*4288+192; ws.p[8]=mWe+1*4288+192; ws.p[9]=mWe+2*4288+192; ws.p[10]=mWe+3*4288+192;
  ws.p[11]=W_m1; ws.p[12]=W_l; ws.p[13]=gWe+0*4288+192; ws.p[14]=gWe+1*4288+192;
  ws.p[15]=W_c;
  k_wprep<<<16, 256, 0, stream>>>(ws, wt, wtc);

  // ---- encoder ----
  k_f1<<<GB_N, 256, 0, stream>>>(features, points, centers, labels, W_fe, b_fe, rel, B0, U0, N_PTS);

  // ---- g0' = f1 @ mWe0 + be0 + points.Wp0 ----
  k_gemm<false,0,true,false,false,true,false><<<GBG_N,256,0,stream>>>(U0, wt+7*4096, mbe+0,
      mWe+0*4288, points, nullptr, nullptr, nullptr, nullptr, gbuf, N_PTS, NT_N);
  // ---- layer0: agg -> f2 = relu(.@Wu0+bu0)+f1 ----
  k_edge_agg<<<GB_N,256,0,stream>>>(offs0, csr0, points, gbuf, mWe+0*4288, abuf, N_PTS);
  k_gemm<true,1,false,false,true,true,false><<<GBG_N,256,0,stream>>>(abuf, wt+0*4096, mbu+0,
      nullptr, nullptr, nullptr, B0, nullptr, B1, U1, N_PTS, NT_N);
  // ---- g1' = f2 @ mWe1 + be1 + points.Wp1 ----
  k_gemm<false,0,true,false,false,true,false><<<GBG_N,256,0,stream>>>(U1, wt+8*4096, mbe+64,
      mWe+1*4288, points, nullptr, nullptr, nullptr, nullptr, gbuf, N_PTS, NT_N);
  // ---- layer1: f2_1 ----
  k_edge_agg<<<GB_N,256,0,stream>>>(offs0, csr0, points, gbuf, mWe+1*4288, abuf, N_PTS);
  k_gemm<true,1,false,false,false,true,false><<<GBG_N,256,0,stream>>>(abuf, wt+1*4096, mbu+64,
      nullptr, nullptr, nullptr, B1, nullptr, nullptr, U0, N_PTS, NT_N);
  // ---- h = relu(f2_1@W_m1 + rel@W_m1[64:] + b_m1) ----
  k_gemm<true,0,true,false,false,true,false><<<GBG_N,256,0,stream>>>(U0, wt+11*4096, b_m1,
      W_m1+4096, rel, nullptr, nullptr, nullptr, nullptr, gbuf, N_PTS, NT_N);
  // ---- c = segsum(h); f3 = relu(c@W_m2+b_m2) ----
  k_seg_gather<<<(M_CL*64+255)/256, 256, 0, stream>>>(offsL, csrL, gbuf, cb_b, M_CL);
  k_gemm<true,0,false,false,true,true,false><<<GBG_M,256,0,stream>>>(cb_b, wt+4*4096, b_m2,
      nullptr, nullptr, nullptr, nullptr, nullptr, f3_32, f3_b, M_CL, NT_M);
  // ---- cluster layer0 ----
  k_gemm<false,0,true,false,false,true,false><<<GBG_M,256,0,stream>>>(f3_b, wt+13*4096, gbe+0,
      gWe+0*4288, centers, nullptr, nullptr, nullptr, nullptr, cg_b, M_CL, NT_M);
  k_edge_agg<<<GBG_M,256,0,stream>>>(offs1, csr1, centers, cg_b, gWe+0*4288, cagg_b, M_CL);
  k_gemm<true,1,false,false,true,true,false><<<GBG_M,256,0,stream>>>(cagg_b, wt+5*4096, gbu+0,
      nullptr, nullptr, nullptr, f3_32, nullptr, f4_32, f4_b, M_CL, NT_M);
  // ---- cluster layer1 ----
  k_gemm<false,0,true,false,false,true,false><<<GBG_M,256,0,stream>>>(f4_b, wt+14*4096, gbe+64,
      gWe+1*4288, centers, nullptr, nullptr, nullptr, nullptr, cg_b, M_CL, NT_M);
  k_edge_agg<<<GBG_M,256,0,stream>>>(offs1, csr1, centers, cg_b, gWe+1*4288, cagg_b, M_CL);
  k_gemm<true,1,false,false,false,true,false><<<GBG_M,256,0,stream>>>(cagg_b, wt+6*4096, gbu+64,
      nullptr, nullptr, nullptr, f4_32, nullptr, nullptr, f41_b, M_CL, NT_M);
  // ---- f5 = relu(f41[labels]@W_l + rel@W_l[64:] + b_l) ----
  k_gemm<true,0,true,true,true,true,false><<<GBG_N,256,0,stream>>>(f41_b, wt+12*4096, b_l,
      W_l+4096, rel, labels, nullptr, nullptr, B0, U1, N_PTS, NT_N);
  // ---- g2' = f5 @ mWe2 + be2 + points.Wp2 ----
  k_gemm<false,0,true,false,false,true,false><<<GBG_N,256,0,stream>>>(U1, wt+9*4096, mbe+128,
      mWe+2*4288, points, nullptr, nullptr, nullptr, nullptr, gbuf, N_PTS, NT_N);
  // ---- layer2: f6 = relu(.@Wu2+bu2)+f5+f2_1(bf16) ----
  k_edge_agg<<<GB_N,256,0,stream>>>(offs0, csr0, points, gbuf, mWe+2*4288, abuf, N_PTS);
  k_gemm<true,2,false,false,true,true,true><<<GBG_N,256,0,stream>>>(abuf, wt+2*4096, mbu+128,
      nullptr, nullptr, nullptr, B0, U0, B3, U2, N_PTS, NT_N);
  // ---- g3' = f6 @ mWe3 + be3 + points.Wp3 ----
  k_gemm<false,0,true,false,false,true,false><<<GBG_N,256,0,stream>>>(U2, wt+10*4096, mbe+192,
      mWe+3*4288, points, nullptr, nullptr, nullptr, nullptr, gbuf, N_PTS, NT_N);
  // ---- layer3: final = relu(.@Wu3+bu3)+f6+f2 ----
  k_edge_agg<<<GB_N,256,0,stream>>>(offs0, csr0, points, gbuf, mWe+3*4288, abuf, N_PTS);
  k_gemm<true,2,false,false,false,true,false><<<GBG_N,256,0,stream>>>(abuf, wt+3*4096, mbu+192,
      nullptr, nullptr, nullptr, B3, B1, nullptr, U2, N_PTS, NT_N);
  // ---- out = final @ W_c + b_c ----
  k_cls<<<GBG_N,256,0,stream>>>(U2, wtc, b_c, out, N_PTS, NT_N);
}

// Round 8
// 672.241 us; speedup vs baseline: 1.8243x; 1.0917x over previous
//
#include <hip/hip_runtime.h>

#define N_PTS   100000
#define M_CL    12500
#define E0_N    1600000
#define E1_N    400000

#define NB      128
#define BIN_CAP 48
#define RANGE0  782
#define RANGE1  98
#define BCAP0   16384
#define BCAP1   4096

typedef unsigned short ushortT;
typedef short  short8 __attribute__((ext_vector_type(8)));
typedef float  v4f    __attribute__((ext_vector_type(4)));
typedef _Float16 h2   __attribute__((ext_vector_type(2)));

__device__ inline ushortT f2bf(float x){
  union{float f; unsigned u;} v; v.f = x;
  unsigned r = v.u + 0x7fffu + ((v.u >> 16) & 1u);   // RNE
  return (ushortT)(r >> 16);
}
__device__ inline float bf2f(ushortT h){
  union{unsigned u; float f;} v; v.u = ((unsigned)h) << 16;
  return v.f;
}
__device__ inline ushortT f2h(float x){
  union{_Float16 h; ushortT u;} v; v.h = (_Float16)x;
  return v.u;
}
__device__ inline float h2f(ushortT u){
  union{ushortT u; _Float16 h;} v; v.u = u;
  return (float)v.h;
}

// ============================ bucketed CSR build ============================

__global__ void k_binit(int* c0, int* c1){
  int t = threadIdx.x;
  if (t < NB) c0[t] = t*BCAP0;
  else        c1[t-NB] = (t-NB)*BCAP1;
}

template<int RANGE>
__global__ __launch_bounds__(256) void k_bin(const int* __restrict__ edges, int E,
                                             int* __restrict__ bcur, unsigned* __restrict__ tmp){
  __shared__ unsigned stage[NB*BIN_CAP];
  __shared__ int scnt[NB];
  __shared__ int sbase[NB];
  int tid = threadIdx.x;
  int nchunks = (E + 2047) / 2048;
  for (int c = blockIdx.x; c < nchunks; c += gridDim.x){
    int base = c*2048;
    if (tid < NB) scnt[tid] = 0;
    __syncthreads();
    #pragma unroll
    for (int r=0;r<8;++r){
      int e = base + r*256 + tid;
      if (e < E){
        int s = edges[2*e], d = edges[2*e+1];
        int bk = d / RANGE;
        unsigned packed = ((unsigned)s << 11) | (unsigned)(d - bk*RANGE);
        int pos = atomicAdd(&scnt[bk], 1);
        if (pos < BIN_CAP) stage[bk*BIN_CAP+pos] = packed;
        else tmp[atomicAdd(&bcur[bk],1)] = packed;
      }
    }
    __syncthreads();
    if (tid < NB){
      int nfl = scnt[tid]; if (nfl > BIN_CAP) nfl = BIN_CAP;
      sbase[tid] = atomicAdd(&bcur[tid], nfl);
    }
    __syncthreads();
    int wv = tid >> 6, ln = tid & 63;
    for (int bb=0; bb<NB/4; ++bb){
      int bk = wv*(NB/4) + bb;
      int nfl = scnt[bk]; if (nfl > BIN_CAP) nfl = BIN_CAP;
      if (ln < nfl) tmp[sbase[bk]+ln] = stage[bk*BIN_CAP+ln];
    }
    __syncthreads();
  }
}

__global__ void k_scan_bases(const int* c0, int* bb0, int* off0e,
                             const int* c1, int* bb1, int* off1e){
  const int* cur = blockIdx.x ? c1 : c0;
  int* bb = blockIdx.x ? bb1 : bb0;
  int* offe = blockIdx.x ? off1e : off0e;
  int BC = blockIdx.x ? BCAP1 : BCAP0;
  int lane = threadIdx.x & 63;
  int v0 = cur[2*lane]   - (2*lane)*BC;
  int v1 = cur[2*lane+1] - (2*lane+1)*BC;
  int psum = v0 + v1, sc = psum;
  #pragma unroll
  for (int st=1; st<64; st<<=1){
    int x = __shfl_up(sc, st, 64);
    if (lane >= st) sc += x;
  }
  int ex = sc - psum;
  bb[2*lane] = ex; bb[2*lane+1] = ex + v0;
  if (lane == 63) *offe = sc;
}

template<int RANGE, int BCAP>
__global__ __launch_bounds__(256) void k_csr_build(const unsigned* __restrict__ tmp, const int* __restrict__ bcur,
                                                   const int* __restrict__ bb, int n,
                                                   int* __restrict__ offs, int* __restrict__ csr){
  constexpr int K = (RANGE + 255) / 256;
  __shared__ int hist[RANGE];
  __shared__ int part[256];
  int b = blockIdx.x, tid = threadIdx.x;
  int dlo = b*RANGE;
  int range = n - dlo; if (range > RANGE) range = RANGE; if (range < 0) range = 0;
  int cnt = bcur[b] - b*BCAP;
  for (int t=tid; t<RANGE; t+=256) hist[t] = 0;
  __syncthreads();
  const unsigned* sl = tmp + (size_t)b*BCAP;
  for (int j=tid; j<cnt; j+=256) atomicAdd(&hist[sl[j] & 2047u], 1);
  __syncthreads();
  int s = 0; int loc[K];
  #pragma unroll
  for (int kk=0; kk<K; ++kk){
    int idx = tid*K + kk;
    int v = (idx < RANGE) ? hist[idx] : 0;
    loc[kk] = s; s += v;
  }
  part[tid] = s; __syncthreads();
  int own = s;
  for (int st=1; st<256; st<<=1){
    int x = (tid >= st) ? part[tid-st] : 0;
    __syncthreads();
    part[tid] += x;
    __syncthreads();
  }
  int ebase = part[tid] - own;
  int gb = bb[b];
  __syncthreads();
  #pragma unroll
  for (int kk=0; kk<K; ++kk){
    int idx = tid*K + kk;
    if (idx < RANGE){
      int ex = ebase + loc[kk];
      if (idx < range) offs[dlo+idx] = gb + ex;
      hist[idx] = ex;
    }
  }
  __syncthreads();
  for (int j=tid; j<cnt; j+=256){
    unsigned p = sl[j];
    int pos = atomicAdd(&hist[p & 2047u], 1);
    csr[gb + pos] = (int)(p >> 11);
  }
}

// ============================ label CSR ============================

__global__ __launch_bounds__(256) void k_count_lab(const int* __restrict__ labels, int n, int* __restrict__ cnt){
  int i = blockIdx.x*256 + threadIdx.x;
  if (i < n) atomicAdd(&cnt[labels[i]], 1);
}

__global__ __launch_bounds__(256) void k_chunk_sum(const int* __restrict__ cnt, int n, int* __restrict__ part){
  __shared__ int sd[256];
  int t = threadIdx.x, base = blockIdx.x*2048;
  int s = 0;
  #pragma unroll
  for (int r=0;r<8;++r){ int i = base + t*8 + r; if (i<n) s += cnt[i]; }
  sd[t]=s; __syncthreads();
  for (int st=128; st>0; st>>=1){ if (t<st) sd[t]+=sd[t+st]; __syncthreads(); }
  if (t==0) part[blockIdx.x]=sd[0];
}

__global__ void k_scan_part(int* part, int B, int* offs, int n){
  int lane = threadIdx.x & 63;
  int v = (lane < B) ? part[lane] : 0;
  int orig = v;
  #pragma unroll
  for (int st=1; st<64; st<<=1){
    int x = __shfl_up(v, st, 64);
    if (lane >= st) v += x;
  }
  if (lane < B) part[lane] = v - orig;
  if (lane == 63) offs[n] = v;
}

__global__ __launch_bounds__(256) void k_chunk_scan(const int* __restrict__ cnt, int n,
                                                    const int* __restrict__ part, int* __restrict__ offs){
  __shared__ int sd[256];
  int t=threadIdx.x, base=blockIdx.x*2048;
  int v[8]; int s=0;
  #pragma unroll
  for (int r=0;r<8;++r){ int i=base+t*8+r; v[r] = (i<n)?cnt[i]:0; s+=v[r]; }
  sd[t]=s; __syncthreads();
  for (int st=1; st<256; st<<=1){
    int x = (t>=st)? sd[t-st] : 0;
    __syncthreads();
    sd[t]+=x;
    __syncthreads();
  }
  int acc = part[blockIdx.x] + sd[t] - s;
  #pragma unroll
  for (int r=0;r<8;++r){ int i=base+t*8+r; if (i<n) offs[i]=acc; acc+=v[r]; }
}

__global__ __launch_bounds__(256) void k_fill_lab(const int* __restrict__ labels, int n,
                                                  const int* __restrict__ offs, int* __restrict__ cur,
                                                  int* __restrict__ csr){
  int i = blockIdx.x*256 + threadIdx.x;
  if (i < n){
    int d = labels[i];
    int p = atomicAdd(&cur[d], 1);
    csr[offs[d]+p] = i;
  }
}

// ============================ weight prep ============================

struct WSrc { const float* p[16]; };

__global__ __launch_bounds__(256) void k_wprep(WSrc s, ushortT* __restrict__ wt, ushortT* __restrict__ wtc){
  int slot = blockIdx.x;
  if (slot < 15){
    const float* src = s.p[slot];
    ushortT* dst = wt + slot*4096;
    for (int e=threadIdx.x; e<4096; e+=256){
      int nn = e>>6, kk = e&63;
      dst[e] = f2bf(src[kk*64+nn]);
    }
  } else {
    const float* src = s.p[15];
    for (int e=threadIdx.x; e<1024; e+=256){
      int nn = e>>6, kk = e&63;
      wtc[e] = (nn<8) ? f2bf(src[kk*8+nn]) : (ushortT)0;
    }
  }
}

// ============================ feature encoder: rel + f1 (fp32 + bf16) ============================

__global__ __launch_bounds__(256) void k_f1(const float* __restrict__ features, const float* __restrict__ points,
                                            const float* __restrict__ centers, const int* __restrict__ labels,
                                            const float* __restrict__ W, const float* __restrict__ b,
                                            float* __restrict__ rel, float* __restrict__ f1,
                                            ushortT* __restrict__ f1b, int n){
  int lane = threadIdx.x & 63;
  int gw = (blockIdx.x*256 + threadIdx.x) >> 6;
  int nw = (gridDim.x*256) >> 6;
  float Wf0=W[0*64+lane], Wf1=W[1*64+lane], Wf2=W[2*64+lane], Wf3=W[3*64+lane];
  float wr0=W[4*64+lane], wr1=W[5*64+lane], wr2=W[6*64+lane];
  float bias=b[lane];
  for (int i=gw; i<n; i+=nw){
    int lb = labels[i];
    float rx = points[i*3+0]-centers[lb*3+0];
    float ry = points[i*3+1]-centers[lb*3+1];
    float rz = points[i*3+2]-centers[lb*3+2];
    if (lane==0){ rel[i*3+0]=rx; rel[i*3+1]=ry; rel[i*3+2]=rz; }
    float acc = bias + wr0*rx + wr1*ry + wr2*rz;
    acc += features[i*4+0]*Wf0 + features[i*4+1]*Wf1;
    acc += features[i*4+2]*Wf2 + features[i*4+3]*Wf3;
    acc = fmaxf(acc, 0.f);
    f1[(size_t)i*64+lane] = acc;
    f1b[(size_t)i*64+lane] = f2bf(acc);
  }
}

// ============================ MFMA GEMM ============================
// USEREL doubles as ADDPOS: pass rel=points/centers + Wr = We rows 0..2 -> out += pos.Wp.
// F16O: 16-bit output stored as f16 (for edge-message g' buffers); else bf16.

template<bool RELU, int NRES, bool USEREL, bool GATHER, bool OUT32, bool OUT16, bool R2BF, bool F16O>
__global__ __launch_bounds__(256) void k_gemm(
    const ushortT* __restrict__ A, const ushortT* __restrict__ Wt,
    const float* __restrict__ bias, const float* __restrict__ Wr,
    const float* __restrict__ rel, const int* __restrict__ gidx,
    const float* __restrict__ r1, const void* __restrict__ r2,
    float* __restrict__ out32, ushortT* __restrict__ out16,
    int n, int ntiles)
{
  int lane = threadIdx.x & 63;
  int quad = lane >> 4, l15 = lane & 15;
  int gw = (blockIdx.x*256 + threadIdx.x) >> 6;
  int nw = (gridDim.x*256) >> 6;

  short8 bfr0_0 = *(const short8*)(Wt + ( 0 + l15)*64 +  0 + quad*8);
  short8 bfr0_1 = *(const short8*)(Wt + ( 0 + l15)*64 + 32 + quad*8);
  short8 bfr1_0 = *(const short8*)(Wt + (16 + l15)*64 +  0 + quad*8);
  short8 bfr1_1 = *(const short8*)(Wt + (16 + l15)*64 + 32 + quad*8);
  short8 bfr2_0 = *(const short8*)(Wt + (32 + l15)*64 +  0 + quad*8);
  short8 bfr2_1 = *(const short8*)(Wt + (32 + l15)*64 + 32 + quad*8);
  short8 bfr3_0 = *(const short8*)(Wt + (48 + l15)*64 +  0 + quad*8);
  short8 bfr3_1 = *(const short8*)(Wt + (48 + l15)*64 + 32 + quad*8);
  float bs0 = bias[ 0 + l15], bs1 = bias[16 + l15];
  float bs2 = bias[32 + l15], bs3 = bias[48 + l15];
  float w0c0=0,w0c1=0,w0c2=0,w0c3=0, w1c0=0,w1c1=0,w1c2=0,w1c3=0, w2c0=0,w2c1=0,w2c2=0,w2c3=0;
  if (USEREL){
    w0c0=Wr[0*64+l15]; w0c1=Wr[0*64+16+l15]; w0c2=Wr[0*64+32+l15]; w0c3=Wr[0*64+48+l15];
    w1c0=Wr[1*64+l15]; w1c1=Wr[1*64+16+l15]; w1c2=Wr[1*64+32+l15]; w1c3=Wr[1*64+48+l15];
    w2c0=Wr[2*64+l15]; w2c1=Wr[2*64+16+l15]; w2c2=Wr[2*64+32+l15]; w2c3=Wr[2*64+48+l15];
  }

  for (int t=gw; t<ntiles; t+=nw){
    int i0 = t*16;
    int rowA = i0 + l15; if (rowA >= n) rowA = n-1;
    if (GATHER) rowA = gidx[rowA];
    const ushortT* ap = A + (size_t)rowA*64 + quad*8;
    short8 a0 = *(const short8*)(ap);
    short8 a1 = *(const short8*)(ap + 32);
    v4f ac0 = {0.f,0.f,0.f,0.f}, ac1 = ac0, ac2 = ac0, ac3 = ac0;
    ac0 = __builtin_amdgcn_mfma_f32_16x16x32_bf16(a0, bfr0_0, ac0, 0,0,0);
    ac1 = __builtin_amdgcn_mfma_f32_16x16x32_bf16(a0, bfr1_0, ac1, 0,0,0);
    ac2 = __builtin_amdgcn_mfma_f32_16x16x32_bf16(a0, bfr2_0, ac2, 0,0,0);
    ac3 = __builtin_amdgcn_mfma_f32_16x16x32_bf16(a0, bfr3_0, ac3, 0,0,0);
    ac0 = __builtin_amdgcn_mfma_f32_16x16x32_bf16(a1, bfr0_1, ac0, 0,0,0);
    ac1 = __builtin_amdgcn_mfma_f32_16x16x32_bf16(a1, bfr1_1, ac1, 0,0,0);
    ac2 = __builtin_amdgcn_mfma_f32_16x16x32_bf16(a1, bfr2_1, ac2, 0,0,0);
    ac3 = __builtin_amdgcn_mfma_f32_16x16x32_bf16(a1, bfr3_1, ac3, 0,0,0);

    #pragma unroll
    for (int r=0;r<4;++r){
      int row = i0 + quad*4 + r;
      bool rowok = (row < n);
      float rx=0.f, ry=0.f, rz=0.f;
      if (USEREL && rowok){ rx=rel[row*3+0]; ry=rel[row*3+1]; rz=rel[row*3+2]; }
      float v0 = ac0[r] + bs0, v1 = ac1[r] + bs1, v2 = ac2[r] + bs2, v3 = ac3[r] + bs3;
      if (USEREL){
        v0 += rx*w0c0 + ry*w1c0 + rz*w2c0;
        v1 += rx*w0c1 + ry*w1c1 + rz*w2c1;
        v2 += rx*w0c2 + ry*w1c2 + rz*w2c2;
        v3 += rx*w0c3 + ry*w1c3 + rz*w2c3;
      }
      if (RELU){ v0=fmaxf(v0,0.f); v1=fmaxf(v1,0.f); v2=fmaxf(v2,0.f); v3=fmaxf(v3,0.f); }
      size_t base = (size_t)row*64 + l15;
      if (rowok){
        if (NRES>=1){
          v0 += r1[base]; v1 += r1[base+16]; v2 += r1[base+32]; v3 += r1[base+48];
        }
        if (NRES>=2){
          if (R2BF){
            const ushortT* rr = (const ushortT*)r2;
            v0 += bf2f(rr[base]); v1 += bf2f(rr[base+16]); v2 += bf2f(rr[base+32]); v3 += bf2f(rr[base+48]);
          } else {
            const float* rr = (const float*)r2;
            v0 += rr[base]; v1 += rr[base+16]; v2 += rr[base+32]; v3 += rr[base+48];
          }
        }
        if (OUT32){
          out32[base] = v0; out32[base+16] = v1; out32[base+32] = v2; out32[base+48] = v3;
        }
        if (OUT16){
          if (F16O){
            out16[base] = f2h(v0); out16[base+16] = f2h(v1); out16[base+32] = f2h(v2); out16[base+48] = f2h(v3);
          } else {
            out16[base] = f2bf(v0); out16[base+16] = f2bf(v1); out16[base+32] = f2bf(v2); out16[base+48] = f2bf(v3);
          }
        }
      }
    }
  }
}

// ============================ classifier ============================

__global__ __launch_bounds__(256) void k_cls(const ushortT* __restrict__ A, const ushortT* __restrict__ wtc,
                                             const float* __restrict__ bc, float* __restrict__ out,
                                             int n, int ntiles){
  int lane = threadIdx.x & 63;
  int quad = lane >> 4, l15 = lane & 15;
  int gw = (blockIdx.x*256 + threadIdx.x) >> 6;
  int nw = (gridDim.x*256) >> 6;
  short8 b0 = *(const short8*)(wtc + l15*64 +  0 + quad*8);
  short8 b1 = *(const short8*)(wtc + l15*64 + 32 + quad*8);
  float bias = (l15 < 8) ? bc[l15] : 0.f;
  for (int t=gw; t<ntiles; t+=nw){
    int i0 = t*16;
    int rowA = i0 + l15; if (rowA >= n) rowA = n-1;
    const ushortT* ap = A + (size_t)rowA*64 + quad*8;
    short8 a0 = *(const short8*)(ap);
    short8 a1 = *(const short8*)(ap + 32);
    v4f acc = {0.f,0.f,0.f,0.f};
    acc = __builtin_amdgcn_mfma_f32_16x16x32_bf16(a0, b0, acc, 0,0,0);
    acc = __builtin_amdgcn_mfma_f32_16x16x32_bf16(a1, b1, acc, 0,0,0);
    if (l15 < 8){
      #pragma unroll
      for (int r=0;r<4;++r){
        int row = i0 + quad*4 + r;
        if (row < n) out[(size_t)row*8 + l15] = acc[r] + bias;
      }
    }
  }
}

// ============================ edge aggregation: f16-packed, 2 edges/iter ============================
// g' rows are f16[64] (128 B). Lane handles dims {2*l31, 2*l31+1} (one dword).
// Lanes 0-31 process even edges, 32-63 odd edges; combine across halves at the end.
// agg[d] = bf16( max(0, max_s g'[s] - Wp.pos[d]) ), packed 2 bf16/dword, row-major.

__device__ inline h2 pkmax(h2 a, h2 b){ return __builtin_elementwise_max(a, b); }
__device__ inline h2 u2h(unsigned u){ union{unsigned u; h2 h;} v{u}; return v.h; }

__global__ __launch_bounds__(256) void k_edge_agg(const int* __restrict__ offs, const int* __restrict__ csr,
                                                  const float* __restrict__ pos, const ushortT* __restrict__ g,
                                                  const float* __restrict__ Wp, ushortT* __restrict__ agg, int n){
  int lane = threadIdx.x & 63;
  int half = lane >> 5, l31 = lane & 31;
  int gw = (blockIdx.x*256 + threadIdx.x) >> 6;
  int nw = (gridDim.x*256) >> 6;
  const unsigned* g32 = (const unsigned*)g;
  float2 w0 = *(const float2*)(Wp + 0*64 + 2*l31);
  float2 w1 = *(const float2*)(Wp + 1*64 + 2*l31);
  float2 w2 = *(const float2*)(Wp + 2*64 + 2*l31);
  const h2 NEGBIG = {(_Float16)-60000.f, (_Float16)-60000.f};
  for (int i=gw; i<n; i+=nw){
    int b = offs[i], e = offs[i+1];
    h2 m0=NEGBIG, m1=NEGBIG, m2=NEGBIG, m3=NEGBIG, m4=NEGBIG, m5=NEGBIG, m6=NEGBIG, m7=NEGBIG;
    for (int cb=b; cb<e; cb+=64){
      int cnt = e - cb; if (cnt > 64) cnt = 64;
      int li = (lane < cnt) ? lane : 0;
      int sv = csr[cb + li];
      int cm1 = cnt - 1;
      for (int j=0; j<cnt; j+=16){
        int i0 = min(j+ 0+half, cm1), i1 = min(j+ 2+half, cm1);
        int i2 = min(j+ 4+half, cm1), i3 = min(j+ 6+half, cm1);
        int i4 = min(j+ 8+half, cm1), i5 = min(j+10+half, cm1);
        int i6 = min(j+12+half, cm1), i7 = min(j+14+half, cm1);
        int s0 = __shfl(sv, i0, 64), s1 = __shfl(sv, i1, 64);
        int s2 = __shfl(sv, i2, 64), s3 = __shfl(sv, i3, 64);
        int s4 = __shfl(sv, i4, 64), s5 = __shfl(sv, i5, 64);
        int s6 = __shfl(sv, i6, 64), s7 = __shfl(sv, i7, 64);
        unsigned u0 = g32[(unsigned)s0*32u + l31];
        unsigned u1 = g32[(unsigned)s1*32u + l31];
        unsigned u2 = g32[(unsigned)s2*32u + l31];
        unsigned u3 = g32[(unsigned)s3*32u + l31];
        unsigned u4 = g32[(unsigned)s4*32u + l31];
        unsigned u5 = g32[(unsigned)s5*32u + l31];
        unsigned u6 = g32[(unsigned)s6*32u + l31];
        unsigned u7 = g32[(unsigned)s7*32u + l31];
        m0 = pkmax(m0, u2h(u0)); m1 = pkmax(m1, u2h(u1));
        m2 = pkmax(m2, u2h(u2)); m3 = pkmax(m3, u2h(u3));
        m4 = pkmax(m4, u2h(u4)); m5 = pkmax(m5, u2h(u5));
        m6 = pkmax(m6, u2h(u6)); m7 = pkmax(m7, u2h(u7));
      }
    }
    h2 mm = pkmax(pkmax(pkmax(m0,m1),pkmax(m2,m3)),
                  pkmax(pkmax(m4,m5),pkmax(m6,m7)));
    union{h2 h; int u;} pk{mm};
    int other = __shfl_xor(pk.u, 32, 64);
    union{int u; h2 h;} po{other};
    mm = pkmax(mm, po.h);
    float x0 = (float)mm.x, x1 = (float)mm.y;
    float px = pos[i*3+0], py = pos[i*3+1], pz = pos[i*3+2];
    float s0 = w0.x*px + w1.x*py + w2.x*pz;
    float s1 = w0.y*px + w1.y*py + w2.y*pz;
    float r0 = fmaxf(x0 - s0, 0.f);
    float r1 = fmaxf(x1 - s1, 0.f);
    if (half == 0){
      unsigned pkout = (unsigned)f2bf(r0) | ((unsigned)f2bf(r1) << 16);
      ((unsigned*)agg)[(size_t)i*32 + l31] = pkout;
    }
  }
}

// ============================ segment sum via label CSR (f16 in, bf16 out) ============================

__global__ __launch_bounds__(256) void k_seg_gather(const int* __restrict__ offs, const int* __restrict__ csr,
                                                    const ushortT* __restrict__ h, ushortT* __restrict__ c, int m){
  int lane = threadIdx.x & 63;
  int wv = (blockIdx.x*256 + threadIdx.x) >> 6;
  if (wv >= m) return;
  int b = offs[wv], e = offs[wv+1];
  float acc = 0.f;
  for (int k=b; k<e; ++k){
    int i = csr[k];
    acc += h2f(h[(size_t)i*64+lane]);
  }
  c[(size_t)wv*64+lane] = f2bf(acc);
}

// ============================ host launcher ============================

extern "C" void kernel_launch(void* const* d_in, const int* in_sizes, int n_in,
                              void* d_out, int out_size, void* d_ws, size_t ws_size,
                              hipStream_t stream){
  const float* features = (const float*)d_in[0];
  const float* points   = (const float*)d_in[1];
  const float* centers  = (const float*)d_in[2];
  const int*   l0e      = (const int*)d_in[3];
  const int*   l1e      = (const int*)d_in[4];
  const int*   labels   = (const int*)d_in[5];
  const float* W_fe = (const float*)d_in[6];
  const float* b_fe = (const float*)d_in[7];
  const float* mWe  = (const float*)d_in[8];   // (4,67,64)
  const float* mbe  = (const float*)d_in[9];
  const float* mWu  = (const float*)d_in[10];  // (4,64,64)
  const float* mbu  = (const float*)d_in[11];
  const float* W_m1 = (const float*)d_in[12];
  const float* b_m1 = (const float*)d_in[13];
  const float* W_m2 = (const float*)d_in[14];
  const float* b_m2 = (const float*)d_in[15];
  const float* gWe  = (const float*)d_in[16];  // (2,67,64)
  const float* gbe  = (const float*)d_in[17];
  const float* gWu  = (const float*)d_in[18];
  const float* gbu  = (const float*)d_in[19];
  const float* W_l  = (const float*)d_in[20];
  const float* b_l  = (const float*)d_in[21];
  const float* W_c  = (const float*)d_in[22];
  const float* b_c  = (const float*)d_in[23];
  float* out = (float*)d_out;

  char* w = (char*)d_ws;
  size_t off = 0;
  auto alloc = [&](size_t bytes)->void*{
    void* p = (void*)(w + off);
    off = (off + bytes + 255) & ~(size_t)255;
    return p;
  };
  float* rel  = (float*)alloc((size_t)N_PTS*3*4);
  float* B0 = (float*)alloc((size_t)N_PTS*64*4);
  float* B1 = (float*)alloc((size_t)N_PTS*64*4);
  float* B3 = (float*)alloc((size_t)N_PTS*64*4);
  ushortT* U0 = (ushortT*)alloc((size_t)N_PTS*64*2);
  ushortT* U1 = (ushortT*)alloc((size_t)N_PTS*64*2);
  ushortT* U2 = (ushortT*)alloc((size_t)N_PTS*64*2);
  ushortT* gbuf = (ushortT*)alloc((size_t)N_PTS*64*2);   // f16 g'/h
  ushortT* abuf = (ushortT*)alloc((size_t)N_PTS*64*2);   // bf16 agg
  ushortT* cb_b = (ushortT*)alloc((size_t)M_CL*64*2);
  float* f3_32  = (float*)alloc((size_t)M_CL*64*4);
  ushortT* f3_b = (ushortT*)alloc((size_t)M_CL*64*2);
  ushortT* cg_b = (ushortT*)alloc((size_t)M_CL*64*2);    // f16 cluster g'
  ushortT* cagg_b = (ushortT*)alloc((size_t)M_CL*64*2);
  float* f4_32  = (float*)alloc((size_t)M_CL*64*4);
  ushortT* f4_b = (ushortT*)alloc((size_t)M_CL*64*2);
  ushortT* f41_b = (ushortT*)alloc((size_t)M_CL*64*2);
  ushortT* wt  = (ushortT*)alloc((size_t)15*4096*2);
  ushortT* wtc = (ushortT*)alloc((size_t)1024*2);
  int* offs0 = (int*)alloc((size_t)(N_PTS+1)*4);
  int* csr0  = (int*)alloc((size_t)E0_N*4);
  int* offs1 = (int*)alloc((size_t)(M_CL+1)*4);
  int* csr1  = (int*)alloc((size_t)E1_N*4);
  unsigned* tmp0 = (unsigned*)alloc((size_t)NB*BCAP0*4);
  unsigned* tmp1 = (unsigned*)alloc((size_t)NB*BCAP1*4);
  int* bcur0 = (int*)alloc(NB*4);
  int* bcur1 = (int*)alloc(NB*4);
  int* bb0   = (int*)alloc(NB*4);
  int* bb1   = (int*)alloc(NB*4);
  char* zbase = (char*)alloc(0);
  int* cntL = (int*)alloc((size_t)M_CL*4);
  int* curL = (int*)alloc((size_t)M_CL*4);
  size_t zbytes = (size_t)((char*)(w+off) - zbase);
  int* offsL = (int*)alloc((size_t)(M_CL+1)*4);
  int* csrL  = (int*)alloc((size_t)N_PTS*4);
  int* partL = (int*)alloc(64*4);
  (void)ws_size; (void)in_sizes; (void)n_in; (void)out_size;

  const int NT_N = (N_PTS+15)/16;
  const int NT_M = (M_CL +15)/16;
  const int GBG_N = 1563;
  const int GBG_M = 196;
  const int GB_N  = 2048;

  hipMemsetAsync(zbase, 0, zbytes, stream);

  // ---- CSR builds ----
  k_binit<<<1, 256, 0, stream>>>(bcur0, bcur1);
  k_bin<RANGE0><<<256, 256, 0, stream>>>(l0e, E0_N, bcur0, tmp0);
  k_bin<RANGE1><<<196, 256, 0, stream>>>(l1e, E1_N, bcur1, tmp1);
  k_scan_bases<<<2, 64, 0, stream>>>(bcur0, bb0, offs0+N_PTS, bcur1, bb1, offs1+M_CL);
  k_csr_build<RANGE0,BCAP0><<<NB, 256, 0, stream>>>(tmp0, bcur0, bb0, N_PTS, offs0, csr0);
  k_csr_build<RANGE1,BCAP1><<<NB, 256, 0, stream>>>(tmp1, bcur1, bb1, M_CL, offs1, csr1);

  // ---- label CSR ----
  k_count_lab<<<(N_PTS+255)/256, 256, 0, stream>>>(labels, N_PTS, cntL);
  k_chunk_sum<<<7, 256, 0, stream>>>(cntL, M_CL, partL);
  k_scan_part<<<1, 64, 0, stream>>>(partL, 7, offsL, M_CL);
  k_chunk_scan<<<7, 256, 0, stream>>>(cntL, M_CL, partL, offsL);
  k_fill_lab<<<(N_PTS+255)/256, 256, 0, stream>>>(labels, N_PTS, offsL, curL, csrL);

  // ---- weight prep ----
  WSrc ws{};
  ws.p[0]=mWu+0*4096; ws.p[1]=mWu+1*4096; ws.p[2]=mWu+2*4096; ws.p[3]=mWu+3*4096;
  ws.p[4]=W_m2; ws.p[5]=gWu+0*4096; ws.p[6]=gWu+1*4096;
  ws.p[7]=mWe+0*4288+192; ws.p[8]=mWe+1*4288+192; ws.p[9]=mWe+2*4288+192; ws.p[10]=mWe+3*4288+192;
  ws.p[11]=W_m1; ws.p[12]=W_l; ws.p[13]=gWe+0*4288+192; ws.p[14]=gWe+1*4288+192;
  ws.p[15]=W_c;
  k_wprep<<<16, 256, 0, stream>>>(ws, wt, wtc);

  // ---- encoder ----
  k_f1<<<GB_N, 256, 0, stream>>>(features, points, centers, labels, W_fe, b_fe, rel, B0, U0, N_PTS);

  // ---- g0' = f1 @ mWe0 + be0 + points.Wp0 (f16) ----
  k_gemm<false,0,true,false,false,true,false,true><<<GBG_N,256,0,stream>>>(U0, wt+7*4096, mbe+0,
      mWe+0*4288, points, nullptr, nullptr, nullptr, nullptr, gbuf, N_PTS, NT_N);
  // ---- layer0: agg -> f2 = relu(.@Wu0+bu0)+f1 ----
  k_edge_agg<<<GB_N,256,0,stream>>>(offs0, csr0, points, gbuf, mWe+0*4288, abuf, N_PTS);
  k_gemm<true,1,false,false,true,true,false,false><<<GBG_N,256,0,stream>>>(abuf, wt+0*4096, mbu+0,
      nullptr, nullptr, nullptr, B0, nullptr, B1, U1, N_PTS, NT_N);
  // ---- g1' (f16) ----
  k_gemm<false,0,true,false,false,true,false,true><<<GBG_N,256,0,stream>>>(U1, wt+8*4096, mbe+64,
      mWe+1*4288, points, nullptr, nullptr, nullptr, nullptr, gbuf, N_PTS, NT_N);
  // ---- layer1: f2_1 ----
  k_edge_agg<<<GB_N,256,0,stream>>>(offs0, csr0, points, gbuf, mWe+1*4288, abuf, N_PTS);
  k_gemm<true,1,false,false,false,true,false,false><<<GBG_N,256,0,stream>>>(abuf, wt+1*4096, mbu+64,
      nullptr, nullptr, nullptr, B1, nullptr, nullptr, U0, N_PTS, NT_N);
  // ---- h (f16) = relu(f2_1@W_m1 + rel.Wr + b_m1) ----
  k_gemm<true,0,true,false,false,true,false,true><<<GBG_N,256,0,stream>>>(U0, wt+11*4096, b_m1,
      W_m1+4096, rel, nullptr, nullptr, nullptr, nullptr, gbuf, N_PTS, NT_N);
  // ---- c = segsum(h); f3 ----
  k_seg_gather<<<(M_CL*64+255)/256, 256, 0, stream>>>(offsL, csrL, gbuf, cb_b, M_CL);
  k_gemm<true,0,false,false,true,true,false,false><<<GBG_M,256,0,stream>>>(cb_b, wt+4*4096, b_m2,
      nullptr, nullptr, nullptr, nullptr, nullptr, f3_32, f3_b, M_CL, NT_M);
  // ---- cluster layer0 ----
  k_gemm<false,0,true,false,false,true,false,true><<<GBG_M,256,0,stream>>>(f3_b, wt+13*4096, gbe+0,
      gWe+0*4288, centers, nullptr, nullptr, nullptr, nullptr, cg_b, M_CL, NT_M);
  k_edge_agg<<<GBG_M,256,0,stream>>>(offs1, csr1, centers, cg_b, gWe+0*4288, cagg_b, M_CL);
  k_gemm<true,1,false,false,true,true,false,false><<<GBG_M,256,0,stream>>>(cagg_b, wt+5*4096, gbu+0,
      nullptr, nullptr, nullptr, f3_32, nullptr, f4_32, f4_b, M_CL, NT_M);
  // ---- cluster layer1 ----
  k_gemm<false,0,true,false,false,true,false,true><<<GBG_M,256,0,stream>>>(f4_b, wt+14*4096, gbe+64,
      gWe+1*4288, centers, nullptr, nullptr, nullptr, nullptr, cg_b, M_CL, NT_M);
  k_edge_agg<<<GBG_M,256,0,stream>>>(offs1, csr1, centers, cg_b, gWe+1*4288, cagg_b, M_CL);
  k_gemm<true,1,false,false,false,true,false,false><<<GBG_M,256,0,stream>>>(cagg_b, wt+6*4096, gbu+64,
      nullptr, nullptr, nullptr, f4_32, nullptr, nullptr, f41_b, M_CL, NT_M);
  // ---- f5 ----
  k_gemm<true,0,true,true,true,true,false,false><<<GBG_N,256,0,stream>>>(f41_b, wt+12*4096, b_l,
      W_l+4096, rel, labels, nullptr, nullptr, B0, U1, N_PTS, NT_N);
  // ---- g2' (f16) ----
  k_gemm<false,0,true,false,false,true,false,true><<<GBG_N,256,0,stream>>>(U1, wt+9*4096, mbe+128,
      mWe+2*4288, points, nullptr, nullptr, nullptr, nullptr, gbuf, N_PTS, NT_N);
  // ---- layer2: f6 ----
  k_edge_agg<<<GB_N,256,0,stream>>>(offs0, csr0, points, gbuf, mWe+2*4288, abuf, N_PTS);
  k_gemm<true,2,false,false,true,true,true,false><<<GBG_N,256,0,stream>>>(abuf, wt+2*4096, mbu+128,
      nullptr, nullptr, nullptr, B0, U0, B3, U2, N_PTS, NT_N);
  // ---- g3' (f16) ----
  k_gemm<false,0,true,false,false,true,false,true><<<GBG_N,256,0,stream>>>(U2, wt+10*4096, mbe+192,
      mWe+3*4288, points, nullptr, nullptr, nullptr, nullptr, gbuf, N_PTS, NT_N);
  // ---- layer3: final ----
  k_edge_agg<<<GB_N,256,0,stream>>>(offs0, csr0, points, gbuf, mWe+3*4288, abuf, N_PTS);
  k_gemm<true,2,false,false,false,true,false,false><<<GBG_N,256,0,stream>>>(abuf, wt+3*4096, mbu+192,
      nullptr, nullptr, nullptr, B3, B1, nullptr, U2, N_PTS, NT_N);
  // ---- out ----
  k_cls<<<GBG_N,256,0,stream>>>(U2, wtc, b_c, out, N_PTS, NT_N);
}

// Round 9
// 646.169 us; speedup vs baseline: 1.8979x; 1.0403x over previous
//
#include <hip/hip_runtime.h>

#define N_PTS   100000
#define M_CL    12500
#define E0_N    1600000
#define E1_N    400000

#define NB      128
#define BIN_CAP 48
#define RANGE0  782
#define RANGE1  98
#define BCAP0   16384
#define BCAP1   4096

#define LSTR    72            // LDS row stride (shorts): 144 B, 16-B aligned for ds_read_b128

typedef unsigned short ushortT;
typedef short  short8 __attribute__((ext_vector_type(8)));
typedef float  v4f    __attribute__((ext_vector_type(4)));
typedef _Float16 h2   __attribute__((ext_vector_type(2)));

__device__ inline ushortT f2bf(float x){
  union{float f; unsigned u;} v; v.f = x;
  unsigned r = v.u + 0x7fffu + ((v.u >> 16) & 1u);   // RNE
  return (ushortT)(r >> 16);
}
__device__ inline float bf2f(ushortT h){
  union{unsigned u; float f;} v; v.u = ((unsigned)h) << 16;
  return v.f;
}
__device__ inline ushortT f2h(float x){
  union{_Float16 h; ushortT u;} v; v.h = (_Float16)x;
  return v.u;
}
__device__ inline float h2f(ushortT u){
  union{ushortT u; _Float16 h;} v; v.u = u;
  return (float)v.h;
}

// ============================ bucketed CSR build ============================

__global__ void k_binit(int* c0, int* c1){
  int t = threadIdx.x;
  if (t < NB) c0[t] = t*BCAP0;
  else        c1[t-NB] = (t-NB)*BCAP1;
}

template<int RANGE>
__global__ __launch_bounds__(256) void k_bin(const int* __restrict__ edges, int E,
                                             int* __restrict__ bcur, unsigned* __restrict__ tmp){
  __shared__ unsigned stage[NB*BIN_CAP];
  __shared__ int scnt[NB];
  __shared__ int sbase[NB];
  int tid = threadIdx.x;
  int nchunks = (E + 2047) / 2048;
  for (int c = blockIdx.x; c < nchunks; c += gridDim.x){
    int base = c*2048;
    if (tid < NB) scnt[tid] = 0;
    __syncthreads();
    #pragma unroll
    for (int r=0;r<8;++r){
      int e = base + r*256 + tid;
      if (e < E){
        int s = edges[2*e], d = edges[2*e+1];
        int bk = d / RANGE;
        unsigned packed = ((unsigned)s << 11) | (unsigned)(d - bk*RANGE);
        int pos = atomicAdd(&scnt[bk], 1);
        if (pos < BIN_CAP) stage[bk*BIN_CAP+pos] = packed;
        else tmp[atomicAdd(&bcur[bk],1)] = packed;
      }
    }
    __syncthreads();
    if (tid < NB){
      int nfl = scnt[tid]; if (nfl > BIN_CAP) nfl = BIN_CAP;
      sbase[tid] = atomicAdd(&bcur[tid], nfl);
    }
    __syncthreads();
    int wv = tid >> 6, ln = tid & 63;
    for (int bb=0; bb<NB/4; ++bb){
      int bk = wv*(NB/4) + bb;
      int nfl = scnt[bk]; if (nfl > BIN_CAP) nfl = BIN_CAP;
      if (ln < nfl) tmp[sbase[bk]+ln] = stage[bk*BIN_CAP+ln];
    }
    __syncthreads();
  }
}

__global__ void k_scan_bases(const int* c0, int* bb0, int* off0e,
                             const int* c1, int* bb1, int* off1e){
  const int* cur = blockIdx.x ? c1 : c0;
  int* bb = blockIdx.x ? bb1 : bb0;
  int* offe = blockIdx.x ? off1e : off0e;
  int BC = blockIdx.x ? BCAP1 : BCAP0;
  int lane = threadIdx.x & 63;
  int v0 = cur[2*lane]   - (2*lane)*BC;
  int v1 = cur[2*lane+1] - (2*lane+1)*BC;
  int psum = v0 + v1, sc = psum;
  #pragma unroll
  for (int st=1; st<64; st<<=1){
    int x = __shfl_up(sc, st, 64);
    if (lane >= st) sc += x;
  }
  int ex = sc - psum;
  bb[2*lane] = ex; bb[2*lane+1] = ex + v0;
  if (lane == 63) *offe = sc;
}

template<int RANGE, int BCAP>
__global__ __launch_bounds__(256) void k_csr_build(const unsigned* __restrict__ tmp, const int* __restrict__ bcur,
                                                   const int* __restrict__ bb, int n,
                                                   int* __restrict__ offs, int* __restrict__ csr){
  constexpr int K = (RANGE + 255) / 256;
  __shared__ int hist[RANGE];
  __shared__ int part[256];
  int b = blockIdx.x, tid = threadIdx.x;
  int dlo = b*RANGE;
  int range = n - dlo; if (range > RANGE) range = RANGE; if (range < 0) range = 0;
  int cnt = bcur[b] - b*BCAP;
  for (int t=tid; t<RANGE; t+=256) hist[t] = 0;
  __syncthreads();
  const unsigned* sl = tmp + (size_t)b*BCAP;
  for (int j=tid; j<cnt; j+=256) atomicAdd(&hist[sl[j] & 2047u], 1);
  __syncthreads();
  int s = 0; int loc[K];
  #pragma unroll
  for (int kk=0; kk<K; ++kk){
    int idx = tid*K + kk;
    int v = (idx < RANGE) ? hist[idx] : 0;
    loc[kk] = s; s += v;
  }
  part[tid] = s; __syncthreads();
  int own = s;
  for (int st=1; st<256; st<<=1){
    int x = (tid >= st) ? part[tid-st] : 0;
    __syncthreads();
    part[tid] += x;
    __syncthreads();
  }
  int ebase = part[tid] - own;
  int gb = bb[b];
  __syncthreads();
  #pragma unroll
  for (int kk=0; kk<K; ++kk){
    int idx = tid*K + kk;
    if (idx < RANGE){
      int ex = ebase + loc[kk];
      if (idx < range) offs[dlo+idx] = gb + ex;
      hist[idx] = ex;
    }
  }
  __syncthreads();
  for (int j=tid; j<cnt; j+=256){
    unsigned p = sl[j];
    int pos = atomicAdd(&hist[p & 2047u], 1);
    csr[gb + pos] = (int)(p >> 11);
  }
}

// ============================ label CSR ============================

__global__ __launch_bounds__(256) void k_count_lab(const int* __restrict__ labels, int n, int* __restrict__ cnt){
  int i = blockIdx.x*256 + threadIdx.x;
  if (i < n) atomicAdd(&cnt[labels[i]], 1);
}

__global__ __launch_bounds__(256) void k_chunk_sum(const int* __restrict__ cnt, int n, int* __restrict__ part){
  __shared__ int sd[256];
  int t = threadIdx.x, base = blockIdx.x*2048;
  int s = 0;
  #pragma unroll
  for (int r=0;r<8;++r){ int i = base + t*8 + r; if (i<n) s += cnt[i]; }
  sd[t]=s; __syncthreads();
  for (int st=128; st>0; st>>=1){ if (t<st) sd[t]+=sd[t+st]; __syncthreads(); }
  if (t==0) part[blockIdx.x]=sd[0];
}

__global__ void k_scan_part(int* part, int B, int* offs, int n){
  int lane = threadIdx.x & 63;
  int v = (lane < B) ? part[lane] : 0;
  int orig = v;
  #pragma unroll
  for (int st=1; st<64; st<<=1){
    int x = __shfl_up(v, st, 64);
    if (lane >= st) v += x;
  }
  if (lane < B) part[lane] = v - orig;
  if (lane == 63) offs[n] = v;
}

__global__ __launch_bounds__(256) void k_chunk_scan(const int* __restrict__ cnt, int n,
                                                    const int* __restrict__ part, int* __restrict__ offs){
  __shared__ int sd[256];
  int t=threadIdx.x, base=blockIdx.x*2048;
  int v[8]; int s=0;
  #pragma unroll
  for (int r=0;r<8;++r){ int i=base+t*8+r; v[r] = (i<n)?cnt[i]:0; s+=v[r]; }
  sd[t]=s; __syncthreads();
  for (int st=1; st<256; st<<=1){
    int x = (t>=st)? sd[t-st] : 0;
    __syncthreads();
    sd[t]+=x;
    __syncthreads();
  }
  int acc = part[blockIdx.x] + sd[t] - s;
  #pragma unroll
  for (int r=0;r<8;++r){ int i=base+t*8+r; if (i<n) offs[i]=acc; acc+=v[r]; }
}

__global__ __launch_bounds__(256) void k_fill_lab(const int* __restrict__ labels, int n,
                                                  const int* __restrict__ offs, int* __restrict__ cur,
                                                  int* __restrict__ csr){
  int i = blockIdx.x*256 + threadIdx.x;
  if (i < n){
    int d = labels[i];
    int p = atomicAdd(&cur[d], 1);
    csr[offs[d]+p] = i;
  }
}

// ============================ weight prep ============================

struct WSrc { const float* p[16]; };

__global__ __launch_bounds__(256) void k_wprep(WSrc s, ushortT* __restrict__ wt, ushortT* __restrict__ wtc){
  int slot = blockIdx.x;
  if (slot < 15){
    const float* src = s.p[slot];
    ushortT* dst = wt + slot*4096;
    for (int e=threadIdx.x; e<4096; e+=256){
      int nn = e>>6, kk = e&63;
      dst[e] = f2bf(src[kk*64+nn]);
    }
  } else {
    const float* src = s.p[15];
    for (int e=threadIdx.x; e<1024; e+=256){
      int nn = e>>6, kk = e&63;
      wtc[e] = (nn<8) ? f2bf(src[kk*8+nn]) : (ushortT)0;
    }
  }
}

// ============================ feature encoder: rel + f1 (fp32 + bf16) ============================

__global__ __launch_bounds__(256) void k_f1(const float* __restrict__ features, const float* __restrict__ points,
                                            const float* __restrict__ centers, const int* __restrict__ labels,
                                            const float* __restrict__ W, const float* __restrict__ b,
                                            float* __restrict__ rel, float* __restrict__ f1,
                                            ushortT* __restrict__ f1b, int n){
  int lane = threadIdx.x & 63;
  int gw = (blockIdx.x*256 + threadIdx.x) >> 6;
  int nw = (gridDim.x*256) >> 6;
  float Wf0=W[0*64+lane], Wf1=W[1*64+lane], Wf2=W[2*64+lane], Wf3=W[3*64+lane];
  float wr0=W[4*64+lane], wr1=W[5*64+lane], wr2=W[6*64+lane];
  float bias=b[lane];
  for (int i=gw; i<n; i+=nw){
    int lb = labels[i];
    float rx = points[i*3+0]-centers[lb*3+0];
    float ry = points[i*3+1]-centers[lb*3+1];
    float rz = points[i*3+2]-centers[lb*3+2];
    if (lane==0){ rel[i*3+0]=rx; rel[i*3+1]=ry; rel[i*3+2]=rz; }
    float acc = bias + wr0*rx + wr1*ry + wr2*rz;
    acc += features[i*4+0]*Wf0 + features[i*4+1]*Wf1;
    acc += features[i*4+2]*Wf2 + features[i*4+3]*Wf3;
    acc = fmaxf(acc, 0.f);
    f1[(size_t)i*64+lane] = acc;
    f1b[(size_t)i*64+lane] = f2bf(acc);
  }
}

// ============================ MFMA GEMM with optional fused secondary GEMM ============================
// Primary: out[rows x 64] = act(A_bf16 @ Wt + bias) (+vec.Wr if USEREL) (+res).
// EMODE=1: secondary = primary_strip @ Wt2 + bias2 + vec2.Wr2 (optional ERELU) -> f16 eout.
//          Strip goes C-layout -> LDS (bf16, padded rows) -> A-layout frags (same wave).
// EMODE=2: secondary = primary_strip @ wtc (16x64 padded) + bias2 -> fp32 eout[n x 8] (classifier).

template<bool RELU, int NRES, bool USEREL, bool GATHER, bool OUT32, bool OUT16, bool R2BF, bool F16O, int EMODE, bool ERELU>
__global__ __launch_bounds__(256) void k_gemm(
    const ushortT* __restrict__ A, const ushortT* __restrict__ Wt,
    const float* __restrict__ bias, const float* __restrict__ Wr,
    const float* __restrict__ rel, const int* __restrict__ gidx,
    const float* __restrict__ r1, const void* __restrict__ r2,
    float* __restrict__ out32, ushortT* __restrict__ out16,
    const ushortT* __restrict__ Wt2, const float* __restrict__ bias2,
    const float* __restrict__ Wr2, const float* __restrict__ vec2,
    void* __restrict__ eout,
    int n, int ntiles)
{
  constexpr int LDSZ = (EMODE>0) ? 4*16*LSTR : 4;
  __shared__ ushortT lds[LDSZ];
  int tid = threadIdx.x;
  int lane = tid & 63, wslot = tid >> 6;
  int quad = lane >> 4, l15 = lane & 15;
  int gw = (blockIdx.x*256 + tid) >> 6;
  int nw = (gridDim.x*256) >> 6;

  short8 bfr0_0 = *(const short8*)(Wt + ( 0 + l15)*64 +  0 + quad*8);
  short8 bfr0_1 = *(const short8*)(Wt + ( 0 + l15)*64 + 32 + quad*8);
  short8 bfr1_0 = *(const short8*)(Wt + (16 + l15)*64 +  0 + quad*8);
  short8 bfr1_1 = *(const short8*)(Wt + (16 + l15)*64 + 32 + quad*8);
  short8 bfr2_0 = *(const short8*)(Wt + (32 + l15)*64 +  0 + quad*8);
  short8 bfr2_1 = *(const short8*)(Wt + (32 + l15)*64 + 32 + quad*8);
  short8 bfr3_0 = *(const short8*)(Wt + (48 + l15)*64 +  0 + quad*8);
  short8 bfr3_1 = *(const short8*)(Wt + (48 + l15)*64 + 32 + quad*8);
  float bs0 = bias[ 0 + l15], bs1 = bias[16 + l15];
  float bs2 = bias[32 + l15], bs3 = bias[48 + l15];
  float w0c0=0,w0c1=0,w0c2=0,w0c3=0, w1c0=0,w1c1=0,w1c2=0,w1c3=0, w2c0=0,w2c1=0,w2c2=0,w2c3=0;
  if (USEREL){
    w0c0=Wr[0*64+l15]; w0c1=Wr[0*64+16+l15]; w0c2=Wr[0*64+32+l15]; w0c3=Wr[0*64+48+l15];
    w1c0=Wr[1*64+l15]; w1c1=Wr[1*64+16+l15]; w1c2=Wr[1*64+32+l15]; w1c3=Wr[1*64+48+l15];
    w2c0=Wr[2*64+l15]; w2c1=Wr[2*64+16+l15]; w2c2=Wr[2*64+32+l15]; w2c3=Wr[2*64+48+l15];
  }

  // secondary weight frags
  short8 s0_0{}, s0_1{}, s1_0{}, s1_1{}, s2_0{}, s2_1{}, s3_0{}, s3_1{};
  float eb0=0, eb1=0, eb2=0, eb3=0;
  float e0c0=0,e0c1=0,e0c2=0,e0c3=0, e1c0=0,e1c1=0,e1c2=0,e1c3=0, e2c0=0,e2c1=0,e2c2=0,e2c3=0;
  float ebias_c = 0.f;
  if (EMODE == 1){
    s0_0 = *(const short8*)(Wt2 + ( 0 + l15)*64 +  0 + quad*8);
    s0_1 = *(const short8*)(Wt2 + ( 0 + l15)*64 + 32 + quad*8);
    s1_0 = *(const short8*)(Wt2 + (16 + l15)*64 +  0 + quad*8);
    s1_1 = *(const short8*)(Wt2 + (16 + l15)*64 + 32 + quad*8);
    s2_0 = *(const short8*)(Wt2 + (32 + l15)*64 +  0 + quad*8);
    s2_1 = *(const short8*)(Wt2 + (32 + l15)*64 + 32 + quad*8);
    s3_0 = *(const short8*)(Wt2 + (48 + l15)*64 +  0 + quad*8);
    s3_1 = *(const short8*)(Wt2 + (48 + l15)*64 + 32 + quad*8);
    eb0 = bias2[l15]; eb1 = bias2[16+l15]; eb2 = bias2[32+l15]; eb3 = bias2[48+l15];
    e0c0=Wr2[0*64+l15]; e0c1=Wr2[0*64+16+l15]; e0c2=Wr2[0*64+32+l15]; e0c3=Wr2[0*64+48+l15];
    e1c0=Wr2[1*64+l15]; e1c1=Wr2[1*64+16+l15]; e1c2=Wr2[1*64+32+l15]; e1c3=Wr2[1*64+48+l15];
    e2c0=Wr2[2*64+l15]; e2c1=Wr2[2*64+16+l15]; e2c2=Wr2[2*64+32+l15]; e2c3=Wr2[2*64+48+l15];
  } else if (EMODE == 2){
    s0_0 = *(const short8*)(Wt2 + l15*64 +  0 + quad*8);
    s0_1 = *(const short8*)(Wt2 + l15*64 + 32 + quad*8);
    ebias_c = (l15 < 8) ? bias2[l15] : 0.f;
  }

  for (int t=gw; t<ntiles; t+=nw){
    int i0 = t*16;
    int rowA = i0 + l15; if (rowA >= n) rowA = n-1;
    if (GATHER) rowA = gidx[rowA];
    const ushortT* ap = A + (size_t)rowA*64 + quad*8;
    short8 a0 = *(const short8*)(ap);
    short8 a1 = *(const short8*)(ap + 32);
    v4f ac0 = {0.f,0.f,0.f,0.f}, ac1 = ac0, ac2 = ac0, ac3 = ac0;
    ac0 = __builtin_amdgcn_mfma_f32_16x16x32_bf16(a0, bfr0_0, ac0, 0,0,0);
    ac1 = __builtin_amdgcn_mfma_f32_16x16x32_bf16(a0, bfr1_0, ac1, 0,0,0);
    ac2 = __builtin_amdgcn_mfma_f32_16x16x32_bf16(a0, bfr2_0, ac2, 0,0,0);
    ac3 = __builtin_amdgcn_mfma_f32_16x16x32_bf16(a0, bfr3_0, ac3, 0,0,0);
    ac0 = __builtin_amdgcn_mfma_f32_16x16x32_bf16(a1, bfr0_1, ac0, 0,0,0);
    ac1 = __builtin_amdgcn_mfma_f32_16x16x32_bf16(a1, bfr1_1, ac1, 0,0,0);
    ac2 = __builtin_amdgcn_mfma_f32_16x16x32_bf16(a1, bfr2_1, ac2, 0,0,0);
    ac3 = __builtin_amdgcn_mfma_f32_16x16x32_bf16(a1, bfr3_1, ac3, 0,0,0);

    #pragma unroll
    for (int r=0;r<4;++r){
      int row = i0 + quad*4 + r;
      bool rowok = (row < n);
      float rx=0.f, ry=0.f, rz=0.f;
      if (USEREL && rowok){ rx=rel[row*3+0]; ry=rel[row*3+1]; rz=rel[row*3+2]; }
      float v0 = ac0[r] + bs0, v1 = ac1[r] + bs1, v2 = ac2[r] + bs2, v3 = ac3[r] + bs3;
      if (USEREL){
        v0 += rx*w0c0 + ry*w1c0 + rz*w2c0;
        v1 += rx*w0c1 + ry*w1c1 + rz*w2c1;
        v2 += rx*w0c2 + ry*w1c2 + rz*w2c2;
        v3 += rx*w0c3 + ry*w1c3 + rz*w2c3;
      }
      if (RELU){ v0=fmaxf(v0,0.f); v1=fmaxf(v1,0.f); v2=fmaxf(v2,0.f); v3=fmaxf(v3,0.f); }
      size_t base = (size_t)row*64 + l15;
      if (rowok){
        if (NRES>=1){
          v0 += r1[base]; v1 += r1[base+16]; v2 += r1[base+32]; v3 += r1[base+48];
        }
        if (NRES>=2){
          if (R2BF){
            const ushortT* rr = (const ushortT*)r2;
            v0 += bf2f(rr[base]); v1 += bf2f(rr[base+16]); v2 += bf2f(rr[base+32]); v3 += bf2f(rr[base+48]);
          } else {
            const float* rr = (const float*)r2;
            v0 += rr[base]; v1 += rr[base+16]; v2 += rr[base+32]; v3 += rr[base+48];
          }
        }
        if (OUT32){
          out32[base] = v0; out32[base+16] = v1; out32[base+32] = v2; out32[base+48] = v3;
        }
        if (OUT16){
          if (F16O){
            out16[base] = f2h(v0); out16[base+16] = f2h(v1); out16[base+32] = f2h(v2); out16[base+48] = f2h(v3);
          } else {
            out16[base] = f2bf(v0); out16[base+16] = f2bf(v1); out16[base+32] = f2bf(v2); out16[base+48] = f2bf(v3);
          }
        }
      }
      if (EMODE > 0){
        int lb = wslot*(16*LSTR) + (quad*4+r)*LSTR + l15;
        lds[lb]      = f2bf(v0);
        lds[lb + 16] = f2bf(v1);
        lds[lb + 32] = f2bf(v2);
        lds[lb + 48] = f2bf(v3);
      }
    }

    if (EMODE > 0){
      __builtin_amdgcn_wave_barrier();
      const ushortT* lp = lds + wslot*(16*LSTR) + l15*LSTR + quad*8;
      short8 sa0 = *(const short8*)(lp);
      short8 sa1 = *(const short8*)(lp + 32);
      __builtin_amdgcn_wave_barrier();
      if (EMODE == 1){
        v4f ec0 = {0.f,0.f,0.f,0.f}, ec1 = ec0, ec2 = ec0, ec3 = ec0;
        ec0 = __builtin_amdgcn_mfma_f32_16x16x32_bf16(sa0, s0_0, ec0, 0,0,0);
        ec1 = __builtin_amdgcn_mfma_f32_16x16x32_bf16(sa0, s1_0, ec1, 0,0,0);
        ec2 = __builtin_amdgcn_mfma_f32_16x16x32_bf16(sa0, s2_0, ec2, 0,0,0);
        ec3 = __builtin_amdgcn_mfma_f32_16x16x32_bf16(sa0, s3_0, ec3, 0,0,0);
        ec0 = __builtin_amdgcn_mfma_f32_16x16x32_bf16(sa1, s0_1, ec0, 0,0,0);
        ec1 = __builtin_amdgcn_mfma_f32_16x16x32_bf16(sa1, s1_1, ec1, 0,0,0);
        ec2 = __builtin_amdgcn_mfma_f32_16x16x32_bf16(sa1, s2_1, ec2, 0,0,0);
        ec3 = __builtin_amdgcn_mfma_f32_16x16x32_bf16(sa1, s3_1, ec3, 0,0,0);
        ushortT* eo = (ushortT*)eout;
        #pragma unroll
        for (int r=0;r<4;++r){
          int row = i0 + quad*4 + r;
          if (row < n){
            float vx=vec2[row*3+0], vy=vec2[row*3+1], vz=vec2[row*3+2];
            float g0 = ec0[r] + eb0 + vx*e0c0 + vy*e1c0 + vz*e2c0;
            float g1 = ec1[r] + eb1 + vx*e0c1 + vy*e1c1 + vz*e2c1;
            float g2 = ec2[r] + eb2 + vx*e0c2 + vy*e1c2 + vz*e2c2;
            float g3 = ec3[r] + eb3 + vx*e0c3 + vy*e1c3 + vz*e2c3;
            if (ERELU){ g0=fmaxf(g0,0.f); g1=fmaxf(g1,0.f); g2=fmaxf(g2,0.f); g3=fmaxf(g3,0.f); }
            size_t base = (size_t)row*64 + l15;
            eo[base] = f2h(g0); eo[base+16] = f2h(g1); eo[base+32] = f2h(g2); eo[base+48] = f2h(g3);
          }
        }
      } else {
        v4f ec = {0.f,0.f,0.f,0.f};
        ec = __builtin_amdgcn_mfma_f32_16x16x32_bf16(sa0, s0_0, ec, 0,0,0);
        ec = __builtin_amdgcn_mfma_f32_16x16x32_bf16(sa1, s0_1, ec, 0,0,0);
        if (l15 < 8){
          float* eo = (float*)eout;
          #pragma unroll
          for (int r=0;r<4;++r){
            int row = i0 + quad*4 + r;
            if (row < n) eo[(size_t)row*8 + l15] = ec[r] + ebias_c;
          }
        }
      }
    }
  }
}

// ============================ edge aggregation: f16-packed, 2 edges/iter ============================

__device__ inline h2 pkmax(h2 a, h2 b){ return __builtin_elementwise_max(a, b); }
__device__ inline h2 u2h(unsigned u){ union{unsigned u; h2 h;} v{u}; return v.h; }

__global__ __launch_bounds__(256) void k_edge_agg(const int* __restrict__ offs, const int* __restrict__ csr,
                                                  const float* __restrict__ pos, const ushortT* __restrict__ g,
                                                  const float* __restrict__ Wp, ushortT* __restrict__ agg, int n){
  int lane = threadIdx.x & 63;
  int half = lane >> 5, l31 = lane & 31;
  int gw = (blockIdx.x*256 + threadIdx.x) >> 6;
  int nw = (gridDim.x*256) >> 6;
  const unsigned* g32 = (const unsigned*)g;
  float2 w0 = *(const float2*)(Wp + 0*64 + 2*l31);
  float2 w1 = *(const float2*)(Wp + 1*64 + 2*l31);
  float2 w2 = *(const float2*)(Wp + 2*64 + 2*l31);
  const h2 NEGBIG = {(_Float16)-60000.f, (_Float16)-60000.f};
  for (int i=gw; i<n; i+=nw){
    int b = offs[i], e = offs[i+1];
    h2 m0=NEGBIG, m1=NEGBIG, m2=NEGBIG, m3=NEGBIG, m4=NEGBIG, m5=NEGBIG, m6=NEGBIG, m7=NEGBIG;
    for (int cb=b; cb<e; cb+=64){
      int cnt = e - cb; if (cnt > 64) cnt = 64;
      int li = (lane < cnt) ? lane : 0;
      int sv = csr[cb + li];
      int cm1 = cnt - 1;
      for (int j=0; j<cnt; j+=16){
        int i0 = min(j+ 0+half, cm1), i1 = min(j+ 2+half, cm1);
        int i2 = min(j+ 4+half, cm1), i3 = min(j+ 6+half, cm1);
        int i4 = min(j+ 8+half, cm1), i5 = min(j+10+half, cm1);
        int i6 = min(j+12+half, cm1), i7 = min(j+14+half, cm1);
        int s0 = __shfl(sv, i0, 64), s1 = __shfl(sv, i1, 64);
        int s2 = __shfl(sv, i2, 64), s3 = __shfl(sv, i3, 64);
        int s4 = __shfl(sv, i4, 64), s5 = __shfl(sv, i5, 64);
        int s6 = __shfl(sv, i6, 64), s7 = __shfl(sv, i7, 64);
        unsigned u0 = g32[(unsigned)s0*32u + l31];
        unsigned u1 = g32[(unsigned)s1*32u + l31];
        unsigned u2 = g32[(unsigned)s2*32u + l31];
        unsigned u3 = g32[(unsigned)s3*32u + l31];
        unsigned u4 = g32[(unsigned)s4*32u + l31];
        unsigned u5 = g32[(unsigned)s5*32u + l31];
        unsigned u6 = g32[(unsigned)s6*32u + l31];
        unsigned u7 = g32[(unsigned)s7*32u + l31];
        m0 = pkmax(m0, u2h(u0)); m1 = pkmax(m1, u2h(u1));
        m2 = pkmax(m2, u2h(u2)); m3 = pkmax(m3, u2h(u3));
        m4 = pkmax(m4, u2h(u4)); m5 = pkmax(m5, u2h(u5));
        m6 = pkmax(m6, u2h(u6)); m7 = pkmax(m7, u2h(u7));
      }
    }
    h2 mm = pkmax(pkmax(pkmax(m0,m1),pkmax(m2,m3)),
                  pkmax(pkmax(m4,m5),pkmax(m6,m7)));
    union{h2 h; int u;} pk{mm};
    int other = __shfl_xor(pk.u, 32, 64);
    union{int u; h2 h;} po{other};
    mm = pkmax(mm, po.h);
    float x0 = (float)mm.x, x1 = (float)mm.y;
    float px = pos[i*3+0], py = pos[i*3+1], pz = pos[i*3+2];
    float s0 = w0.x*px + w1.x*py + w2.x*pz;
    float s1 = w0.y*px + w1.y*py + w2.y*pz;
    float r0 = fmaxf(x0 - s0, 0.f);
    float r1 = fmaxf(x1 - s1, 0.f);
    if (half == 0){
      unsigned pkout = (unsigned)f2bf(r0) | ((unsigned)f2bf(r1) << 16);
      ((unsigned*)agg)[(size_t)i*32 + l31] = pkout;
    }
  }
}

// ============================ segment sum via label CSR (f16 in, bf16 out) ============================

__global__ __launch_bounds__(256) void k_seg_gather(const int* __restrict__ offs, const int* __restrict__ csr,
                                                    const ushortT* __restrict__ h, ushortT* __restrict__ c, int m){
  int lane = threadIdx.x & 63;
  int wv = (blockIdx.x*256 + threadIdx.x) >> 6;
  if (wv >= m) return;
  int b = offs[wv], e = offs[wv+1];
  float acc = 0.f;
  for (int k=b; k<e; ++k){
    int i = csr[k];
    acc += h2f(h[(size_t)i*64+lane]);
  }
  c[(size_t)wv*64+lane] = f2bf(acc);
}

// ============================ host launcher ============================

extern "C" void kernel_launch(void* const* d_in, const int* in_sizes, int n_in,
                              void* d_out, int out_size, void* d_ws, size_t ws_size,
                              hipStream_t stream){
  const float* features = (const float*)d_in[0];
  const float* points   = (const float*)d_in[1];
  const float* centers  = (const float*)d_in[2];
  const int*   l0e      = (const int*)d_in[3];
  const int*   l1e      = (const int*)d_in[4];
  const int*   labels   = (const int*)d_in[5];
  const float* W_fe = (const float*)d_in[6];
  const float* b_fe = (const float*)d_in[7];
  const float* mWe  = (const float*)d_in[8];   // (4,67,64)
  const float* mbe  = (const float*)d_in[9];
  const float* mWu  = (const float*)d_in[10];  // (4,64,64)
  const float* mbu  = (const float*)d_in[11];
  const float* W_m1 = (const float*)d_in[12];
  const float* b_m1 = (const float*)d_in[13];
  const float* W_m2 = (const float*)d_in[14];
  const float* b_m2 = (const float*)d_in[15];
  const float* gWe  = (const float*)d_in[16];  // (2,67,64)
  const float* gbe  = (const float*)d_in[17];
  const float* gWu  = (const float*)d_in[18];
  const float* gbu  = (const float*)d_in[19];
  const float* W_l  = (const float*)d_in[20];
  const float* b_l  = (const float*)d_in[21];
  const float* W_c  = (const float*)d_in[22];
  const float* b_c  = (const float*)d_in[23];
  float* out = (float*)d_out;

  char* w = (char*)d_ws;
  size_t off = 0;
  auto alloc = [&](size_t bytes)->void*{
    void* p = (void*)(w + off);
    off = (off + bytes + 255) & ~(size_t)255;
    return p;
  };
  float* rel  = (float*)alloc((size_t)N_PTS*3*4);
  float* B0 = (float*)alloc((size_t)N_PTS*64*4);   // f1 -> f5
  float* B1 = (float*)alloc((size_t)N_PTS*64*4);   // f2
  float* B3 = (float*)alloc((size_t)N_PTS*64*4);   // f6
  ushortT* U0 = (ushortT*)alloc((size_t)N_PTS*64*2);  // f1b -> f2_1 bf16
  ushortT* gbuf = (ushortT*)alloc((size_t)N_PTS*64*2); // f16 g'/h
  ushortT* abuf = (ushortT*)alloc((size_t)N_PTS*64*2); // bf16 agg
  ushortT* cb_b = (ushortT*)alloc((size_t)M_CL*64*2);
  float* f3_32  = (float*)alloc((size_t)M_CL*64*4);
  ushortT* cg_b = (ushortT*)alloc((size_t)M_CL*64*2);  // f16 cluster g'
  ushortT* cagg_b = (ushortT*)alloc((size_t)M_CL*64*2);
  float* f4_32  = (float*)alloc((size_t)M_CL*64*4);
  ushortT* f41_b = (ushortT*)alloc((size_t)M_CL*64*2);
  ushortT* wt  = (ushortT*)alloc((size_t)15*4096*2);
  ushortT* wtc = (ushortT*)alloc((size_t)1024*2);
  int* offs0 = (int*)alloc((size_t)(N_PTS+1)*4);
  int* csr0  = (int*)alloc((size_t)E0_N*4);
  int* offs1 = (int*)alloc((size_t)(M_CL+1)*4);
  int* csr1  = (int*)alloc((size_t)E1_N*4);
  unsigned* tmp0 = (unsigned*)alloc((size_t)NB*BCAP0*4);
  unsigned* tmp1 = (unsigned*)alloc((size_t)NB*BCAP1*4);
  int* bcur0 = (int*)alloc(NB*4);
  int* bcur1 = (int*)alloc(NB*4);
  int* bb0   = (int*)alloc(NB*4);
  int* bb1   = (int*)alloc(NB*4);
  char* zbase = (char*)alloc(0);
  int* cntL = (int*)alloc((size_t)M_CL*4);
  int* curL = (int*)alloc((size_t)M_CL*4);
  size_t zbytes = (size_t)((char*)(w+off) - zbase);
  int* offsL = (int*)alloc((size_t)(M_CL+1)*4);
  int* csrL  = (int*)alloc((size_t)N_PTS*4);
  int* partL = (int*)alloc(64*4);
  (void)ws_size; (void)in_sizes; (void)n_in; (void)out_size;

  const int NT_N = (N_PTS+15)/16;
  const int NT_M = (M_CL +15)/16;
  const int GBG_N = 1563;
  const int GBG_M = 196;
  const int GB_N  = 2048;

  hipMemsetAsync(zbase, 0, zbytes, stream);

  // ---- CSR builds ----
  k_binit<<<1, 256, 0, stream>>>(bcur0, bcur1);
  k_bin<RANGE0><<<256, 256, 0, stream>>>(l0e, E0_N, bcur0, tmp0);
  k_bin<RANGE1><<<196, 256, 0, stream>>>(l1e, E1_N, bcur1, tmp1);
  k_scan_bases<<<2, 64, 0, stream>>>(bcur0, bb0, offs0+N_PTS, bcur1, bb1, offs1+M_CL);
  k_csr_build<RANGE0,BCAP0><<<NB, 256, 0, stream>>>(tmp0, bcur0, bb0, N_PTS, offs0, csr0);
  k_csr_build<RANGE1,BCAP1><<<NB, 256, 0, stream>>>(tmp1, bcur1, bb1, M_CL, offs1, csr1);

  // ---- label CSR ----
  k_count_lab<<<(N_PTS+255)/256, 256, 0, stream>>>(labels, N_PTS, cntL);
  k_chunk_sum<<<7, 256, 0, stream>>>(cntL, M_CL, partL);
  k_scan_part<<<1, 64, 0, stream>>>(partL, 7, offsL, M_CL);
  k_chunk_scan<<<7, 256, 0, stream>>>(cntL, M_CL, partL, offsL);
  k_fill_lab<<<(N_PTS+255)/256, 256, 0, stream>>>(labels, N_PTS, offsL, curL, csrL);

  // ---- weight prep ----
  WSrc ws{};
  ws.p[0]=mWu+0*4096; ws.p[1]=mWu+1*4096; ws.p[2]=mWu+2*4096; ws.p[3]=mWu+3*4096;
  ws.p[4]=W_m2; ws.p[5]=gWu+0*4096; ws.p[6]=gWu+1*4096;
  ws.p[7]=mWe+0*4288+192; ws.p[8]=mWe+1*4288+192; ws.p[9]=mWe+2*4288+192; ws.p[10]=mWe+3*4288+192;
  ws.p[11]=W_m1; ws.p[12]=W_l; ws.p[13]=gWe+0*4288+192; ws.p[14]=gWe+1*4288+192;
  ws.p[15]=W_c;
  k_wprep<<<16, 256, 0, stream>>>(ws, wt, wtc);

  // ---- encoder ----
  k_f1<<<GB_N, 256, 0, stream>>>(features, points, centers, labels, W_fe, b_fe, rel, B0, U0, N_PTS);

  // ---- g0' = f1 @ mWe0 + be0 + points.Wp0 (f16, standalone) ----
  k_gemm<false,0,true,false,false,true,false,true,0,false><<<GBG_N,256,0,stream>>>(U0, wt+7*4096, mbe+0,
      mWe+0*4288, points, nullptr, nullptr, nullptr, nullptr, gbuf,
      nullptr, nullptr, nullptr, nullptr, nullptr, N_PTS, NT_N);
  // ---- layer0: agg -> FUSED [f2 = relu(.@Wu0+bu0)+f1 -> B1] + [g1' = f2@We1+be1+pos.Wp1 -> gbuf] ----
  k_edge_agg<<<GB_N,256,0,stream>>>(offs0, csr0, points, gbuf, mWe+0*4288, abuf, N_PTS);
  k_gemm<true,1,false,false,true,false,false,false,1,false><<<GBG_N,256,0,stream>>>(abuf, wt+0*4096, mbu+0,
      nullptr, nullptr, nullptr, B0, nullptr, B1, nullptr,
      wt+8*4096, mbe+64, mWe+1*4288, points, gbuf, N_PTS, NT_N);
  // ---- layer1: agg -> FUSED [f2_1 -> U0 bf16] + [h = relu(f2_1@W_m1 + rel.Wr + b_m1) -> gbuf] ----
  k_edge_agg<<<GB_N,256,0,stream>>>(offs0, csr0, points, gbuf, mWe+1*4288, abuf, N_PTS);
  k_gemm<true,1,false,false,false,true,false,false,1,true><<<GBG_N,256,0,stream>>>(abuf, wt+1*4096, mbu+64,
      nullptr, nullptr, nullptr, B1, nullptr, nullptr, U0,
      wt+11*4096, b_m1, W_m1+4096, rel, gbuf, N_PTS, NT_N);
  // ---- c = segsum(h); FUSED [f3 -> f3_32] + [cg0' -> cg_b] ----
  k_seg_gather<<<(M_CL*64+255)/256, 256, 0, stream>>>(offsL, csrL, gbuf, cb_b, M_CL);
  k_gemm<true,0,false,false,true,false,false,false,1,false><<<GBG_M,256,0,stream>>>(cb_b, wt+4*4096, b_m2,
      nullptr, nullptr, nullptr, nullptr, nullptr, f3_32, nullptr,
      wt+13*4096, gbe+0, gWe+0*4288, centers, cg_b, M_CL, NT_M);
  // ---- cluster layer0: agg -> FUSED [f4 -> f4_32] + [cg1' -> cg_b] ----
  k_edge_agg<<<GBG_M,256,0,stream>>>(offs1, csr1, centers, cg_b, gWe+0*4288, cagg_b, M_CL);
  k_gemm<true,1,false,false,true,false,false,false,1,false><<<GBG_M,256,0,stream>>>(cagg_b, wt+5*4096, gbu+0,
      nullptr, nullptr, nullptr, f3_32, nullptr, f4_32, nullptr,
      wt+14*4096, gbe+64, gWe+1*4288, centers, cg_b, M_CL, NT_M);
  // ---- cluster layer1: agg -> f4_1 (bf16, standalone: next consumer gathers) ----
  k_edge_agg<<<GBG_M,256,0,stream>>>(offs1, csr1, centers, cg_b, gWe+1*4288, cagg_b, M_CL);
  k_gemm<true,1,false,false,false,true,false,false,0,false><<<GBG_M,256,0,stream>>>(cagg_b, wt+6*4096, gbu+64,
      nullptr, nullptr, nullptr, f4_32, nullptr, nullptr, f41_b,
      nullptr, nullptr, nullptr, nullptr, nullptr, M_CL, NT_M);
  // ---- FUSED [f5 = relu(f41[labels]@W_l + rel.Wr + b_l) -> B0] + [g2' -> gbuf] ----
  k_gemm<true,0,true,true,true,false,false,false,1,false><<<GBG_N,256,0,stream>>>(f41_b, wt+12*4096, b_l,
      W_l+4096, rel, labels, nullptr, nullptr, B0, nullptr,
      wt+9*4096, mbe+128, mWe+2*4288, points, gbuf, N_PTS, NT_N);
  // ---- layer2: agg -> FUSED [f6 = relu+f5+f2_1 -> B3] + [g3' -> gbuf] ----
  k_edge_agg<<<GB_N,256,0,stream>>>(offs0, csr0, points, gbuf, mWe+2*4288, abuf, N_PTS);
  k_gemm<true,2,false,false,true,false,true,false,1,false><<<GBG_N,256,0,stream>>>(abuf, wt+2*4096, mbu+128,
      nullptr, nullptr, nullptr, B0, U0, B3, nullptr,
      wt+10*4096, mbe+192, mWe+3*4288, points, gbuf, N_PTS, NT_N);
  // ---- layer3: agg -> FUSED [final = relu+f6+f2] + [out = final@W_c + b_c] ----
  k_edge_agg<<<GB_N,256,0,stream>>>(offs0, csr0, points, gbuf, mWe+3*4288, abuf, N_PTS);
  k_gemm<true,2,false,false,false,false,false,false,2,false><<<GBG_N,256,0,stream>>>(abuf, wt+3*4096, mbu+192,
      nullptr, nullptr, nullptr, B3, B1, nullptr, nullptr,
      wtc, b_c, nullptr, nullptr, out, N_PTS, NT_N);
}

// Round 10
// 605.685 us; speedup vs baseline: 2.0248x; 1.0668x over previous
//
#include <hip/hip_runtime.h>

#define N_PTS   100000
#define M_CL    12500
#define E0_N    1600000
#define E1_N    400000

#define NB      256
#define BIN_CAP 32
#define RANGE0  391          // ceil(100000/256)
#define RANGE1  49           // ceil(12500/256)
#define BCAP0   8192         // mean 6250 (+24 sigma)
#define BCAP1   2048         // mean 1562

#define LSTR    72           // LDS row stride (shorts): 144 B, 16-B aligned

typedef unsigned short ushortT;
typedef short  short8 __attribute__((ext_vector_type(8)));
typedef float  v4f    __attribute__((ext_vector_type(4)));
typedef _Float16 h2   __attribute__((ext_vector_type(2)));

__device__ inline ushortT f2bf(float x){
  union{float f; unsigned u;} v; v.f = x;
  unsigned r = v.u + 0x7fffu + ((v.u >> 16) & 1u);   // RNE
  return (ushortT)(r >> 16);
}
__device__ inline float bf2f(ushortT h){
  union{unsigned u; float f;} v; v.u = ((unsigned)h) << 16;
  return v.f;
}
__device__ inline ushortT f2h(float x){
  union{_Float16 h; ushortT u;} v; v.h = (_Float16)x;
  return v.u;
}
__device__ inline float h2f(ushortT u){
  union{ushortT u; _Float16 h;} v; v.u = u;
  return (float)v.h;
}
__device__ inline h2 pkmax(h2 a, h2 b){ return __builtin_elementwise_max(a, b); }
__device__ inline h2 u2h(unsigned u){ union{unsigned u; h2 h;} v{u}; return v.h; }

// ============================ bucketed CSR build ============================

__global__ void k_binit(int* c0, int* c1){
  int t = threadIdx.x;
  c0[t] = t*BCAP0;
  c1[t] = t*BCAP1;
}

template<int RANGE>
__global__ __launch_bounds__(256) void k_bin(const int* __restrict__ edges, int E,
                                             int* __restrict__ bcur, unsigned* __restrict__ tmp){
  __shared__ unsigned stage[NB*BIN_CAP];   // 32 KB
  __shared__ int scnt[NB];
  __shared__ int sbase[NB];
  int tid = threadIdx.x;
  int nchunks = (E + 2047) / 2048;
  for (int c = blockIdx.x; c < nchunks; c += gridDim.x){
    int base = c*2048;
    scnt[tid] = 0;
    __syncthreads();
    #pragma unroll
    for (int r=0;r<8;++r){
      int e = base + r*256 + tid;
      if (e < E){
        int s = edges[2*e], d = edges[2*e+1];
        int bk = d / RANGE;
        unsigned packed = ((unsigned)s << 11) | (unsigned)(d - bk*RANGE);
        int pos = atomicAdd(&scnt[bk], 1);
        if (pos < BIN_CAP) stage[bk*BIN_CAP+pos] = packed;
        else tmp[atomicAdd(&bcur[bk],1)] = packed;
      }
    }
    __syncthreads();
    {
      int nfl = scnt[tid]; if (nfl > BIN_CAP) nfl = BIN_CAP;
      sbase[tid] = atomicAdd(&bcur[tid], nfl);
    }
    __syncthreads();
    int wv = tid >> 6, ln = tid & 63;
    for (int bb=0; bb<32; ++bb){
      int bk = wv*64 + bb*2 + (ln>>5);
      int ent = ln & 31;
      int nf = scnt[bk]; if (nf > BIN_CAP) nf = BIN_CAP;
      if (ent < nf) tmp[sbase[bk]+ent] = stage[bk*BIN_CAP+ent];
    }
    __syncthreads();
  }
}

// exclusive scan of 256 bucket counts (block 0 -> l0, block 1 -> l1)
__global__ void k_scan_bases(const int* c0, int* bb0, int* off0e,
                             const int* c1, int* bb1, int* off1e){
  const int* cur = blockIdx.x ? c1 : c0;
  int* bb = blockIdx.x ? bb1 : bb0;
  int* offe = blockIdx.x ? off1e : off0e;
  int BC = blockIdx.x ? BCAP1 : BCAP0;
  int lane = threadIdx.x & 63;
  int base = lane*4;
  int v0 = cur[base+0] - (base+0)*BC;
  int v1 = cur[base+1] - (base+1)*BC;
  int v2 = cur[base+2] - (base+2)*BC;
  int v3 = cur[base+3] - (base+3)*BC;
  int psum = v0+v1+v2+v3, sc = psum;
  #pragma unroll
  for (int st=1; st<64; st<<=1){
    int x = __shfl_up(sc, st, 64);
    if (lane >= st) sc += x;
  }
  int ex = sc - psum;
  bb[base+0] = ex;
  bb[base+1] = ex + v0;
  bb[base+2] = ex + v0 + v1;
  bb[base+3] = ex + v0 + v1 + v2;
  if (lane == 63) *offe = sc;
}

template<int RANGE, int BCAP>
__global__ __launch_bounds__(256) void k_csr_build(const unsigned* __restrict__ tmp, const int* __restrict__ bcur,
                                                   const int* __restrict__ bb, int n,
                                                   int* __restrict__ offs, int* __restrict__ csr){
  constexpr int K = (RANGE + 255) / 256;
  __shared__ int hist[RANGE];
  __shared__ int part[256];
  int b = blockIdx.x, tid = threadIdx.x;
  int dlo = b*RANGE;
  int range = n - dlo; if (range > RANGE) range = RANGE; if (range < 0) range = 0;
  int cnt = bcur[b] - b*BCAP;
  for (int t=tid; t<RANGE; t+=256) hist[t] = 0;
  __syncthreads();
  const unsigned* sl = tmp + (size_t)b*BCAP;
  for (int j=tid; j<cnt; j+=256) atomicAdd(&hist[sl[j] & 2047u], 1);
  __syncthreads();
  int s = 0; int loc[K];
  #pragma unroll
  for (int kk=0; kk<K; ++kk){
    int idx = tid*K + kk;
    int v = (idx < RANGE) ? hist[idx] : 0;
    loc[kk] = s; s += v;
  }
  part[tid] = s; __syncthreads();
  int own = s;
  for (int st=1; st<256; st<<=1){
    int x = (tid >= st) ? part[tid-st] : 0;
    __syncthreads();
    part[tid] += x;
    __syncthreads();
  }
  int ebase = part[tid] - own;
  int gb = bb[b];
  __syncthreads();
  #pragma unroll
  for (int kk=0; kk<K; ++kk){
    int idx = tid*K + kk;
    if (idx < RANGE){
      int ex = ebase + loc[kk];
      if (idx < range) offs[dlo+idx] = gb + ex;
      hist[idx] = ex;
    }
  }
  __syncthreads();
  for (int j=tid; j<cnt; j+=256){
    unsigned p = sl[j];
    int pos = atomicAdd(&hist[p & 2047u], 1);
    csr[gb + pos] = (int)(p >> 11);
  }
}

// ============================ label CSR ============================

__global__ __launch_bounds__(256) void k_count_lab(const int* __restrict__ labels, int n, int* __restrict__ cnt){
  int i = blockIdx.x*256 + threadIdx.x;
  if (i < n) atomicAdd(&cnt[labels[i]], 1);
}

__global__ __launch_bounds__(256) void k_chunk_sum(const int* __restrict__ cnt, int n, int* __restrict__ part){
  __shared__ int sd[256];
  int t = threadIdx.x, base = blockIdx.x*2048;
  int s = 0;
  #pragma unroll
  for (int r=0;r<8;++r){ int i = base + t*8 + r; if (i<n) s += cnt[i]; }
  sd[t]=s; __syncthreads();
  for (int st=128; st>0; st>>=1){ if (t<st) sd[t]+=sd[t+st]; __syncthreads(); }
  if (t==0) part[blockIdx.x]=sd[0];
}

__global__ void k_scan_part(int* part, int B, int* offs, int n){
  int lane = threadIdx.x & 63;
  int v = (lane < B) ? part[lane] : 0;
  int orig = v;
  #pragma unroll
  for (int st=1; st<64; st<<=1){
    int x = __shfl_up(v, st, 64);
    if (lane >= st) v += x;
  }
  if (lane < B) part[lane] = v - orig;
  if (lane == 63) offs[n] = v;
}

__global__ __launch_bounds__(256) void k_chunk_scan(const int* __restrict__ cnt, int n,
                                                    const int* __restrict__ part, int* __restrict__ offs){
  __shared__ int sd[256];
  int t=threadIdx.x, base=blockIdx.x*2048;
  int v[8]; int s=0;
  #pragma unroll
  for (int r=0;r<8;++r){ int i=base+t*8+r; v[r] = (i<n)?cnt[i]:0; s+=v[r]; }
  sd[t]=s; __syncthreads();
  for (int st=1; st<256; st<<=1){
    int x = (t>=st)? sd[t-st] : 0;
    __syncthreads();
    sd[t]+=x;
    __syncthreads();
  }
  int acc = part[blockIdx.x] + sd[t] - s;
  #pragma unroll
  for (int r=0;r<8;++r){ int i=base+t*8+r; if (i<n) offs[i]=acc; acc+=v[r]; }
}

__global__ __launch_bounds__(256) void k_fill_lab(const int* __restrict__ labels, int n,
                                                  const int* __restrict__ offs, int* __restrict__ cur,
                                                  int* __restrict__ csr){
  int i = blockIdx.x*256 + threadIdx.x;
  if (i < n){
    int d = labels[i];
    int p = atomicAdd(&cur[d], 1);
    csr[offs[d]+p] = i;
  }
}

// ============================ weight prep ============================

struct WSrc { const float* p[16]; };

__global__ __launch_bounds__(256) void k_wprep(WSrc s, ushortT* __restrict__ wt, ushortT* __restrict__ wtc){
  int slot = blockIdx.x;
  if (slot < 15){
    const float* src = s.p[slot];
    ushortT* dst = wt + slot*4096;
    for (int e=threadIdx.x; e<4096; e+=256){
      int nn = e>>6, kk = e&63;
      dst[e] = f2bf(src[kk*64+nn]);
    }
  } else {
    const float* src = s.p[15];
    for (int e=threadIdx.x; e<1024; e+=256){
      int nn = e>>6, kk = e&63;
      wtc[e] = (nn<8) ? f2bf(src[kk*8+nn]) : (ushortT)0;
    }
  }
}

// ============================ feature encoder: rel + f1 (bf16) ============================

__global__ __launch_bounds__(256) void k_f1(const float* __restrict__ features, const float* __restrict__ points,
                                            const float* __restrict__ centers, const int* __restrict__ labels,
                                            const float* __restrict__ W, const float* __restrict__ b,
                                            float* __restrict__ rel, ushortT* __restrict__ f1b, int n){
  int lane = threadIdx.x & 63;
  int gw = (blockIdx.x*256 + threadIdx.x) >> 6;
  int nw = (gridDim.x*256) >> 6;
  float Wf0=W[0*64+lane], Wf1=W[1*64+lane], Wf2=W[2*64+lane], Wf3=W[3*64+lane];
  float wr0=W[4*64+lane], wr1=W[5*64+lane], wr2=W[6*64+lane];
  float bias=b[lane];
  for (int i=gw; i<n; i+=nw){
    int lb = labels[i];
    float rx = points[i*3+0]-centers[lb*3+0];
    float ry = points[i*3+1]-centers[lb*3+1];
    float rz = points[i*3+2]-centers[lb*3+2];
    if (lane==0){ rel[i*3+0]=rx; rel[i*3+1]=ry; rel[i*3+2]=rz; }
    float acc = bias + wr0*rx + wr1*ry + wr2*rz;
    acc += features[i*4+0]*Wf0 + features[i*4+1]*Wf1;
    acc += features[i*4+2]*Wf2 + features[i*4+3]*Wf3;
    f1b[(size_t)i*64+lane] = f2bf(fmaxf(acc, 0.f));
  }
}

// ============================ MFMA GEMM with optional fused secondary GEMM ============================
// Primary: out16[rows x 64] = act(A_bf16 @ Wt + bias) (+vec.Wr if USEREL) (+bf16 residuals).
// EMODE=1: secondary = strip @ Wt2 + bias2 + vec2.Wr2 (opt ERELU) -> f16 eout (via LDS relayout).
// EMODE=2: secondary = strip @ wtc + bias2 -> fp32 eout[n x 8] (classifier).

template<bool RELU, int NRES, bool USEREL, bool GATHER, bool OUT16, bool F16O, int EMODE, bool ERELU>
__global__ __launch_bounds__(256) void k_gemm(
    const ushortT* __restrict__ A, const ushortT* __restrict__ Wt,
    const float* __restrict__ bias, const float* __restrict__ Wr,
    const float* __restrict__ rel, const int* __restrict__ gidx,
    const ushortT* __restrict__ r1, const ushortT* __restrict__ r2,
    ushortT* __restrict__ out16,
    const ushortT* __restrict__ Wt2, const float* __restrict__ bias2,
    const float* __restrict__ Wr2, const float* __restrict__ vec2,
    void* __restrict__ eout,
    int n, int ntiles)
{
  constexpr int LDSZ = (EMODE>0) ? 4*16*LSTR : 4;
  __shared__ ushortT lds[LDSZ];
  int tid = threadIdx.x;
  int lane = tid & 63, wslot = tid >> 6;
  int quad = lane >> 4, l15 = lane & 15;
  int gw = (blockIdx.x*256 + tid) >> 6;
  int nw = (gridDim.x*256) >> 6;

  short8 bfr0_0 = *(const short8*)(Wt + ( 0 + l15)*64 +  0 + quad*8);
  short8 bfr0_1 = *(const short8*)(Wt + ( 0 + l15)*64 + 32 + quad*8);
  short8 bfr1_0 = *(const short8*)(Wt + (16 + l15)*64 +  0 + quad*8);
  short8 bfr1_1 = *(const short8*)(Wt + (16 + l15)*64 + 32 + quad*8);
  short8 bfr2_0 = *(const short8*)(Wt + (32 + l15)*64 +  0 + quad*8);
  short8 bfr2_1 = *(const short8*)(Wt + (32 + l15)*64 + 32 + quad*8);
  short8 bfr3_0 = *(const short8*)(Wt + (48 + l15)*64 +  0 + quad*8);
  short8 bfr3_1 = *(const short8*)(Wt + (48 + l15)*64 + 32 + quad*8);
  float bs0 = bias[ 0 + l15], bs1 = bias[16 + l15];
  float bs2 = bias[32 + l15], bs3 = bias[48 + l15];
  float w0c0=0,w0c1=0,w0c2=0,w0c3=0, w1c0=0,w1c1=0,w1c2=0,w1c3=0, w2c0=0,w2c1=0,w2c2=0,w2c3=0;
  if (USEREL){
    w0c0=Wr[0*64+l15]; w0c1=Wr[0*64+16+l15]; w0c2=Wr[0*64+32+l15]; w0c3=Wr[0*64+48+l15];
    w1c0=Wr[1*64+l15]; w1c1=Wr[1*64+16+l15]; w1c2=Wr[1*64+32+l15]; w1c3=Wr[1*64+48+l15];
    w2c0=Wr[2*64+l15]; w2c1=Wr[2*64+16+l15]; w2c2=Wr[2*64+32+l15]; w2c3=Wr[2*64+48+l15];
  }

  short8 s0_0{}, s0_1{}, s1_0{}, s1_1{}, s2_0{}, s2_1{}, s3_0{}, s3_1{};
  float eb0=0, eb1=0, eb2=0, eb3=0;
  float e0c0=0,e0c1=0,e0c2=0,e0c3=0, e1c0=0,e1c1=0,e1c2=0,e1c3=0, e2c0=0,e2c1=0,e2c2=0,e2c3=0;
  float ebias_c = 0.f;
  if (EMODE == 1){
    s0_0 = *(const short8*)(Wt2 + ( 0 + l15)*64 +  0 + quad*8);
    s0_1 = *(const short8*)(Wt2 + ( 0 + l15)*64 + 32 + quad*8);
    s1_0 = *(const short8*)(Wt2 + (16 + l15)*64 +  0 + quad*8);
    s1_1 = *(const short8*)(Wt2 + (16 + l15)*64 + 32 + quad*8);
    s2_0 = *(const short8*)(Wt2 + (32 + l15)*64 +  0 + quad*8);
    s2_1 = *(const short8*)(Wt2 + (32 + l15)*64 + 32 + quad*8);
    s3_0 = *(const short8*)(Wt2 + (48 + l15)*64 +  0 + quad*8);
    s3_1 = *(const short8*)(Wt2 + (48 + l15)*64 + 32 + quad*8);
    eb0 = bias2[l15]; eb1 = bias2[16+l15]; eb2 = bias2[32+l15]; eb3 = bias2[48+l15];
    e0c0=Wr2[0*64+l15]; e0c1=Wr2[0*64+16+l15]; e0c2=Wr2[0*64+32+l15]; e0c3=Wr2[0*64+48+l15];
    e1c0=Wr2[1*64+l15]; e1c1=Wr2[1*64+16+l15]; e1c2=Wr2[1*64+32+l15]; e1c3=Wr2[1*64+48+l15];
    e2c0=Wr2[2*64+l15]; e2c1=Wr2[2*64+16+l15]; e2c2=Wr2[2*64+32+l15]; e2c3=Wr2[2*64+48+l15];
  } else if (EMODE == 2){
    s0_0 = *(const short8*)(Wt2 + l15*64 +  0 + quad*8);
    s0_1 = *(const short8*)(Wt2 + l15*64 + 32 + quad*8);
    ebias_c = (l15 < 8) ? bias2[l15] : 0.f;
  }

  for (int t=gw; t<ntiles; t+=nw){
    int i0 = t*16;
    int rowA = i0 + l15; if (rowA >= n) rowA = n-1;
    if (GATHER) rowA = gidx[rowA];
    const ushortT* ap = A + (size_t)rowA*64 + quad*8;
    short8 a0 = *(const short8*)(ap);
    short8 a1 = *(const short8*)(ap + 32);
    v4f ac0 = {0.f,0.f,0.f,0.f}, ac1 = ac0, ac2 = ac0, ac3 = ac0;
    ac0 = __builtin_amdgcn_mfma_f32_16x16x32_bf16(a0, bfr0_0, ac0, 0,0,0);
    ac1 = __builtin_amdgcn_mfma_f32_16x16x32_bf16(a0, bfr1_0, ac1, 0,0,0);
    ac2 = __builtin_amdgcn_mfma_f32_16x16x32_bf16(a0, bfr2_0, ac2, 0,0,0);
    ac3 = __builtin_amdgcn_mfma_f32_16x16x32_bf16(a0, bfr3_0, ac3, 0,0,0);
    ac0 = __builtin_amdgcn_mfma_f32_16x16x32_bf16(a1, bfr0_1, ac0, 0,0,0);
    ac1 = __builtin_amdgcn_mfma_f32_16x16x32_bf16(a1, bfr1_1, ac1, 0,0,0);
    ac2 = __builtin_amdgcn_mfma_f32_16x16x32_bf16(a1, bfr2_1, ac2, 0,0,0);
    ac3 = __builtin_amdgcn_mfma_f32_16x16x32_bf16(a1, bfr3_1, ac3, 0,0,0);

    #pragma unroll
    for (int r=0;r<4;++r){
      int row = i0 + quad*4 + r;
      bool rowok = (row < n);
      float rx=0.f, ry=0.f, rz=0.f;
      if (USEREL && rowok){ rx=rel[row*3+0]; ry=rel[row*3+1]; rz=rel[row*3+2]; }
      float v0 = ac0[r] + bs0, v1 = ac1[r] + bs1, v2 = ac2[r] + bs2, v3 = ac3[r] + bs3;
      if (USEREL){
        v0 += rx*w0c0 + ry*w1c0 + rz*w2c0;
        v1 += rx*w0c1 + ry*w1c1 + rz*w2c1;
        v2 += rx*w0c2 + ry*w1c2 + rz*w2c2;
        v3 += rx*w0c3 + ry*w1c3 + rz*w2c3;
      }
      if (RELU){ v0=fmaxf(v0,0.f); v1=fmaxf(v1,0.f); v2=fmaxf(v2,0.f); v3=fmaxf(v3,0.f); }
      size_t base = (size_t)row*64 + l15;
      if (rowok){
        if (NRES>=1){
          v0 += bf2f(r1[base]); v1 += bf2f(r1[base+16]); v2 += bf2f(r1[base+32]); v3 += bf2f(r1[base+48]);
        }
        if (NRES>=2){
          v0 += bf2f(r2[base]); v1 += bf2f(r2[base+16]); v2 += bf2f(r2[base+32]); v3 += bf2f(r2[base+48]);
        }
        if (OUT16){
          if (F16O){
            out16[base] = f2h(v0); out16[base+16] = f2h(v1); out16[base+32] = f2h(v2); out16[base+48] = f2h(v3);
          } else {
            out16[base] = f2bf(v0); out16[base+16] = f2bf(v1); out16[base+32] = f2bf(v2); out16[base+48] = f2bf(v3);
          }
        }
      }
      if (EMODE > 0){
        int lb = wslot*(16*LSTR) + (quad*4+r)*LSTR + l15;
        lds[lb]      = f2bf(v0);
        lds[lb + 16] = f2bf(v1);
        lds[lb + 32] = f2bf(v2);
        lds[lb + 48] = f2bf(v3);
      }
    }

    if (EMODE > 0){
      __builtin_amdgcn_wave_barrier();
      const ushortT* lp = lds + wslot*(16*LSTR) + l15*LSTR + quad*8;
      short8 sa0 = *(const short8*)(lp);
      short8 sa1 = *(const short8*)(lp + 32);
      __builtin_amdgcn_wave_barrier();
      if (EMODE == 1){
        v4f ec0 = {0.f,0.f,0.f,0.f}, ec1 = ec0, ec2 = ec0, ec3 = ec0;
        ec0 = __builtin_amdgcn_mfma_f32_16x16x32_bf16(sa0, s0_0, ec0, 0,0,0);
        ec1 = __builtin_amdgcn_mfma_f32_16x16x32_bf16(sa0, s1_0, ec1, 0,0,0);
        ec2 = __builtin_amdgcn_mfma_f32_16x16x32_bf16(sa0, s2_0, ec2, 0,0,0);
        ec3 = __builtin_amdgcn_mfma_f32_16x16x32_bf16(sa0, s3_0, ec3, 0,0,0);
        ec0 = __builtin_amdgcn_mfma_f32_16x16x32_bf16(sa1, s0_1, ec0, 0,0,0);
        ec1 = __builtin_amdgcn_mfma_f32_16x16x32_bf16(sa1, s1_1, ec1, 0,0,0);
        ec2 = __builtin_amdgcn_mfma_f32_16x16x32_bf16(sa1, s2_1, ec2, 0,0,0);
        ec3 = __builtin_amdgcn_mfma_f32_16x16x32_bf16(sa1, s3_1, ec3, 0,0,0);
        ushortT* eo = (ushortT*)eout;
        #pragma unroll
        for (int r=0;r<4;++r){
          int row = i0 + quad*4 + r;
          if (row < n){
            float vx=vec2[row*3+0], vy=vec2[row*3+1], vz=vec2[row*3+2];
            float g0 = ec0[r] + eb0 + vx*e0c0 + vy*e1c0 + vz*e2c0;
            float g1 = ec1[r] + eb1 + vx*e0c1 + vy*e1c1 + vz*e2c1;
            float g2 = ec2[r] + eb2 + vx*e0c2 + vy*e1c2 + vz*e2c2;
            float g3 = ec3[r] + eb3 + vx*e0c3 + vy*e1c3 + vz*e2c3;
            if (ERELU){ g0=fmaxf(g0,0.f); g1=fmaxf(g1,0.f); g2=fmaxf(g2,0.f); g3=fmaxf(g3,0.f); }
            size_t base = (size_t)row*64 + l15;
            eo[base] = f2h(g0); eo[base+16] = f2h(g1); eo[base+32] = f2h(g2); eo[base+48] = f2h(g3);
          }
        }
      } else {
        v4f ec = {0.f,0.f,0.f,0.f};
        ec = __builtin_amdgcn_mfma_f32_16x16x32_bf16(sa0, s0_0, ec, 0,0,0);
        ec = __builtin_amdgcn_mfma_f32_16x16x32_bf16(sa1, s0_1, ec, 0,0,0);
        if (l15 < 8){
          float* eo = (float*)eout;
          #pragma unroll
          for (int r=0;r<4;++r){
            int row = i0 + quad*4 + r;
            if (row < n) eo[(size_t)row*8 + l15] = ec[r] + ebias_c;
          }
        }
      }
    }
  }
}

// ============================ edge aggregation: 2 dsts per wave for ILP ============================
// g' f16[64] rows; lane -> dims {2*l31, 2*l31+1}; halves split edge slots.
// Fast path (1 <= deg <= 64): process dst pair with 16 gathers in flight.

__global__ __launch_bounds__(256) void k_edge_agg(const int* __restrict__ offs, const int* __restrict__ csr,
                                                  const float* __restrict__ pos, const ushortT* __restrict__ g,
                                                  const float* __restrict__ Wp, ushortT* __restrict__ agg, int n){
  int lane = threadIdx.x & 63;
  int half = lane >> 5, l31 = lane & 31;
  int gw = (blockIdx.x*256 + threadIdx.x) >> 6;
  int nw = (gridDim.x*256) >> 6;
  const unsigned* g32 = (const unsigned*)g;
  float2 w0 = *(const float2*)(Wp + 0*64 + 2*l31);
  float2 w1 = *(const float2*)(Wp + 1*64 + 2*l31);
  float2 w2 = *(const float2*)(Wp + 2*64 + 2*l31);
  const h2 NEGBIG = {(_Float16)-60000.f, (_Float16)-60000.f};

  auto epi = [&](int i, h2 m0, h2 m1, h2 m2, h2 m3, h2 m4, h2 m5, h2 m6, h2 m7){
    h2 mm = pkmax(pkmax(pkmax(m0,m1),pkmax(m2,m3)),
                  pkmax(pkmax(m4,m5),pkmax(m6,m7)));
    union{h2 h; int u;} pk{mm};
    int other = __shfl_xor(pk.u, 32, 64);
    union{int u; h2 h;} po{other};
    mm = pkmax(mm, po.h);
    float x0 = (float)mm.x, x1 = (float)mm.y;
    float px = pos[i*3+0], py = pos[i*3+1], pz = pos[i*3+2];
    float s0 = w0.x*px + w1.x*py + w2.x*pz;
    float s1 = w0.y*px + w1.y*py + w2.y*pz;
    float r0 = fmaxf(x0 - s0, 0.f);
    float r1 = fmaxf(x1 - s1, 0.f);
    if (half == 0){
      unsigned pkout = (unsigned)f2bf(r0) | ((unsigned)f2bf(r1) << 16);
      ((unsigned*)agg)[(size_t)i*32 + l31] = pkout;
    }
  };

  auto slow = [&](int i){
    int b = offs[i], e = offs[i+1];
    h2 m0=NEGBIG,m1=NEGBIG,m2=NEGBIG,m3=NEGBIG,m4=NEGBIG,m5=NEGBIG,m6=NEGBIG,m7=NEGBIG;
    for (int cb=b; cb<e; cb+=64){
      int cnt = e - cb; if (cnt > 64) cnt = 64;
      int li = (lane < cnt) ? lane : 0;
      int sv = csr[cb + li];
      int cm1 = cnt - 1;
      for (int j=0; j<cnt; j+=16){
        int i0 = min(j+ 0+half, cm1), i1 = min(j+ 2+half, cm1);
        int i2 = min(j+ 4+half, cm1), i3 = min(j+ 6+half, cm1);
        int i4 = min(j+ 8+half, cm1), i5 = min(j+10+half, cm1);
        int i6 = min(j+12+half, cm1), i7 = min(j+14+half, cm1);
        int s0 = __shfl(sv, i0, 64), s1 = __shfl(sv, i1, 64);
        int s2 = __shfl(sv, i2, 64), s3 = __shfl(sv, i3, 64);
        int s4 = __shfl(sv, i4, 64), s5 = __shfl(sv, i5, 64);
        int s6 = __shfl(sv, i6, 64), s7 = __shfl(sv, i7, 64);
        unsigned u0 = g32[(unsigned)s0*32u + l31];
        unsigned u1 = g32[(unsigned)s1*32u + l31];
        unsigned u2 = g32[(unsigned)s2*32u + l31];
        unsigned u3 = g32[(unsigned)s3*32u + l31];
        unsigned u4 = g32[(unsigned)s4*32u + l31];
        unsigned u5 = g32[(unsigned)s5*32u + l31];
        unsigned u6 = g32[(unsigned)s6*32u + l31];
        unsigned u7 = g32[(unsigned)s7*32u + l31];
        m0 = pkmax(m0, u2h(u0)); m1 = pkmax(m1, u2h(u1));
        m2 = pkmax(m2, u2h(u2)); m3 = pkmax(m3, u2h(u3));
        m4 = pkmax(m4, u2h(u4)); m5 = pkmax(m5, u2h(u5));
        m6 = pkmax(m6, u2h(u6)); m7 = pkmax(m7, u2h(u7));
      }
    }
    epi(i, m0,m1,m2,m3,m4,m5,m6,m7);
  };

  int nh = (n+1) >> 1;
  for (int ii=gw; ii<nh; ii+=nw){
    int iA = ii*2;
    int iB = iA+1; if (iB >= n) iB = n-1;
    int bA = offs[iA], eA = offs[iA+1], cntA = eA-bA;
    int bB = offs[iB], eB = offs[iB+1], cntB = eB-bB;
    if ((unsigned)(cntA-1) <= 63u && (unsigned)(cntB-1) <= 63u){
      int cA1 = cntA-1, cB1 = cntB-1;
      int svA = csr[bA + min(lane, cA1)];
      int svB = csr[bB + min(lane, cB1)];
      h2 a0=NEGBIG,a1=NEGBIG,a2=NEGBIG,a3=NEGBIG,a4=NEGBIG,a5=NEGBIG,a6=NEGBIG,a7=NEGBIG;
      h2 b0=NEGBIG,b1=NEGBIG,b2=NEGBIG,b3=NEGBIG,b4=NEGBIG,b5=NEGBIG,b6=NEGBIG,b7=NEGBIG;
      int mx = cntA > cntB ? cntA : cntB;
      for (int j=0; j<mx; j+=16){
        int jb = j + half;
        int qa0=min(jb   ,cA1), qa1=min(jb+ 2,cA1), qa2=min(jb+ 4,cA1), qa3=min(jb+ 6,cA1);
        int qa4=min(jb+ 8,cA1), qa5=min(jb+10,cA1), qa6=min(jb+12,cA1), qa7=min(jb+14,cA1);
        int qb0=min(jb   ,cB1), qb1=min(jb+ 2,cB1), qb2=min(jb+ 4,cB1), qb3=min(jb+ 6,cB1);
        int qb4=min(jb+ 8,cB1), qb5=min(jb+10,cB1), qb6=min(jb+12,cB1), qb7=min(jb+14,cB1);
        int sA0=__shfl(svA,qa0,64), sA1=__shfl(svA,qa1,64), sA2=__shfl(svA,qa2,64), sA3=__shfl(svA,qa3,64);
        int sA4=__shfl(svA,qa4,64), sA5=__shfl(svA,qa5,64), sA6=__shfl(svA,qa6,64), sA7=__shfl(svA,qa7,64);
        int sB0=__shfl(svB,qb0,64), sB1=__shfl(svB,qb1,64), sB2=__shfl(svB,qb2,64), sB3=__shfl(svB,qb3,64);
        int sB4=__shfl(svB,qb4,64), sB5=__shfl(svB,qb5,64), sB6=__shfl(svB,qb6,64), sB7=__shfl(svB,qb7,64);
        unsigned uA0=g32[(unsigned)sA0*32u+l31], uA1=g32[(unsigned)sA1*32u+l31];
        unsigned uA2=g32[(unsigned)sA2*32u+l31], uA3=g32[(unsigned)sA3*32u+l31];
        unsigned uA4=g32[(unsigned)sA4*32u+l31], uA5=g32[(unsigned)sA5*32u+l31];
        unsigned uA6=g32[(unsigned)sA6*32u+l31], uA7=g32[(unsigned)sA7*32u+l31];
        unsigned uB0=g32[(unsigned)sB0*32u+l31], uB1=g32[(unsigned)sB1*32u+l31];
        unsigned uB2=g32[(unsigned)sB2*32u+l31], uB3=g32[(unsigned)sB3*32u+l31];
        unsigned uB4=g32[(unsigned)sB4*32u+l31], uB5=g32[(unsigned)sB5*32u+l31];
        unsigned uB6=g32[(unsigned)sB6*32u+l31], uB7=g32[(unsigned)sB7*32u+l31];
        a0=pkmax(a0,u2h(uA0)); a1=pkmax(a1,u2h(uA1)); a2=pkmax(a2,u2h(uA2)); a3=pkmax(a3,u2h(uA3));
        a4=pkmax(a4,u2h(uA4)); a5=pkmax(a5,u2h(uA5)); a6=pkmax(a6,u2h(uA6)); a7=pkmax(a7,u2h(uA7));
        b0=pkmax(b0,u2h(uB0)); b1=pkmax(b1,u2h(uB1)); b2=pkmax(b2,u2h(uB2)); b3=pkmax(b3,u2h(uB3));
        b4=pkmax(b4,u2h(uB4)); b5=pkmax(b5,u2h(uB5)); b6=pkmax(b6,u2h(uB6)); b7=pkmax(b7,u2h(uB7));
      }
      epi(iA, a0,a1,a2,a3,a4,a5,a6,a7);
      if (iB != iA) epi(iB, b0,b1,b2,b3,b4,b5,b6,b7);
    } else {
      slow(iA);
      if (iB != iA) slow(iB);
    }
  }
}

// ============================ segment sum via label CSR (f16 in, bf16 out) ============================

__global__ __launch_bounds__(256) void k_seg_gather(const int* __restrict__ offs, const int* __restrict__ csr,
                                                    const ushortT* __restrict__ h, ushortT* __restrict__ c, int m){
  int lane = threadIdx.x & 63;
  int wv = (blockIdx.x*256 + threadIdx.x) >> 6;
  if (wv >= m) return;
  int b = offs[wv], e = offs[wv+1];
  float acc = 0.f;
  for (int k=b; k<e; ++k){
    int i = csr[k];
    acc += h2f(h[(size_t)i*64+lane]);
  }
  c[(size_t)wv*64+lane] = f2bf(acc);
}

// ============================ host launcher ============================

extern "C" void kernel_launch(void* const* d_in, const int* in_sizes, int n_in,
                              void* d_out, int out_size, void* d_ws, size_t ws_size,
                              hipStream_t stream){
  const float* features = (const float*)d_in[0];
  const float* points   = (const float*)d_in[1];
  const float* centers  = (const float*)d_in[2];
  const int*   l0e      = (const int*)d_in[3];
  const int*   l1e      = (const int*)d_in[4];
  const int*   labels   = (const int*)d_in[5];
  const float* W_fe = (const float*)d_in[6];
  const float* b_fe = (const float*)d_in[7];
  const float* mWe  = (const float*)d_in[8];
  const float* mbe  = (const float*)d_in[9];
  const float* mWu  = (const float*)d_in[10];
  const float* mbu  = (const float*)d_in[11];
  const float* W_m1 = (const float*)d_in[12];
  const float* b_m1 = (const float*)d_in[13];
  const float* W_m2 = (const float*)d_in[14];
  const float* b_m2 = (const float*)d_in[15];
  const float* gWe  = (const float*)d_in[16];
  const float* gbe  = (const float*)d_in[17];
  const float* gWu  = (const float*)d_in[18];
  const float* gbu  = (const float*)d_in[19];
  const float* W_l  = (const float*)d_in[20];
  const float* b_l  = (const float*)d_in[21];
  const float* W_c  = (const float*)d_in[22];
  const float* b_c  = (const float*)d_in[23];
  float* out = (float*)d_out;

  char* w = (char*)d_ws;
  size_t off = 0;
  auto alloc = [&](size_t bytes)->void*{
    void* p = (void*)(w + off);
    off = (off + bytes + 255) & ~(size_t)255;
    return p;
  };
  float* rel  = (float*)alloc((size_t)N_PTS*3*4);
  ushortT* UF1 = (ushortT*)alloc((size_t)N_PTS*64*2);   // f1
  ushortT* UF2 = (ushortT*)alloc((size_t)N_PTS*64*2);   // f2
  ushortT* UF21= (ushortT*)alloc((size_t)N_PTS*64*2);   // f2_1
  ushortT* UF5 = (ushortT*)alloc((size_t)N_PTS*64*2);   // f5
  ushortT* UF6 = (ushortT*)alloc((size_t)N_PTS*64*2);   // f6
  ushortT* gbuf= (ushortT*)alloc((size_t)N_PTS*64*2);   // f16 g'/h
  ushortT* abuf= (ushortT*)alloc((size_t)N_PTS*64*2);   // bf16 agg
  ushortT* cb_b= (ushortT*)alloc((size_t)M_CL*64*2);
  ushortT* UF3 = (ushortT*)alloc((size_t)M_CL*64*2);    // f3
  ushortT* UF4 = (ushortT*)alloc((size_t)M_CL*64*2);    // f4
  ushortT* cg_b= (ushortT*)alloc((size_t)M_CL*64*2);
  ushortT* cagg_b = (ushortT*)alloc((size_t)M_CL*64*2);
  ushortT* f41_b  = (ushortT*)alloc((size_t)M_CL*64*2);
  ushortT* wt  = (ushortT*)alloc((size_t)15*4096*2);
  ushortT* wtc = (ushortT*)alloc((size_t)1024*2);
  int* offs0 = (int*)alloc((size_t)(N_PTS+1)*4);
  int* csr0  = (int*)alloc((size_t)E0_N*4);
  int* offs1 = (int*)alloc((size_t)(M_CL+1)*4);
  int* csr1  = (int*)alloc((size_t)E1_N*4);
  unsigned* tmp0 = (unsigned*)alloc((size_t)NB*BCAP0*4);
  unsigned* tmp1 = (unsigned*)alloc((size_t)NB*BCAP1*4);
  int* bcur0 = (int*)alloc(NB*4);
  int* bcur1 = (int*)alloc(NB*4);
  int* bb0   = (int*)alloc(NB*4);
  int* bb1   = (int*)alloc(NB*4);
  char* zbase = (char*)alloc(0);
  int* cntL = (int*)alloc((size_t)M_CL*4);
  int* curL = (int*)alloc((size_t)M_CL*4);
  size_t zbytes = (size_t)((char*)(w+off) - zbase);
  int* offsL = (int*)alloc((size_t)(M_CL+1)*4);
  int* csrL  = (int*)alloc((size_t)N_PTS*4);
  int* partL = (int*)alloc(64*4);
  (void)ws_size; (void)in_sizes; (void)n_in; (void)out_size;

  const int NT_N = (N_PTS+15)/16;
  const int NT_M = (M_CL +15)/16;
  const int GBG_N = 1563;
  const int GBG_M = 196;
  const int GB_N  = 2048;

  hipMemsetAsync(zbase, 0, zbytes, stream);

  // ---- CSR builds (256 buckets) ----
  k_binit<<<1, 256, 0, stream>>>(bcur0, bcur1);
  k_bin<RANGE0><<<256, 256, 0, stream>>>(l0e, E0_N, bcur0, tmp0);
  k_bin<RANGE1><<<196, 256, 0, stream>>>(l1e, E1_N, bcur1, tmp1);
  k_scan_bases<<<2, 64, 0, stream>>>(bcur0, bb0, offs0+N_PTS, bcur1, bb1, offs1+M_CL);
  k_csr_build<RANGE0,BCAP0><<<NB, 256, 0, stream>>>(tmp0, bcur0, bb0, N_PTS, offs0, csr0);
  k_csr_build<RANGE1,BCAP1><<<NB, 256, 0, stream>>>(tmp1, bcur1, bb1, M_CL, offs1, csr1);

  // ---- label CSR ----
  k_count_lab<<<(N_PTS+255)/256, 256, 0, stream>>>(labels, N_PTS, cntL);
  k_chunk_sum<<<7, 256, 0, stream>>>(cntL, M_CL, partL);
  k_scan_part<<<1, 64, 0, stream>>>(partL, 7, offsL, M_CL);
  k_chunk_scan<<<7, 256, 0, stream>>>(cntL, M_CL, partL, offsL);
  k_fill_lab<<<(N_PTS+255)/256, 256, 0, stream>>>(labels, N_PTS, offsL, curL, csrL);

  // ---- weight prep ----
  WSrc ws{};
  ws.p[0]=mWu+0*4096; ws.p[1]=mWu+1*4096; ws.p[2]=mWu+2*4096; ws.p[3]=mWu+3*4096;
  ws.p[4]=W_m2; ws.p[5]=gWu+0*4096; ws.p[6]=gWu+1*4096;
  ws.p[7]=mWe+0*4288+192; ws.p[8]=mWe+1*4288+192; ws.p[9]=mWe+2*4288+192; ws.p[10]=mWe+3*4288+192;
  ws.p[11]=W_m1; ws.p[12]=W_l; ws.p[13]=gWe+0*4288+192; ws.p[14]=gWe+1*4288+192;
  ws.p[15]=W_c;
  k_wprep<<<16, 256, 0, stream>>>(ws, wt, wtc);

  // ---- encoder: rel + f1 (bf16) ----
  k_f1<<<GB_N, 256, 0, stream>>>(features, points, centers, labels, W_fe, b_fe, rel, UF1, N_PTS);

  // ---- g0' = f1 @ mWe0 + be0 + points.Wp0 (f16) ----
  k_gemm<false,0,true,false,true,true,0,false><<<GBG_N,256,0,stream>>>(UF1, wt+7*4096, mbe+0,
      mWe+0*4288, points, nullptr, nullptr, nullptr, gbuf,
      nullptr, nullptr, nullptr, nullptr, nullptr, N_PTS, NT_N);
  // ---- layer0: agg -> FUSED [f2 -> UF2] + [g1' -> gbuf] ----
  k_edge_agg<<<GB_N,256,0,stream>>>(offs0, csr0, points, gbuf, mWe+0*4288, abuf, N_PTS);
  k_gemm<true,1,false,false,true,false,1,false><<<GBG_N,256,0,stream>>>(abuf, wt+0*4096, mbu+0,
      nullptr, nullptr, nullptr, UF1, nullptr, UF2,
      wt+8*4096, mbe+64, mWe+1*4288, points, gbuf, N_PTS, NT_N);
  // ---- layer1: agg -> FUSED [f2_1 -> UF21] + [h -> gbuf] ----
  k_edge_agg<<<GB_N,256,0,stream>>>(offs0, csr0, points, gbuf, mWe+1*4288, abuf, N_PTS);
  k_gemm<true,1,false,false,true,false,1,true><<<GBG_N,256,0,stream>>>(abuf, wt+1*4096, mbu+64,
      nullptr, nullptr, nullptr, UF2, nullptr, UF21,
      wt+11*4096, b_m1, W_m1+4096, rel, gbuf, N_PTS, NT_N);
  // ---- c = segsum(h); FUSED [f3 -> UF3] + [cg0' -> cg_b] ----
  k_seg_gather<<<(M_CL*64+255)/256, 256, 0, stream>>>(offsL, csrL, gbuf, cb_b, M_CL);
  k_gemm<true,0,false,false,true,false,1,false><<<GBG_M,256,0,stream>>>(cb_b, wt+4*4096, b_m2,
      nullptr, nullptr, nullptr, nullptr, nullptr, UF3,
      wt+13*4096, gbe+0, gWe+0*4288, centers, cg_b, M_CL, NT_M);
  // ---- cluster layer0: agg -> FUSED [f4 -> UF4] + [cg1' -> cg_b] ----
  k_edge_agg<<<GBG_M,256,0,stream>>>(offs1, csr1, centers, cg_b, gWe+0*4288, cagg_b, M_CL);
  k_gemm<true,1,false,false,true,false,1,false><<<GBG_M,256,0,stream>>>(cagg_b, wt+5*4096, gbu+0,
      nullptr, nullptr, nullptr, UF3, nullptr, UF4,
      wt+14*4096, gbe+64, gWe+1*4288, centers, cg_b, M_CL, NT_M);
  // ---- cluster layer1: agg -> f4_1 -> f41_b ----
  k_edge_agg<<<GBG_M,256,0,stream>>>(offs1, csr1, centers, cg_b, gWe+1*4288, cagg_b, M_CL);
  k_gemm<true,1,false,false,true,false,0,false><<<GBG_M,256,0,stream>>>(cagg_b, wt+6*4096, gbu+64,
      nullptr, nullptr, nullptr, UF4, nullptr, f41_b,
      nullptr, nullptr, nullptr, nullptr, nullptr, M_CL, NT_M);
  // ---- FUSED [f5 -> UF5] + [g2' -> gbuf] ----
  k_gemm<true,0,true,true,true,false,1,false><<<GBG_N,256,0,stream>>>(f41_b, wt+12*4096, b_l,
      W_l+4096, rel, labels, nullptr, nullptr, UF5,
      wt+9*4096, mbe+128, mWe+2*4288, points, gbuf, N_PTS, NT_N);
  // ---- layer2: agg -> FUSED [f6 = relu+f5+f2_1 -> UF6] + [g3' -> gbuf] ----
  k_edge_agg<<<GB_N,256,0,stream>>>(offs0, csr0, points, gbuf, mWe+2*4288, abuf, N_PTS);
  k_gemm<true,2,false,false,true,false,1,false><<<GBG_N,256,0,stream>>>(abuf, wt+2*4096, mbu+128,
      nullptr, nullptr, nullptr, UF5, UF21, UF6,
      wt+10*4096, mbe+192, mWe+3*4288, points, gbuf, N_PTS, NT_N);
  // ---- layer3: agg -> FUSED [final = relu+f6+f2] + [out = final@W_c + b_c] ----
  k_edge_agg<<<GB_N,256,0,stream>>>(offs0, csr0, points, gbuf, mWe+3*4288, abuf, N_PTS);
  k_gemm<true,2,false,false,false,false,2,false><<<GBG_N,256,0,stream>>>(abuf, wt+3*4096, mbu+192,
      nullptr, nullptr, nullptr, UF6, UF2, nullptr,
      wtc, b_c, nullptr, nullptr, out, N_PTS, NT_N);
}